// Round 12
// baseline (775.191 us; speedup 1.0000x reference)
//
#include <hip/hip_runtime.h>
#include <math.h>

// Problem constants (fixed by the reference)
#define BATCH 2
#define T_LEN 2048
#define D_DIM 1024
#define KSEL  15
#define HIDN  64
#define NCAND 24

typedef double f64x4 __attribute__((ext_vector_type(4)));
typedef short  bf16x8 __attribute__((ext_vector_type(8)));
typedef float  f32x4v __attribute__((ext_vector_type(4)));

__device__ __forceinline__ float geluf(float x) {
  return 0.5f * x * (1.0f + erff(x * 0.70710678118654752440f));
}

__device__ __forceinline__ unsigned short f32_to_bf16_rne(float x) {
  unsigned u = __builtin_bit_cast(unsigned, x);
  unsigned lsb = (u >> 16) & 1u;
  u += 0x7fffu + lsb;
  return (unsigned short)(u >> 16);
}
__device__ __forceinline__ float bf16_to_f32(unsigned short h) {
  unsigned u = ((unsigned)h) << 16;
  return __builtin_bit_cast(float, u);
}

// ---------------------------------------------------------------------------
// f64 MFMA GEMM (f32 in / f32 out), v_mfma_f64_16x16x4_f64, LAYOUT-PROBED,
// 64x128 tile + LDS double-buffer + reg prefetch. (r9-r11, unchanged.)
// Used ONLY for x@Wi / x@Wp (selection-critical values).
// ---------------------------------------------------------------------------
template<bool BT, bool CAUSAL>
__global__ void __launch_bounds__(256, 3) gemm64q(
    const float* __restrict__ A, const float* __restrict__ Ba,
    const float* __restrict__ Bb, float* __restrict__ C,
    int N, int K, long sA, long sB, long sC, double alpha)
{
  int m0, n0;
  if (CAUSAL) {
    int rem = blockIdx.x, bi = 0;
    while (rem >= (bi >> 1) + 1) { rem -= (bi >> 1) + 1; ++bi; }
    m0 = bi << 6; n0 = rem << 7;
  } else {
    m0 = blockIdx.y << 6; n0 = blockIdx.x << 7;
  }
  const int z = blockIdx.z;
  A += (size_t)z * sA;
  const float* B = (z ? Bb : Ba) + (size_t)z * sB;
  C += (size_t)z * sC;

  const int tid = threadIdx.x;
  const int w = tid >> 6, lane = tid & 63;
  const int kl = lane >> 4, lm = lane & 15;
  const int am0 = (w & 1) << 5;
  const int bn0 = (w >> 1) << 6;

  __shared__ double As[2][16][66];
  __shared__ double Bs[2][16][130];

  // layout probe (buf 0)
  {
    int m = tid & 63, k4 = (tid >> 6) << 2;
#pragma unroll
    for (int q = 0; q < 4; ++q) As[0][k4 + q][m] = (double)m;
    int n = tid & 127, k8 = (tid >> 7) << 3;
#pragma unroll
    for (int q = 0; q < 8; ++q) Bs[0][k8 + q][n] = (double)n;
  }
  __syncthreads();
  int mr[4], nc[4];
  {
    double pa = As[0][kl][am0 + lm];
    double pb = Bs[0][kl][bn0 + lm];
    f64x4 d1 = {0.0, 0.0, 0.0, 0.0}, d2 = {0.0, 0.0, 0.0, 0.0};
    d1 = __builtin_amdgcn_mfma_f64_16x16x4f64(pa, 1.0, d1, 0, 0, 0);
    d2 = __builtin_amdgcn_mfma_f64_16x16x4f64(1.0, pb, d2, 0, 0, 0);
#pragma unroll
    for (int i = 0; i < 4; ++i) {
      mr[i] = ((int)d1[i]) >> 2;
      nc[i] = ((int)d2[i]) >> 2;
    }
  }
  __syncthreads();

  f64x4 c00 = {0,0,0,0}, c01 = {0,0,0,0}, c02 = {0,0,0,0}, c03 = {0,0,0,0};
  f64x4 c10 = {0,0,0,0}, c11 = {0,0,0,0}, c12 = {0,0,0,0}, c13 = {0,0,0,0};

  const int am = tid >> 2, akq = (tid & 3) << 2;
  const int bk = tid >> 4, bn8 = (tid & 15) << 3;
  const int tn = tid >> 1, tkq = (tid & 1) << 3;

  float4 ra, rb0, rb1;

  ra = *(const float4*)(A + (size_t)(m0 + am) * K + akq);
  if (!BT) {
    const float* bp = B + (size_t)bk * N + n0 + bn8;
    rb0 = *(const float4*)(bp); rb1 = *(const float4*)(bp + 4);
  } else {
    const float* bp = B + (size_t)(n0 + tn) * K + tkq;
    rb0 = *(const float4*)(bp); rb1 = *(const float4*)(bp + 4);
  }
  {
    As[0][akq + 0][am] = (double)ra.x; As[0][akq + 1][am] = (double)ra.y;
    As[0][akq + 2][am] = (double)ra.z; As[0][akq + 3][am] = (double)ra.w;
    if (!BT) {
      Bs[0][bk][bn8 + 0] = (double)rb0.x; Bs[0][bk][bn8 + 1] = (double)rb0.y;
      Bs[0][bk][bn8 + 2] = (double)rb0.z; Bs[0][bk][bn8 + 3] = (double)rb0.w;
      Bs[0][bk][bn8 + 4] = (double)rb1.x; Bs[0][bk][bn8 + 5] = (double)rb1.y;
      Bs[0][bk][bn8 + 6] = (double)rb1.z; Bs[0][bk][bn8 + 7] = (double)rb1.w;
    } else {
      Bs[0][tkq + 0][tn] = (double)rb0.x; Bs[0][tkq + 1][tn] = (double)rb0.y;
      Bs[0][tkq + 2][tn] = (double)rb0.z; Bs[0][tkq + 3][tn] = (double)rb0.w;
      Bs[0][tkq + 4][tn] = (double)rb1.x; Bs[0][tkq + 5][tn] = (double)rb1.y;
      Bs[0][tkq + 6][tn] = (double)rb1.z; Bs[0][tkq + 7][tn] = (double)rb1.w;
    }
  }
  __syncthreads();

  int buf = 0;
  for (int k0 = 0; k0 < K; k0 += 16) {
    const bool more = (k0 + 16) < K;
    if (more) {
      const int kn = k0 + 16;
      ra = *(const float4*)(A + (size_t)(m0 + am) * K + kn + akq);
      if (!BT) {
        const float* bp = B + (size_t)(kn + bk) * N + n0 + bn8;
        rb0 = *(const float4*)(bp); rb1 = *(const float4*)(bp + 4);
      } else {
        const float* bp = B + (size_t)(n0 + tn) * K + kn + tkq;
        rb0 = *(const float4*)(bp); rb1 = *(const float4*)(bp + 4);
      }
    }
#pragma unroll
    for (int ks = 0; ks < 4; ++ks) {
      const int kr = (ks << 2) + kl;
      double a0 = As[buf][kr][am0 + lm];
      double a1 = As[buf][kr][am0 + 16 + lm];
      double b0 = Bs[buf][kr][bn0 + lm];
      double b1 = Bs[buf][kr][bn0 + 16 + lm];
      double b2 = Bs[buf][kr][bn0 + 32 + lm];
      double b3 = Bs[buf][kr][bn0 + 48 + lm];
      c00 = __builtin_amdgcn_mfma_f64_16x16x4f64(a0, b0, c00, 0, 0, 0);
      c01 = __builtin_amdgcn_mfma_f64_16x16x4f64(a0, b1, c01, 0, 0, 0);
      c02 = __builtin_amdgcn_mfma_f64_16x16x4f64(a0, b2, c02, 0, 0, 0);
      c03 = __builtin_amdgcn_mfma_f64_16x16x4f64(a0, b3, c03, 0, 0, 0);
      c10 = __builtin_amdgcn_mfma_f64_16x16x4f64(a1, b0, c10, 0, 0, 0);
      c11 = __builtin_amdgcn_mfma_f64_16x16x4f64(a1, b1, c11, 0, 0, 0);
      c12 = __builtin_amdgcn_mfma_f64_16x16x4f64(a1, b2, c12, 0, 0, 0);
      c13 = __builtin_amdgcn_mfma_f64_16x16x4f64(a1, b3, c13, 0, 0, 0);
    }
    if (more) {
      const int nb = buf ^ 1;
      As[nb][akq + 0][am] = (double)ra.x; As[nb][akq + 1][am] = (double)ra.y;
      As[nb][akq + 2][am] = (double)ra.z; As[nb][akq + 3][am] = (double)ra.w;
      if (!BT) {
        Bs[nb][bk][bn8 + 0] = (double)rb0.x; Bs[nb][bk][bn8 + 1] = (double)rb0.y;
        Bs[nb][bk][bn8 + 2] = (double)rb0.z; Bs[nb][bk][bn8 + 3] = (double)rb0.w;
        Bs[nb][bk][bn8 + 4] = (double)rb1.x; Bs[nb][bk][bn8 + 5] = (double)rb1.y;
        Bs[nb][bk][bn8 + 6] = (double)rb1.z; Bs[nb][bk][bn8 + 7] = (double)rb1.w;
      } else {
        Bs[nb][tkq + 0][tn] = (double)rb0.x; Bs[nb][tkq + 1][tn] = (double)rb0.y;
        Bs[nb][tkq + 2][tn] = (double)rb0.z; Bs[nb][tkq + 3][tn] = (double)rb0.w;
        Bs[nb][tkq + 4][tn] = (double)rb1.x; Bs[nb][tkq + 5][tn] = (double)rb1.y;
        Bs[nb][tkq + 6][tn] = (double)rb1.z; Bs[nb][tkq + 7][tn] = (double)rb1.w;
      }
    }
    __syncthreads();
    buf ^= 1;
  }

#pragma unroll
  for (int i = 0; i < 4; ++i) {
    const size_t r0 = (size_t)(m0 + mr[i]) * N;
    const size_t r1 = r0 + (size_t)16 * N;
    const int c = n0 + nc[i];
    C[r0 + c +  0] = (float)(c00[i] * alpha);
    C[r0 + c + 16] = (float)(c01[i] * alpha);
    C[r0 + c + 32] = (float)(c02[i] * alpha);
    C[r0 + c + 48] = (float)(c03[i] * alpha);
    C[r1 + c +  0] = (float)(c10[i] * alpha);
    C[r1 + c + 16] = (float)(c11[i] * alpha);
    C[r1 + c + 32] = (float)(c12[i] * alpha);
    C[r1 + c + 48] = (float)(c13[i] * alpha);
  }
}

// ---------------------------------------------------------------------------
// Extract bf16 hi plane of I or P (blockIdx.y picks array). One conversion
// per element, done ONCE (r11's screen converted in-loop with ~32x panel
// redundancy -> VALU-bound).
// ---------------------------------------------------------------------------
__global__ void __launch_bounds__(256) split_hi(const float* __restrict__ I,
                                                const float* __restrict__ P,
                                                unsigned short* __restrict__ Ih,
                                                unsigned short* __restrict__ Ph)
{
  const float* src = blockIdx.y ? P : I;
  unsigned short* dst = blockIdx.y ? Ph : Ih;
  const size_t i = ((size_t)blockIdx.x * 256 + threadIdx.x) * 4;
  float4 v = *(const float4*)(src + i);
  ushort4 h;
  h.x = f32_to_bf16_rne(v.x); h.y = f32_to_bf16_rne(v.y);
  h.z = f32_to_bf16_rne(v.z); h.w = f32_to_bf16_rne(v.w);
  *(ushort4*)(dst + i) = h;
}

// ---------------------------------------------------------------------------
// bf16 SCREEN for S: pure single-plane bf16 MFMA GEMM, ushort8 loads from
// pre-split Ih/Ph (no in-loop conversions), LDS dbuf, causal packed 64x128,
// layout probe. Output S stored as bf16 ushort (ranking-only use; rescore
// recomputes exactly). Noise budget: inputs 2^-9 + store 2^-9 -> sigma~3.4e-3
// vs rank-15->24 spacing ~0.21 -> candidate set safe.
// ---------------------------------------------------------------------------
__global__ void __launch_bounds__(256) screen_bf16(
    const unsigned short* __restrict__ Ih, const unsigned short* __restrict__ Ph,
    unsigned short* __restrict__ Ssc)
{
  int rem = blockIdx.x, bi = 0;
  while (rem >= (bi >> 1) + 1) { rem -= (bi >> 1) + 1; ++bi; }
  const int m0 = bi << 6, n0 = rem << 7;
  const int z = blockIdx.z;
  const unsigned short* A = Ih + (size_t)z * T_LEN * D_DIM;
  const unsigned short* B = Ph + (size_t)z * T_LEN * D_DIM;
  unsigned short* C = Ssc + (size_t)z * T_LEN * T_LEN;
  const int N = T_LEN, K = D_DIM;

  const int tid = threadIdx.x;
  const int w = tid >> 6, lane = tid & 63;
  const int kg = lane >> 4, lm = lane & 15;
  const int am0 = (w & 1) << 5;
  const int bn0 = (w >> 1) << 6;

  __shared__ unsigned short As_h[2][64][40];
  __shared__ unsigned short Bs_h[2][128][40];

  bf16x8 ones;
#pragma unroll
  for (int e = 0; e < 8; ++e) ones[e] = (short)0x3F80;

  // layout probe (buf 0)
  for (int idx = tid; idx < 2048; idx += 256)
    As_h[0][idx >> 5][idx & 31] = f32_to_bf16_rne((float)(idx >> 5));
  for (int idx = tid; idx < 4096; idx += 256)
    Bs_h[0][idx >> 5][idx & 31] = f32_to_bf16_rne((float)(idx >> 5));
  __syncthreads();
  int mr[4], nc[4];
  {
    bf16x8 pa = *(const bf16x8*)&As_h[0][am0 + lm][kg << 3];
    bf16x8 pb = *(const bf16x8*)&Bs_h[0][bn0 + lm][kg << 3];
    f32x4v d1 = {0.f, 0.f, 0.f, 0.f}, d2 = {0.f, 0.f, 0.f, 0.f};
    d1 = __builtin_amdgcn_mfma_f32_16x16x32_bf16(pa, ones, d1, 0, 0, 0);
    d2 = __builtin_amdgcn_mfma_f32_16x16x32_bf16(ones, pb, d2, 0, 0, 0);
#pragma unroll
    for (int e = 0; e < 4; ++e) {
      mr[e] = ((int)d1[e]) >> 5;
      nc[e] = ((int)d2[e]) >> 5;
    }
  }
  __syncthreads();

  f32x4v c00 = {0,0,0,0}, c01 = {0,0,0,0}, c02 = {0,0,0,0}, c03 = {0,0,0,0};
  f32x4v c10 = {0,0,0,0}, c11 = {0,0,0,0}, c12 = {0,0,0,0}, c13 = {0,0,0,0};

  const int ar  = tid >> 2, ak8 = (tid & 3) << 3;
  const int bna = tid >> 2, bnb = 64 + (tid >> 2), bk8 = (tid & 3) << 3;

  bf16x8 ra, rb0, rb1;

  ra  = *(const bf16x8*)(A + (size_t)(m0 + ar) * K + ak8);
  rb0 = *(const bf16x8*)(B + (size_t)(n0 + bna) * K + bk8);
  rb1 = *(const bf16x8*)(B + (size_t)(n0 + bnb) * K + bk8);
  *(bf16x8*)&As_h[0][ar][ak8]  = ra;
  *(bf16x8*)&Bs_h[0][bna][bk8] = rb0;
  *(bf16x8*)&Bs_h[0][bnb][bk8] = rb1;
  __syncthreads();

  int buf = 0;
  for (int k0 = 0; k0 < K; k0 += 32) {
    const bool more = (k0 + 32) < K;
    if (more) {
      const int kn = k0 + 32;
      ra  = *(const bf16x8*)(A + (size_t)(m0 + ar) * K + kn + ak8);
      rb0 = *(const bf16x8*)(B + (size_t)(n0 + bna) * K + kn + bk8);
      rb1 = *(const bf16x8*)(B + (size_t)(n0 + bnb) * K + kn + bk8);
    }
    {
      bf16x8 a0 = *(const bf16x8*)&As_h[buf][am0 + lm][kg << 3];
      bf16x8 a1 = *(const bf16x8*)&As_h[buf][am0 + 16 + lm][kg << 3];
      bf16x8 b0 = *(const bf16x8*)&Bs_h[buf][bn0 + lm][kg << 3];
      bf16x8 b1 = *(const bf16x8*)&Bs_h[buf][bn0 + 16 + lm][kg << 3];
      bf16x8 b2 = *(const bf16x8*)&Bs_h[buf][bn0 + 32 + lm][kg << 3];
      bf16x8 b3 = *(const bf16x8*)&Bs_h[buf][bn0 + 48 + lm][kg << 3];
      c00 = __builtin_amdgcn_mfma_f32_16x16x32_bf16(a0, b0, c00, 0, 0, 0);
      c01 = __builtin_amdgcn_mfma_f32_16x16x32_bf16(a0, b1, c01, 0, 0, 0);
      c02 = __builtin_amdgcn_mfma_f32_16x16x32_bf16(a0, b2, c02, 0, 0, 0);
      c03 = __builtin_amdgcn_mfma_f32_16x16x32_bf16(a0, b3, c03, 0, 0, 0);
      c10 = __builtin_amdgcn_mfma_f32_16x16x32_bf16(a1, b0, c10, 0, 0, 0);
      c11 = __builtin_amdgcn_mfma_f32_16x16x32_bf16(a1, b1, c11, 0, 0, 0);
      c12 = __builtin_amdgcn_mfma_f32_16x16x32_bf16(a1, b2, c12, 0, 0, 0);
      c13 = __builtin_amdgcn_mfma_f32_16x16x32_bf16(a1, b3, c13, 0, 0, 0);
    }
    if (more) {
      const int nb = buf ^ 1;
      *(bf16x8*)&As_h[nb][ar][ak8]  = ra;
      *(bf16x8*)&Bs_h[nb][bna][bk8] = rb0;
      *(bf16x8*)&Bs_h[nb][bnb][bk8] = rb1;
    }
    __syncthreads();
    buf ^= 1;
  }

#pragma unroll
  for (int e = 0; e < 4; ++e) {
    const size_t r0 = (size_t)(m0 + mr[e]) * N;
    const size_t r1 = r0 + (size_t)16 * N;
    const int c = n0 + nc[e];
    C[r0 + c +  0] = f32_to_bf16_rne(c00[e]);
    C[r0 + c + 16] = f32_to_bf16_rne(c01[e]);
    C[r0 + c + 32] = f32_to_bf16_rne(c02[e]);
    C[r0 + c + 48] = f32_to_bf16_rne(c03[e]);
    C[r1 + c +  0] = f32_to_bf16_rne(c10[e]);
    C[r1 + c + 16] = f32_to_bf16_rne(c11[e]);
    C[r1 + c + 32] = f32_to_bf16_rne(c12[e]);
    C[r1 + c + 48] = f32_to_bf16_rne(c13[e]);
  }
}

// ---------------------------------------------------------------------------
// Top-NCAND screen candidates per causal row (bf16 S input). -1 = invalid.
// ---------------------------------------------------------------------------
__global__ void __launch_bounds__(256) topk24(const unsigned short* __restrict__ Ssc,
                                              int* __restrict__ cand)
{
  const int b = blockIdx.y;
  const unsigned short* S = Ssc + (size_t)b * T_LEN * T_LEN;
  const int wave = threadIdx.x >> 6, lane = threadIdx.x & 63;
  const int t = blockIdx.x * 4 + wave;
  const unsigned short* rowp = S + (size_t)t * T_LEN;
  float v[32];
#pragma unroll
  for (int i = 0; i < 32; ++i) {
    int s = lane + (i << 6);
    v[i] = (s <= t) ? bf16_to_f32(rowp[s]) : -INFINITY;
  }
  float pv = INFINITY; int pidx = -1;
  int* outp = cand + ((size_t)b * T_LEN + t) * NCAND;
  for (int k = 0; k < NCAND; ++k) {
    float bv = -INFINITY; int bi = 0x7fffffff;
#pragma unroll
    for (int i = 0; i < 32; ++i) {
      int s = lane + (i << 6);
      float vv = v[i];
      bool elig = (vv < pv) || (vv == pv && s > pidx);
      if (elig && vv > bv) { bv = vv; bi = s; }
    }
#pragma unroll
    for (int o = 32; o >= 1; o >>= 1) {
      float ov = __shfl_xor(bv, o);
      int oi = __shfl_xor(bi, o);
      if (ov > bv || (ov == bv && oi < bi)) { bv = ov; bi = oi; }
    }
    pv = bv; pidx = bi;
    if (lane == 0) outp[k] = (bi == 0x7fffffff || bv == -INFINITY) ? -1 : bi;
  }
}

// ---------------------------------------------------------------------------
// Exact rescore: f64 dot of I_t with each candidate P row, rounded to f32
// after the 2^-5 scale (replicates r3-r11 f32-compare semantics, tie ->
// lower index), select top-15 -> idx.
// ---------------------------------------------------------------------------
__global__ void __launch_bounds__(256) rescore_kernel(
    const float* __restrict__ I, const float* __restrict__ P,
    const int* __restrict__ cand, int* __restrict__ idx)
{
  const int row = blockIdx.x;
  const int base = row & ~(T_LEN - 1);
  const int tid = threadIdx.x;
  const int w = tid >> 6, lane = tid & 63;

  __shared__ float valS[NCAND];
  __shared__ int   sidxS[NCAND];
  __shared__ int   candS[NCAND];

  if (tid < NCAND) candS[tid] = cand[(size_t)row * NCAND + tid];
  __syncthreads();

  double iv[16];
  const float* irow = I + (size_t)row * D_DIM;
#pragma unroll
  for (int j = 0; j < 16; ++j) iv[j] = (double)irow[lane + (j << 6)];

  for (int c = w; c < NCAND; c += 4) {
    int s = candS[c];
    double acc = 0.0;
    if (s >= 0) {
      const float* prow = P + ((size_t)base + s) * D_DIM;
#pragma unroll
      for (int j = 0; j < 16; ++j)
        acc = fma(iv[j], (double)prow[lane + (j << 6)], acc);
    }
#pragma unroll
    for (int o = 32; o >= 1; o >>= 1) acc += __shfl_xor(acc, o);
    if (lane == 0) {
      valS[c] = (s >= 0) ? (float)(acc * 0.03125) : -INFINITY;
      sidxS[c] = s;
    }
  }
  __syncthreads();
  if (tid == 0) {
    bool taken[NCAND];
#pragma unroll
    for (int c = 0; c < NCAND; ++c) taken[c] = false;
    int* outp = idx + (size_t)row * 16;
    for (int k = 0; k < KSEL; ++k) {
      float best = -INFINITY; int bidx = 0x7fffffff; int bc = -1;
      for (int c = 0; c < NCAND; ++c) {
        if (taken[c] || sidxS[c] < 0) continue;
        float v = valS[c];
        if (v > best || (v == best && sidxS[c] < bidx)) { best = v; bidx = sidxS[c]; bc = c; }
      }
      if (bc >= 0) { taken[bc] = true; outp[k] = bidx; }
      else outp[k] = 0;
    }
  }
}

// ---------------------------------------------------------------------------
// Split f32 array into bf16 hi/lo planes. (r10, unchanged.)
// ---------------------------------------------------------------------------
__global__ void __launch_bounds__(256) split_bf16(const float* __restrict__ X,
                                                  unsigned short* __restrict__ H,
                                                  unsigned short* __restrict__ L)
{
  const int i = (blockIdx.x * 256 + threadIdx.x) * 4;
  float4 v = *(const float4*)(X + i);
  ushort4 h, l;
  h.x = f32_to_bf16_rne(v.x); l.x = f32_to_bf16_rne(v.x - bf16_to_f32(h.x));
  h.y = f32_to_bf16_rne(v.y); l.y = f32_to_bf16_rne(v.y - bf16_to_f32(h.y));
  h.z = f32_to_bf16_rne(v.z); l.z = f32_to_bf16_rne(v.z - bf16_to_f32(h.z));
  h.w = f32_to_bf16_rne(v.w); l.w = f32_to_bf16_rne(v.w - bf16_to_f32(h.w));
  *(ushort4*)(H + i) = h;
  *(ushort4*)(L + i) = l;
}

// ---------------------------------------------------------------------------
// Wo (K x N) -> transposed bf16 hi/lo planes (N x K). (r10, unchanged.)
// ---------------------------------------------------------------------------
__global__ void __launch_bounds__(256) woconvT(const float* __restrict__ Wo,
                                               unsigned short* __restrict__ HT,
                                               unsigned short* __restrict__ LT)
{
  __shared__ float tile[64][65];
  const int k0 = blockIdx.y << 6, n0 = blockIdx.x << 6;
  const int tid = threadIdx.x;
  for (int idx = tid; idx < 4096; idx += 256) {
    int r = idx >> 6, c = idx & 63;
    tile[r][c] = Wo[(size_t)(k0 + r) * D_DIM + n0 + c];
  }
  __syncthreads();
  for (int idx = tid; idx < 4096; idx += 256) {
    int n = idx >> 6, k = idx & 63;
    float v = tile[k][n];
    unsigned short h = f32_to_bf16_rne(v);
    HT[(size_t)(n0 + n) * D_DIM + k0 + k] = h;
    LT[(size_t)(n0 + n) * D_DIM + k0 + k] = f32_to_bf16_rne(v - bf16_to_f32(h));
  }
}

// ---------------------------------------------------------------------------
// Split-bf16 MFMA GEMM for out = V @ Wo. (r10, unchanged.)
// ---------------------------------------------------------------------------
__global__ void __launch_bounds__(256) gemmbf(
    const unsigned short* __restrict__ Ah, const unsigned short* __restrict__ Al,
    const unsigned short* __restrict__ BhT, const unsigned short* __restrict__ BlT,
    float* __restrict__ C, int N, int K)
{
  const int m0 = blockIdx.y << 6, n0 = blockIdx.x << 7;
  const int tid = threadIdx.x;
  const int w = tid >> 6, lane = tid & 63;
  const int kg = lane >> 4, lm = lane & 15;
  const int am0 = (w & 1) << 5;
  const int bn0 = (w >> 1) << 6;

  __shared__ unsigned short As_h[2][64][40],  As_l[2][64][40];
  __shared__ unsigned short Bs_h[2][128][40], Bs_l[2][128][40];

  bf16x8 ones;
#pragma unroll
  for (int e = 0; e < 8; ++e) ones[e] = (short)0x3F80;

  for (int idx = tid; idx < 2048; idx += 256)
    As_h[0][idx >> 5][idx & 31] = f32_to_bf16_rne((float)(idx >> 5));
  for (int idx = tid; idx < 4096; idx += 256)
    Bs_h[0][idx >> 5][idx & 31] = f32_to_bf16_rne((float)(idx >> 5));
  __syncthreads();
  int mr[4], nc[4];
  {
    bf16x8 pa = *(const bf16x8*)&As_h[0][am0 + lm][kg << 3];
    bf16x8 pb = *(const bf16x8*)&Bs_h[0][bn0 + lm][kg << 3];
    f32x4v d1 = {0.f, 0.f, 0.f, 0.f}, d2 = {0.f, 0.f, 0.f, 0.f};
    d1 = __builtin_amdgcn_mfma_f32_16x16x32_bf16(pa, ones, d1, 0, 0, 0);
    d2 = __builtin_amdgcn_mfma_f32_16x16x32_bf16(ones, pb, d2, 0, 0, 0);
#pragma unroll
    for (int e = 0; e < 4; ++e) {
      mr[e] = ((int)d1[e]) >> 5;
      nc[e] = ((int)d2[e]) >> 5;
    }
  }
  __syncthreads();

  f32x4v c00 = {0,0,0,0}, c01 = {0,0,0,0}, c02 = {0,0,0,0}, c03 = {0,0,0,0};
  f32x4v c10 = {0,0,0,0}, c11 = {0,0,0,0}, c12 = {0,0,0,0}, c13 = {0,0,0,0};

  const int ar  = tid >> 2, ak8 = (tid & 3) << 3;
  const int bna = tid >> 2, bnb = 64 + (tid >> 2), bk8 = (tid & 3) << 3;

  bf16x8 rah, ral, rbh0, rbl0, rbh1, rbl1;

  rah  = *(const bf16x8*)(Ah  + (size_t)(m0 + ar) * K + ak8);
  ral  = *(const bf16x8*)(Al  + (size_t)(m0 + ar) * K + ak8);
  rbh0 = *(const bf16x8*)(BhT + (size_t)(n0 + bna) * K + bk8);
  rbl0 = *(const bf16x8*)(BlT + (size_t)(n0 + bna) * K + bk8);
  rbh1 = *(const bf16x8*)(BhT + (size_t)(n0 + bnb) * K + bk8);
  rbl1 = *(const bf16x8*)(BlT + (size_t)(n0 + bnb) * K + bk8);
  *(bf16x8*)&As_h[0][ar][ak8]  = rah;
  *(bf16x8*)&As_l[0][ar][ak8]  = ral;
  *(bf16x8*)&Bs_h[0][bna][bk8] = rbh0;
  *(bf16x8*)&Bs_l[0][bna][bk8] = rbl0;
  *(bf16x8*)&Bs_h[0][bnb][bk8] = rbh1;
  *(bf16x8*)&Bs_l[0][bnb][bk8] = rbl1;
  __syncthreads();

  int buf = 0;
  for (int k0 = 0; k0 < K; k0 += 32) {
    const bool more = (k0 + 32) < K;
    if (more) {
      const int kn = k0 + 32;
      rah  = *(const bf16x8*)(Ah  + (size_t)(m0 + ar) * K + kn + ak8);
      ral  = *(const bf16x8*)(Al  + (size_t)(m0 + ar) * K + kn + ak8);
      rbh0 = *(const bf16x8*)(BhT + (size_t)(n0 + bna) * K + kn + bk8);
      rbl0 = *(const bf16x8*)(BlT + (size_t)(n0 + bna) * K + kn + bk8);
      rbh1 = *(const bf16x8*)(BhT + (size_t)(n0 + bnb) * K + kn + bk8);
      rbl1 = *(const bf16x8*)(BlT + (size_t)(n0 + bnb) * K + kn + bk8);
    }
    {
      bf16x8 ah0 = *(const bf16x8*)&As_h[buf][am0 + lm][kg << 3];
      bf16x8 ah1 = *(const bf16x8*)&As_h[buf][am0 + 16 + lm][kg << 3];
      bf16x8 al0 = *(const bf16x8*)&As_l[buf][am0 + lm][kg << 3];
      bf16x8 al1 = *(const bf16x8*)&As_l[buf][am0 + 16 + lm][kg << 3];
      bf16x8 bh0 = *(const bf16x8*)&Bs_h[buf][bn0 + lm][kg << 3];
      bf16x8 bh1 = *(const bf16x8*)&Bs_h[buf][bn0 + 16 + lm][kg << 3];
      bf16x8 bh2 = *(const bf16x8*)&Bs_h[buf][bn0 + 32 + lm][kg << 3];
      bf16x8 bh3 = *(const bf16x8*)&Bs_h[buf][bn0 + 48 + lm][kg << 3];
      bf16x8 bl0 = *(const bf16x8*)&Bs_l[buf][bn0 + lm][kg << 3];
      bf16x8 bl1 = *(const bf16x8*)&Bs_l[buf][bn0 + 16 + lm][kg << 3];
      bf16x8 bl2 = *(const bf16x8*)&Bs_l[buf][bn0 + 32 + lm][kg << 3];
      bf16x8 bl3 = *(const bf16x8*)&Bs_l[buf][bn0 + 48 + lm][kg << 3];

      c00 = __builtin_amdgcn_mfma_f32_16x16x32_bf16(ah0, bh0, c00, 0, 0, 0);
      c01 = __builtin_amdgcn_mfma_f32_16x16x32_bf16(ah0, bh1, c01, 0, 0, 0);
      c02 = __builtin_amdgcn_mfma_f32_16x16x32_bf16(ah0, bh2, c02, 0, 0, 0);
      c03 = __builtin_amdgcn_mfma_f32_16x16x32_bf16(ah0, bh3, c03, 0, 0, 0);
      c10 = __builtin_amdgcn_mfma_f32_16x16x32_bf16(ah1, bh0, c10, 0, 0, 0);
      c11 = __builtin_amdgcn_mfma_f32_16x16x32_bf16(ah1, bh1, c11, 0, 0, 0);
      c12 = __builtin_amdgcn_mfma_f32_16x16x32_bf16(ah1, bh2, c12, 0, 0, 0);
      c13 = __builtin_amdgcn_mfma_f32_16x16x32_bf16(ah1, bh3, c13, 0, 0, 0);

      c00 = __builtin_amdgcn_mfma_f32_16x16x32_bf16(ah0, bl0, c00, 0, 0, 0);
      c01 = __builtin_amdgcn_mfma_f32_16x16x32_bf16(ah0, bl1, c01, 0, 0, 0);
      c02 = __builtin_amdgcn_mfma_f32_16x16x32_bf16(ah0, bl2, c02, 0, 0, 0);
      c03 = __builtin_amdgcn_mfma_f32_16x16x32_bf16(ah0, bl3, c03, 0, 0, 0);
      c10 = __builtin_amdgcn_mfma_f32_16x16x32_bf16(ah1, bl0, c10, 0, 0, 0);
      c11 = __builtin_amdgcn_mfma_f32_16x16x32_bf16(ah1, bl1, c11, 0, 0, 0);
      c12 = __builtin_amdgcn_mfma_f32_16x16x32_bf16(ah1, bl2, c12, 0, 0, 0);
      c13 = __builtin_amdgcn_mfma_f32_16x16x32_bf16(ah1, bl3, c13, 0, 0, 0);

      c00 = __builtin_amdgcn_mfma_f32_16x16x32_bf16(al0, bh0, c00, 0, 0, 0);
      c01 = __builtin_amdgcn_mfma_f32_16x16x32_bf16(al0, bh1, c01, 0, 0, 0);
      c02 = __builtin_amdgcn_mfma_f32_16x16x32_bf16(al0, bh2, c02, 0, 0, 0);
      c03 = __builtin_amdgcn_mfma_f32_16x16x32_bf16(al0, bh3, c03, 0, 0, 0);
      c10 = __builtin_amdgcn_mfma_f32_16x16x32_bf16(al1, bh0, c10, 0, 0, 0);
      c11 = __builtin_amdgcn_mfma_f32_16x16x32_bf16(al1, bh1, c11, 0, 0, 0);
      c12 = __builtin_amdgcn_mfma_f32_16x16x32_bf16(al1, bh2, c12, 0, 0, 0);
      c13 = __builtin_amdgcn_mfma_f32_16x16x32_bf16(al1, bh3, c13, 0, 0, 0);
    }
    if (more) {
      const int nb = buf ^ 1;
      *(bf16x8*)&As_h[nb][ar][ak8]  = rah;
      *(bf16x8*)&As_l[nb][ar][ak8]  = ral;
      *(bf16x8*)&Bs_h[nb][bna][bk8] = rbh0;
      *(bf16x8*)&Bs_l[nb][bna][bk8] = rbl0;
      *(bf16x8*)&Bs_h[nb][bnb][bk8] = rbh1;
      *(bf16x8*)&Bs_l[nb][bnb][bk8] = rbl1;
    }
    __syncthreads();
    buf ^= 1;
  }

#pragma unroll
  for (int e = 0; e < 4; ++e) {
    const size_t r0 = (size_t)(m0 + mr[e]) * N;
    const size_t r1 = r0 + (size_t)16 * N;
    const int c = n0 + nc[e];
    C[r0 + c +  0] = c00[e];
    C[r0 + c + 16] = c01[e];
    C[r0 + c + 32] = c02[e];
    C[r0 + c + 48] = c03[e];
    C[r1 + c +  0] = c10[e];
    C[r1 + c + 16] = c11[e];
    C[r1 + c + 32] = c12[e];
    C[r1 + c + 48] = c13[e];
  }
}

// ---------------------------------------------------------------------------
// Trig table: EXACT reference f32 bits. DO NOT change — selection-critical.
// ---------------------------------------------------------------------------
__global__ void __launch_bounds__(256) trig_table_kernel(float2* __restrict__ tab)
{
  const int t = blockIdx.x;
  for (int j = threadIdx.x; j < 512; j += 256) {
    double e = (double)j * (1.0 / 512.0);
    float pf = (float)pow(10000.0, e);
    float invf = 1.0f / pf;
    float angf = (float)t * invf;
    double s64, c64;
    sincos((double)angf, &s64, &c64);
    tab[(size_t)t * 512 + j] = make_float2((float)c64, (float)s64);
  }
}

// ---------------------------------------------------------------------------
// RoPE in place + row L2 norms. DO NOT change — selection-critical.
// ---------------------------------------------------------------------------
__global__ void __launch_bounds__(256) rope_norm_kernel(float* __restrict__ bI,
                                                        float* __restrict__ bP,
                                                        const float2* __restrict__ tab,
                                                        float* __restrict__ nI,
                                                        float* __restrict__ nP)
{
  const int row = blockIdx.x;
  const int t = row & (T_LEN - 1);
  const int tid = threadIdx.x;
  __shared__ double redI[4], redP[4];
  double ssI = 0.0, ssP = 0.0;
  const size_t off = (size_t)row * D_DIM;
  for (int j = tid; j < 512; j += 256) {
    float2 cs = tab[(size_t)t * 512 + j];
    float c = cs.x, s = cs.y;

    float a1 = bI[off + j], a2 = bI[off + 512 + j];
    float o1 = __fsub_rn(__fmul_rn(a1, c), __fmul_rn(a2, s));
    float o2 = __fadd_rn(__fmul_rn(a1, s), __fmul_rn(a2, c));
    bI[off + j] = o1; bI[off + 512 + j] = o2;
    ssI += (double)o1 * o1 + (double)o2 * o2;

    float p1 = bP[off + j], p2 = bP[off + 512 + j];
    float q1 = __fsub_rn(__fmul_rn(p1, c), __fmul_rn(p2, s));
    float q2 = __fadd_rn(__fmul_rn(p1, s), __fmul_rn(p2, c));
    bP[off + j] = q1; bP[off + 512 + j] = q2;
    ssP += (double)q1 * q1 + (double)q2 * q2;
  }
#pragma unroll
  for (int o = 32; o >= 1; o >>= 1) { ssI += __shfl_xor(ssI, o); ssP += __shfl_xor(ssP, o); }
  if ((tid & 63) == 0) { redI[tid >> 6] = ssI; redP[tid >> 6] = ssP; }
  __syncthreads();
  if (tid == 0) {
    nI[row] = fmaxf((float)sqrt(redI[0] + redI[1] + redI[2] + redI[3]), 1e-12f);
    nP[row] = fmaxf((float)sqrt(redP[0] + redP[1] + redP[2] + redP[3]), 1e-12f);
  }
}

// ---------------------------------------------------------------------------
// palette (D x 256) -> palT (256 x D)
// ---------------------------------------------------------------------------
__global__ void transpose_pal(const float* __restrict__ pal, float* __restrict__ palT)
{
  int c = blockIdx.x;
  int d = blockIdx.y * 256 + threadIdx.x;
  palT[(size_t)c * D_DIM + d] = pal[(size_t)d * 256 + c];
}

// ---------------------------------------------------------------------------
// Per-(b,t): gather + normalized gram + rel features + MLP + heads + softmax
// + bilinear palette blend -> V[b,t,:]. (unchanged)
// ---------------------------------------------------------------------------
__global__ void __launch_bounds__(256) relmlp_kernel(
    const float* __restrict__ I, const float* __restrict__ P,
    const float* __restrict__ nI, const float* __restrict__ nP,
    const int* __restrict__ topk,
    const float* __restrict__ W1, const float* __restrict__ b1,
    const float* __restrict__ W2, const float* __restrict__ b2,
    const float* __restrict__ Wc, const float* __restrict__ bc,
    const float* __restrict__ Wm, const float* __restrict__ bm,
    const float* __restrict__ palT, float* __restrict__ V)
{
  const int row = blockIdx.x;
  const int t = row & (T_LEN - 1);
  const int base = row & ~(T_LEN - 1);
  const int nk = (t + 1 < KSEL) ? (t + 1) : KSEL;
  const int tid = threadIdx.x;

  __shared__ float vecS[16][516];
  __shared__ float gS[16][16];
  __shared__ float relS[KSEL][17];
  __shared__ float h1S[KSEL][HIDN];
  __shared__ float h2S[KSEL][HIDN];
  __shared__ float nrmS[16];
  __shared__ int   sidxS[16];
  __shared__ float mixS[KSEL], wS[KSEL], zxS[KSEL], zyS[KSEL];
  __shared__ float coefS[4 * KSEL];
  __shared__ int   cellS[4 * KSEL];

  if (tid < 16) {
    int s = t;
    if (tid >= 1) s = (tid <= nk) ? topk[(size_t)row * 16 + (tid - 1)] : 0;
    sidxS[tid] = s;
    nrmS[tid] = (tid == 0) ? nI[row] : nP[base + s];
  }
  __syncthreads();

  const int r = tid >> 4, c0 = tid & 15;
  const float* srcrow = (r == 0) ? (I + (size_t)row * D_DIM)
                                 : (P + ((size_t)base + sidxS[r]) * D_DIM);

  int pi = 0, pj = 0;
  {
    int p = tid;
    if (p < 136) {
      int i = 0;
      while (p >= 16 - i) { p -= 16 - i; ++i; }
      pi = i; pj = i + p;
    }
  }
  const bool pairOn = (tid < 136) && (pi <= nk) && (pj <= nk);
  float4 acc4 = make_float4(0.f, 0.f, 0.f, 0.f);

  for (int half = 0; half < 2; ++half) {
    if (half) __syncthreads();
    if (r <= nk) {
#pragma unroll
      for (int rep = 0; rep < 8; ++rep) {
        int q = c0 + 16 * rep;
        float4 v4 = *(const float4*)(srcrow + half * 512 + (q << 2));
        *(float4*)&vecS[r][q << 2] = v4;
      }
    }
    __syncthreads();
    if (pairOn) {
      const float4* va = (const float4*)&vecS[pi][0];
      const float4* vb = (const float4*)&vecS[pj][0];
#pragma unroll 4
      for (int q = 0; q < 128; ++q) {
        float4 a4 = va[q], b4 = vb[q];
        acc4.x = fmaf(a4.x, b4.x, acc4.x);
        acc4.y = fmaf(a4.y, b4.y, acc4.y);
        acc4.z = fmaf(a4.z, b4.z, acc4.z);
        acc4.w = fmaf(a4.w, b4.w, acc4.w);
      }
    }
  }
  if (tid < 136) {
    float g = 0.f;
    if (pairOn) {
      float acc = (acc4.x + acc4.y) + (acc4.z + acc4.w);
      g = acc / (nrmS[pi] * nrmS[pj]);
      g = fminf(fmaxf(g, -1.f), 1.f);
    }
    gS[pi][pj] = g;
    gS[pj][pi] = g;
  }
  __syncthreads();

  if (tid < KSEL * 17) {
    int k = tid / 17, f = tid % 17;
    float v = 0.f;
    if (k < nk) {
      if (f < KSEL)        v = (f < nk) ? gS[k + 1][f + 1] : 0.f;
      else if (f == KSEL)  v = gS[0][k + 1];
      else                 v = (float)(t - sidxS[k + 1]) * (1.0f / (float)T_LEN);
    }
    relS[k][f] = v;
  }
  __syncthreads();

  for (int o = tid; o < KSEL * HIDN; o += 256) {
    int k = o >> 6, m = o & 63;
    float a = b1[m];
#pragma unroll
    for (int f = 0; f < 17; ++f) a = fmaf(relS[k][f], W1[f * HIDN + m], a);
    h1S[k][m] = geluf(a);
  }
  __syncthreads();
  for (int o = tid; o < KSEL * HIDN; o += 256) {
    int k = o >> 6, m = o & 63;
    float a = b2[m];
#pragma unroll 8
    for (int n = 0; n < HIDN; ++n) a = fmaf(h1S[k][n], W2[n * HIDN + m], a);
    h2S[k][m] = geluf(a);
  }
  __syncthreads();
  if (tid < KSEL) {
    float a0 = 0.f, a1 = 0.f, am = 0.f;
#pragma unroll 8
    for (int n = 0; n < HIDN; ++n) {
      float h = h2S[tid][n];
      a0 = fmaf(h, Wc[n * 2 + 0], a0);
      a1 = fmaf(h, Wc[n * 2 + 1], a1);
      am = fmaf(h, Wm[n], am);
    }
    zxS[tid] = tanhf(a0 + bc[0]);
    zyS[tid] = tanhf(a1 + bc[1]);
    mixS[tid] = am + bm[0];
  }
  __syncthreads();
  if (tid == 0) {
    float mx = -INFINITY;
    for (int k = 0; k < nk; ++k) mx = fmaxf(mx, mixS[k]);
    float ssum = 0.f;
    for (int k = 0; k < nk; ++k) { float e = expf(mixS[k] - mx); wS[k] = e; ssum += e; }
    float inv = 1.f / ssum;
    for (int k = 0; k < nk; ++k) wS[k] *= inv;
  }
  __syncthreads();
  if (tid < KSEL) {
    int k = tid;
    if (k < nk) {
      float w = wS[k];
      float fx = fminf(fmaxf((zxS[k] + 1.f) * 0.5f * 15.f, 0.f), 15.f);
      float fy = fminf(fmaxf((zyS[k] + 1.f) * 0.5f * 15.f, 0.f), 15.f);
      int x0 = (int)floorf(fx); int x1i = (x0 + 1 < 15) ? x0 + 1 : 15;
      int y0 = (int)floorf(fy); int y1i = (y0 + 1 < 15) ? y0 + 1 : 15;
      float wx = fx - (float)x0, wy = fy - (float)y0;
      cellS[k * 4 + 0] = y0 * 16 + x0;   coefS[k * 4 + 0] = w * (1.f - wy) * (1.f - wx);
      cellS[k * 4 + 1] = y0 * 16 + x1i;  coefS[k * 4 + 1] = w * (1.f - wy) * wx;
      cellS[k * 4 + 2] = y1i * 16 + x0;  coefS[k * 4 + 2] = w * wy * (1.f - wx);
      cellS[k * 4 + 3] = y1i * 16 + x1i; coefS[k * 4 + 3] = w * wy * wx;
    } else {
      cellS[k * 4 + 0] = cellS[k * 4 + 1] = cellS[k * 4 + 2] = cellS[k * 4 + 3] = 0;
      coefS[k * 4 + 0] = coefS[k * 4 + 1] = coefS[k * 4 + 2] = coefS[k * 4 + 3] = 0.f;
    }
  }
  __syncthreads();
  const int nj = 4 * nk;
  for (int d = tid; d < D_DIM; d += 256) {
    float a = 0.f;
    for (int j = 0; j < nj; ++j)
      a = fmaf(coefS[j], palT[(size_t)cellS[j] * D_DIM + d], a);
    V[(size_t)row * D_DIM + d] = a;
  }
}

// ---------------------------------------------------------------------------
// Host launcher. Sb region (32MB) reuse timeline:
//   [0,8MB) tab -> consumed by rope;
//   [0,16MB) Ssc (bf16 screen S) -> consumed by topk24;
//   [16,24MB) Ih, [24,32MB) Ph -> written post-rope, consumed by screen;
//   [0,16MB) Vb (f32 V) post-topk; [16,24MB) Vh, [24,32MB) Vl post-relmlp.
// P region hosts Wo bf16 planes after relmlp (P dead).
// ---------------------------------------------------------------------------
extern "C" void kernel_launch(void* const* d_in, const int* in_sizes, int n_in,
                              void* d_out, int out_size, void* d_ws, size_t ws_size,
                              hipStream_t stream)
{
  (void)in_sizes; (void)n_in; (void)out_size; (void)ws_size;
  const float* x   = (const float*)d_in[0];
  const float* Wi  = (const float*)d_in[1];
  const float* Wp  = (const float*)d_in[2];
  const float* pal = (const float*)d_in[3];
  const float* W1  = (const float*)d_in[4];
  const float* b1  = (const float*)d_in[5];
  const float* W2  = (const float*)d_in[6];
  const float* b2  = (const float*)d_in[7];
  const float* Wc  = (const float*)d_in[8];
  const float* bc  = (const float*)d_in[9];
  const float* Wm  = (const float*)d_in[10];
  const float* bm  = (const float*)d_in[11];
  const float* Wo  = (const float*)d_in[12];
  float* out = (float*)d_out;

  float* w = (float*)d_ws;
  float* palT = w;  w += (size_t)256 * D_DIM;
  float* I    = w;  w += (size_t)BATCH * T_LEN * D_DIM;
  float* P    = w;  w += (size_t)BATCH * T_LEN * D_DIM;
  float* Sb   = w;  w += (size_t)BATCH * T_LEN * T_LEN;
  float* nIb  = w;  w += (size_t)BATCH * T_LEN;
  float* nPb  = w;  w += (size_t)BATCH * T_LEN;
  int*   idx  = (int*)w;  w += (size_t)BATCH * T_LEN * 16;
  int*   cand = (int*)w;

  float2* tab = (float2*)Sb;
  unsigned short* Ssc = (unsigned short*)Sb;                              // 16MB
  unsigned short* Ih  = (unsigned short*)(Sb + (size_t)4 * 1024 * 1024);  // +16MB
  unsigned short* Ph  = Ih + (size_t)4 * 1024 * 1024;                     // +24MB
  float*  Vb = Sb;
  unsigned short* Vh = (unsigned short*)(Sb + (size_t)4 * 1024 * 1024);
  unsigned short* Vl = Vh + (size_t)4 * 1024 * 1024;
  unsigned short* WohT = (unsigned short*)P;
  unsigned short* WolT = WohT + (size_t)D_DIM * D_DIM;

  const int MROWS = BATCH * T_LEN;  // 4096

  trig_table_kernel<<<T_LEN, 256, 0, stream>>>(tab);
  transpose_pal<<<dim3(256, 4), 256, 0, stream>>>(pal, palT);

  // I = x@Wi (z=0), P = x@Wp (z=1): f64 MFMA (selection-critical values).
  gemm64q<false, false><<<dim3(D_DIM / 128, MROWS / 64, 2), 256, 0, stream>>>(
      x, Wi, Wp, I, D_DIM, D_DIM,
      0L, 0L, (long)MROWS * D_DIM, 1.0);

  rope_norm_kernel<<<MROWS, 256, 0, stream>>>(I, P, tab, nIb, nPb);

  // bf16 hi planes of I,P (once), then pure-bf16 screen GEMM.
  split_hi<<<dim3((MROWS * D_DIM) / (256 * 4), 2), 256, 0, stream>>>(I, P, Ih, Ph);
  screen_bf16<<<dim3(272, 1, 2), 256, 0, stream>>>(Ih, Ph, Ssc);

  topk24<<<dim3(T_LEN / 4, BATCH), 256, 0, stream>>>(Ssc, cand);
  rescore_kernel<<<MROWS, 256, 0, stream>>>(I, P, cand, idx);

  relmlp_kernel<<<MROWS, 256, 0, stream>>>(I, P, nIb, nPb, idx,
                                           W1, b1, W2, b2, Wc, bc, Wm, bm,
                                           palT, Vb);

  // V @ Wo via split-bf16 MFMA (r10)
  split_bf16<<<(MROWS * D_DIM) / (256 * 4), 256, 0, stream>>>(Vb, Vh, Vl);
  woconvT<<<dim3(D_DIM / 64, D_DIM / 64), 256, 0, stream>>>(Wo, WohT, WolT);
  gemmbf<<<dim3(D_DIM / 128, MROWS / 64), 256, 0, stream>>>(
      Vh, Vl, WohT, WolT, out, D_DIM, D_DIM);
}

// Round 13
// 725.665 us; speedup vs baseline: 1.0682x; 1.0682x over previous
//
#include <hip/hip_runtime.h>
#include <math.h>

// Problem constants (fixed by the reference)
#define BATCH 2
#define T_LEN 2048
#define D_DIM 1024
#define KSEL  15
#define HIDN  64
#define NCAND 20

typedef double f64x4 __attribute__((ext_vector_type(4)));
typedef short  bf16x8 __attribute__((ext_vector_type(8)));
typedef float  f32x4v __attribute__((ext_vector_type(4)));

__device__ __forceinline__ float geluf(float x) {
  return 0.5f * x * (1.0f + erff(x * 0.70710678118654752440f));
}

__device__ __forceinline__ unsigned short f32_to_bf16_rne(float x) {
  unsigned u = __builtin_bit_cast(unsigned, x);
  unsigned lsb = (u >> 16) & 1u;
  u += 0x7fffu + lsb;
  return (unsigned short)(u >> 16);
}
__device__ __forceinline__ float bf16_to_f32(unsigned short h) {
  unsigned u = ((unsigned)h) << 16;
  return __builtin_bit_cast(float, u);
}

// ---------------------------------------------------------------------------
// f64 MFMA GEMM (f32 in / f32 out), v_mfma_f64_16x16x4_f64, LAYOUT-PROBED,
// 64x128 tile + LDS double-buffer + reg prefetch. (r9-r12, unchanged.)
// Used ONLY for x@Wi / x@Wp (selection-critical values).
// ---------------------------------------------------------------------------
template<bool BT>
__global__ void __launch_bounds__(256, 3) gemm64q(
    const float* __restrict__ A, const float* __restrict__ Ba,
    const float* __restrict__ Bb, float* __restrict__ C,
    int N, int K, long sA, long sB, long sC, double alpha)
{
  const int m0 = blockIdx.y << 6, n0 = blockIdx.x << 7;
  const int z = blockIdx.z;
  A += (size_t)z * sA;
  const float* B = (z ? Bb : Ba) + (size_t)z * sB;
  C += (size_t)z * sC;

  const int tid = threadIdx.x;
  const int w = tid >> 6, lane = tid & 63;
  const int kl = lane >> 4, lm = lane & 15;
  const int am0 = (w & 1) << 5;
  const int bn0 = (w >> 1) << 6;

  __shared__ double As[2][16][66];
  __shared__ double Bs[2][16][130];

  // layout probe (buf 0)
  {
    int m = tid & 63, k4 = (tid >> 6) << 2;
#pragma unroll
    for (int q = 0; q < 4; ++q) As[0][k4 + q][m] = (double)m;
    int n = tid & 127, k8 = (tid >> 7) << 3;
#pragma unroll
    for (int q = 0; q < 8; ++q) Bs[0][k8 + q][n] = (double)n;
  }
  __syncthreads();
  int mr[4], nc[4];
  {
    double pa = As[0][kl][am0 + lm];
    double pb = Bs[0][kl][bn0 + lm];
    f64x4 d1 = {0.0, 0.0, 0.0, 0.0}, d2 = {0.0, 0.0, 0.0, 0.0};
    d1 = __builtin_amdgcn_mfma_f64_16x16x4f64(pa, 1.0, d1, 0, 0, 0);
    d2 = __builtin_amdgcn_mfma_f64_16x16x4f64(1.0, pb, d2, 0, 0, 0);
#pragma unroll
    for (int i = 0; i < 4; ++i) {
      mr[i] = ((int)d1[i]) >> 2;
      nc[i] = ((int)d2[i]) >> 2;
    }
  }
  __syncthreads();

  f64x4 c00 = {0,0,0,0}, c01 = {0,0,0,0}, c02 = {0,0,0,0}, c03 = {0,0,0,0};
  f64x4 c10 = {0,0,0,0}, c11 = {0,0,0,0}, c12 = {0,0,0,0}, c13 = {0,0,0,0};

  const int am = tid >> 2, akq = (tid & 3) << 2;
  const int bk = tid >> 4, bn8 = (tid & 15) << 3;
  const int tn = tid >> 1, tkq = (tid & 1) << 3;

  float4 ra, rb0, rb1;

  ra = *(const float4*)(A + (size_t)(m0 + am) * K + akq);
  if (!BT) {
    const float* bp = B + (size_t)bk * N + n0 + bn8;
    rb0 = *(const float4*)(bp); rb1 = *(const float4*)(bp + 4);
  } else {
    const float* bp = B + (size_t)(n0 + tn) * K + tkq;
    rb0 = *(const float4*)(bp); rb1 = *(const float4*)(bp + 4);
  }
  {
    As[0][akq + 0][am] = (double)ra.x; As[0][akq + 1][am] = (double)ra.y;
    As[0][akq + 2][am] = (double)ra.z; As[0][akq + 3][am] = (double)ra.w;
    if (!BT) {
      Bs[0][bk][bn8 + 0] = (double)rb0.x; Bs[0][bk][bn8 + 1] = (double)rb0.y;
      Bs[0][bk][bn8 + 2] = (double)rb0.z; Bs[0][bk][bn8 + 3] = (double)rb0.w;
      Bs[0][bk][bn8 + 4] = (double)rb1.x; Bs[0][bk][bn8 + 5] = (double)rb1.y;
      Bs[0][bk][bn8 + 6] = (double)rb1.z; Bs[0][bk][bn8 + 7] = (double)rb1.w;
    } else {
      Bs[0][tkq + 0][tn] = (double)rb0.x; Bs[0][tkq + 1][tn] = (double)rb0.y;
      Bs[0][tkq + 2][tn] = (double)rb0.z; Bs[0][tkq + 3][tn] = (double)rb0.w;
      Bs[0][tkq + 4][tn] = (double)rb1.x; Bs[0][tkq + 5][tn] = (double)rb1.y;
      Bs[0][tkq + 6][tn] = (double)rb1.z; Bs[0][tkq + 7][tn] = (double)rb1.w;
    }
  }
  __syncthreads();

  int buf = 0;
  for (int k0 = 0; k0 < K; k0 += 16) {
    const bool more = (k0 + 16) < K;
    if (more) {
      const int kn = k0 + 16;
      ra = *(const float4*)(A + (size_t)(m0 + am) * K + kn + akq);
      if (!BT) {
        const float* bp = B + (size_t)(kn + bk) * N + n0 + bn8;
        rb0 = *(const float4*)(bp); rb1 = *(const float4*)(bp + 4);
      } else {
        const float* bp = B + (size_t)(n0 + tn) * K + kn + tkq;
        rb0 = *(const float4*)(bp); rb1 = *(const float4*)(bp + 4);
      }
    }
#pragma unroll
    for (int ks = 0; ks < 4; ++ks) {
      const int kr = (ks << 2) + kl;
      double a0 = As[buf][kr][am0 + lm];
      double a1 = As[buf][kr][am0 + 16 + lm];
      double b0 = Bs[buf][kr][bn0 + lm];
      double b1 = Bs[buf][kr][bn0 + 16 + lm];
      double b2 = Bs[buf][kr][bn0 + 32 + lm];
      double b3 = Bs[buf][kr][bn0 + 48 + lm];
      c00 = __builtin_amdgcn_mfma_f64_16x16x4f64(a0, b0, c00, 0, 0, 0);
      c01 = __builtin_amdgcn_mfma_f64_16x16x4f64(a0, b1, c01, 0, 0, 0);
      c02 = __builtin_amdgcn_mfma_f64_16x16x4f64(a0, b2, c02, 0, 0, 0);
      c03 = __builtin_amdgcn_mfma_f64_16x16x4f64(a0, b3, c03, 0, 0, 0);
      c10 = __builtin_amdgcn_mfma_f64_16x16x4f64(a1, b0, c10, 0, 0, 0);
      c11 = __builtin_amdgcn_mfma_f64_16x16x4f64(a1, b1, c11, 0, 0, 0);
      c12 = __builtin_amdgcn_mfma_f64_16x16x4f64(a1, b2, c12, 0, 0, 0);
      c13 = __builtin_amdgcn_mfma_f64_16x16x4f64(a1, b3, c13, 0, 0, 0);
    }
    if (more) {
      const int nb = buf ^ 1;
      As[nb][akq + 0][am] = (double)ra.x; As[nb][akq + 1][am] = (double)ra.y;
      As[nb][akq + 2][am] = (double)ra.z; As[nb][akq + 3][am] = (double)ra.w;
      if (!BT) {
        Bs[nb][bk][bn8 + 0] = (double)rb0.x; Bs[nb][bk][bn8 + 1] = (double)rb0.y;
        Bs[nb][bk][bn8 + 2] = (double)rb0.z; Bs[nb][bk][bn8 + 3] = (double)rb0.w;
        Bs[nb][bk][bn8 + 4] = (double)rb1.x; Bs[nb][bk][bn8 + 5] = (double)rb1.y;
        Bs[nb][bk][bn8 + 6] = (double)rb1.z; Bs[nb][bk][bn8 + 7] = (double)rb1.w;
      } else {
        Bs[nb][tkq + 0][tn] = (double)rb0.x; Bs[nb][tkq + 1][tn] = (double)rb0.y;
        Bs[nb][tkq + 2][tn] = (double)rb0.z; Bs[nb][tkq + 3][tn] = (double)rb0.w;
        Bs[nb][tkq + 4][tn] = (double)rb1.x; Bs[nb][tkq + 5][tn] = (double)rb1.y;
        Bs[nb][tkq + 6][tn] = (double)rb1.z; Bs[nb][tkq + 7][tn] = (double)rb1.w;
      }
    }
    __syncthreads();
    buf ^= 1;
  }

#pragma unroll
  for (int i = 0; i < 4; ++i) {
    const size_t r0 = (size_t)(m0 + mr[i]) * N;
    const size_t r1 = r0 + (size_t)16 * N;
    const int c = n0 + nc[i];
    C[r0 + c +  0] = (float)(c00[i] * alpha);
    C[r0 + c + 16] = (float)(c01[i] * alpha);
    C[r0 + c + 32] = (float)(c02[i] * alpha);
    C[r0 + c + 48] = (float)(c03[i] * alpha);
    C[r1 + c +  0] = (float)(c10[i] * alpha);
    C[r1 + c + 16] = (float)(c11[i] * alpha);
    C[r1 + c + 32] = (float)(c12[i] * alpha);
    C[r1 + c + 48] = (float)(c13[i] * alpha);
  }
}

// ---------------------------------------------------------------------------
// PREP (fused): blocks [0,T_LEN) build the trig table (EXACT reference f32
// bits — selection-critical, do not change the math); blocks [T_LEN, T_LEN
// +1024) transpose the palette.
// ---------------------------------------------------------------------------
__global__ void __launch_bounds__(256) prep_kernel(float2* __restrict__ tab,
                                                   const float* __restrict__ pal,
                                                   float* __restrict__ palT)
{
  const int b = blockIdx.x;
  if (b < T_LEN) {
    const int t = b;
    for (int j = threadIdx.x; j < 512; j += 256) {
      double e = (double)j * (1.0 / 512.0);
      float pf = (float)pow(10000.0, e);
      float invf = 1.0f / pf;
      float angf = (float)t * invf;
      double s64, c64;
      sincos((double)angf, &s64, &c64);
      tab[(size_t)t * 512 + j] = make_float2((float)c64, (float)s64);
    }
  } else {
    const int bb = b - T_LEN;
    const int c = bb & 255, dg = bb >> 8;
    const int d = dg * 256 + threadIdx.x;
    palT[(size_t)c * D_DIM + d] = pal[(size_t)d * 256 + c];
  }
}

// ---------------------------------------------------------------------------
// RoPE in place + row L2 norms + bf16 hi planes Ih/Ph (fused emit).
// f32 rotation math unchanged — selection-critical.
// ---------------------------------------------------------------------------
__global__ void __launch_bounds__(256) rope_norm_kernel(
    float* __restrict__ bI, float* __restrict__ bP,
    const float2* __restrict__ tab,
    float* __restrict__ nI, float* __restrict__ nP,
    unsigned short* __restrict__ Ih, unsigned short* __restrict__ Ph)
{
  const int row = blockIdx.x;
  const int t = row & (T_LEN - 1);
  const int tid = threadIdx.x;
  __shared__ double redI[4], redP[4];
  double ssI = 0.0, ssP = 0.0;
  const size_t off = (size_t)row * D_DIM;
  for (int j = tid; j < 512; j += 256) {
    float2 cs = tab[(size_t)t * 512 + j];
    float c = cs.x, s = cs.y;

    float a1 = bI[off + j], a2 = bI[off + 512 + j];
    float o1 = __fsub_rn(__fmul_rn(a1, c), __fmul_rn(a2, s));
    float o2 = __fadd_rn(__fmul_rn(a1, s), __fmul_rn(a2, c));
    bI[off + j] = o1; bI[off + 512 + j] = o2;
    Ih[off + j] = f32_to_bf16_rne(o1); Ih[off + 512 + j] = f32_to_bf16_rne(o2);
    ssI += (double)o1 * o1 + (double)o2 * o2;

    float p1 = bP[off + j], p2 = bP[off + 512 + j];
    float q1 = __fsub_rn(__fmul_rn(p1, c), __fmul_rn(p2, s));
    float q2 = __fadd_rn(__fmul_rn(p1, s), __fmul_rn(p2, c));
    bP[off + j] = q1; bP[off + 512 + j] = q2;
    Ph[off + j] = f32_to_bf16_rne(q1); Ph[off + 512 + j] = f32_to_bf16_rne(q2);
    ssP += (double)q1 * q1 + (double)q2 * q2;
  }
#pragma unroll
  for (int o = 32; o >= 1; o >>= 1) { ssI += __shfl_xor(ssI, o); ssP += __shfl_xor(ssP, o); }
  if ((tid & 63) == 0) { redI[tid >> 6] = ssI; redP[tid >> 6] = ssP; }
  __syncthreads();
  if (tid == 0) {
    nI[row] = fmaxf((float)sqrt(redI[0] + redI[1] + redI[2] + redI[3]), 1e-12f);
    nP[row] = fmaxf((float)sqrt(redP[0] + redP[1] + redP[2] + redP[3]), 1e-12f);
  }
}

// ---------------------------------------------------------------------------
// bf16 SCREEN for S (candidates only; exact rescore follows). (r12, unchanged.)
// ---------------------------------------------------------------------------
__global__ void __launch_bounds__(256) screen_bf16(
    const unsigned short* __restrict__ Ih, const unsigned short* __restrict__ Ph,
    unsigned short* __restrict__ Ssc)
{
  int rem = blockIdx.x, bi = 0;
  while (rem >= (bi >> 1) + 1) { rem -= (bi >> 1) + 1; ++bi; }
  const int m0 = bi << 6, n0 = rem << 7;
  const int z = blockIdx.z;
  const unsigned short* A = Ih + (size_t)z * T_LEN * D_DIM;
  const unsigned short* B = Ph + (size_t)z * T_LEN * D_DIM;
  unsigned short* C = Ssc + (size_t)z * T_LEN * T_LEN;
  const int N = T_LEN, K = D_DIM;

  const int tid = threadIdx.x;
  const int w = tid >> 6, lane = tid & 63;
  const int kg = lane >> 4, lm = lane & 15;
  const int am0 = (w & 1) << 5;
  const int bn0 = (w >> 1) << 6;

  __shared__ unsigned short As_h[2][64][40];
  __shared__ unsigned short Bs_h[2][128][40];

  bf16x8 ones;
#pragma unroll
  for (int e = 0; e < 8; ++e) ones[e] = (short)0x3F80;

  for (int idx = tid; idx < 2048; idx += 256)
    As_h[0][idx >> 5][idx & 31] = f32_to_bf16_rne((float)(idx >> 5));
  for (int idx = tid; idx < 4096; idx += 256)
    Bs_h[0][idx >> 5][idx & 31] = f32_to_bf16_rne((float)(idx >> 5));
  __syncthreads();
  int mr[4], nc[4];
  {
    bf16x8 pa = *(const bf16x8*)&As_h[0][am0 + lm][kg << 3];
    bf16x8 pb = *(const bf16x8*)&Bs_h[0][bn0 + lm][kg << 3];
    f32x4v d1 = {0.f, 0.f, 0.f, 0.f}, d2 = {0.f, 0.f, 0.f, 0.f};
    d1 = __builtin_amdgcn_mfma_f32_16x16x32_bf16(pa, ones, d1, 0, 0, 0);
    d2 = __builtin_amdgcn_mfma_f32_16x16x32_bf16(ones, pb, d2, 0, 0, 0);
#pragma unroll
    for (int e = 0; e < 4; ++e) {
      mr[e] = ((int)d1[e]) >> 5;
      nc[e] = ((int)d2[e]) >> 5;
    }
  }
  __syncthreads();

  f32x4v c00 = {0,0,0,0}, c01 = {0,0,0,0}, c02 = {0,0,0,0}, c03 = {0,0,0,0};
  f32x4v c10 = {0,0,0,0}, c11 = {0,0,0,0}, c12 = {0,0,0,0}, c13 = {0,0,0,0};

  const int ar  = tid >> 2, ak8 = (tid & 3) << 3;
  const int bna = tid >> 2, bnb = 64 + (tid >> 2), bk8 = (tid & 3) << 3;

  bf16x8 ra, rb0, rb1;

  ra  = *(const bf16x8*)(A + (size_t)(m0 + ar) * K + ak8);
  rb0 = *(const bf16x8*)(B + (size_t)(n0 + bna) * K + bk8);
  rb1 = *(const bf16x8*)(B + (size_t)(n0 + bnb) * K + bk8);
  *(bf16x8*)&As_h[0][ar][ak8]  = ra;
  *(bf16x8*)&Bs_h[0][bna][bk8] = rb0;
  *(bf16x8*)&Bs_h[0][bnb][bk8] = rb1;
  __syncthreads();

  int buf = 0;
  for (int k0 = 0; k0 < K; k0 += 32) {
    const bool more = (k0 + 32) < K;
    if (more) {
      const int kn = k0 + 32;
      ra  = *(const bf16x8*)(A + (size_t)(m0 + ar) * K + kn + ak8);
      rb0 = *(const bf16x8*)(B + (size_t)(n0 + bna) * K + kn + bk8);
      rb1 = *(const bf16x8*)(B + (size_t)(n0 + bnb) * K + kn + bk8);
    }
    {
      bf16x8 a0 = *(const bf16x8*)&As_h[buf][am0 + lm][kg << 3];
      bf16x8 a1 = *(const bf16x8*)&As_h[buf][am0 + 16 + lm][kg << 3];
      bf16x8 b0 = *(const bf16x8*)&Bs_h[buf][bn0 + lm][kg << 3];
      bf16x8 b1 = *(const bf16x8*)&Bs_h[buf][bn0 + 16 + lm][kg << 3];
      bf16x8 b2 = *(const bf16x8*)&Bs_h[buf][bn0 + 32 + lm][kg << 3];
      bf16x8 b3 = *(const bf16x8*)&Bs_h[buf][bn0 + 48 + lm][kg << 3];
      c00 = __builtin_amdgcn_mfma_f32_16x16x32_bf16(a0, b0, c00, 0, 0, 0);
      c01 = __builtin_amdgcn_mfma_f32_16x16x32_bf16(a0, b1, c01, 0, 0, 0);
      c02 = __builtin_amdgcn_mfma_f32_16x16x32_bf16(a0, b2, c02, 0, 0, 0);
      c03 = __builtin_amdgcn_mfma_f32_16x16x32_bf16(a0, b3, c03, 0, 0, 0);
      c10 = __builtin_amdgcn_mfma_f32_16x16x32_bf16(a1, b0, c10, 0, 0, 0);
      c11 = __builtin_amdgcn_mfma_f32_16x16x32_bf16(a1, b1, c11, 0, 0, 0);
      c12 = __builtin_amdgcn_mfma_f32_16x16x32_bf16(a1, b2, c12, 0, 0, 0);
      c13 = __builtin_amdgcn_mfma_f32_16x16x32_bf16(a1, b3, c13, 0, 0, 0);
    }
    if (more) {
      const int nb = buf ^ 1;
      *(bf16x8*)&As_h[nb][ar][ak8]  = ra;
      *(bf16x8*)&Bs_h[nb][bna][bk8] = rb0;
      *(bf16x8*)&Bs_h[nb][bnb][bk8] = rb1;
    }
    __syncthreads();
    buf ^= 1;
  }

#pragma unroll
  for (int e = 0; e < 4; ++e) {
    const size_t r0 = (size_t)(m0 + mr[e]) * N;
    const size_t r1 = r0 + (size_t)16 * N;
    const int c = n0 + nc[e];
    C[r0 + c +  0] = f32_to_bf16_rne(c00[e]);
    C[r0 + c + 16] = f32_to_bf16_rne(c01[e]);
    C[r0 + c + 32] = f32_to_bf16_rne(c02[e]);
    C[r0 + c + 48] = f32_to_bf16_rne(c03[e]);
    C[r1 + c +  0] = f32_to_bf16_rne(c10[e]);
    C[r1 + c + 16] = f32_to_bf16_rne(c11[e]);
    C[r1 + c + 32] = f32_to_bf16_rne(c12[e]);
    C[r1 + c + 48] = f32_to_bf16_rne(c13[e]);
  }
}

// ---------------------------------------------------------------------------
// Top-NCAND screen candidates per causal row (bf16 S). -1 = invalid.
// ---------------------------------------------------------------------------
__global__ void __launch_bounds__(256) topk_screen(const unsigned short* __restrict__ Ssc,
                                                   int* __restrict__ cand)
{
  const int b = blockIdx.y;
  const unsigned short* S = Ssc + (size_t)b * T_LEN * T_LEN;
  const int wave = threadIdx.x >> 6, lane = threadIdx.x & 63;
  const int t = blockIdx.x * 4 + wave;
  const unsigned short* rowp = S + (size_t)t * T_LEN;
  float v[32];
#pragma unroll
  for (int i = 0; i < 32; ++i) {
    int s = lane + (i << 6);
    v[i] = (s <= t) ? bf16_to_f32(rowp[s]) : -INFINITY;
  }
  float pv = INFINITY; int pidx = -1;
  int* outp = cand + ((size_t)b * T_LEN + t) * NCAND;
  for (int k = 0; k < NCAND; ++k) {
    float bv = -INFINITY; int bi = 0x7fffffff;
#pragma unroll
    for (int i = 0; i < 32; ++i) {
      int s = lane + (i << 6);
      float vv = v[i];
      bool elig = (vv < pv) || (vv == pv && s > pidx);
      if (elig && vv > bv) { bv = vv; bi = s; }
    }
#pragma unroll
    for (int o = 32; o >= 1; o >>= 1) {
      float ov = __shfl_xor(bv, o);
      int oi = __shfl_xor(bi, o);
      if (ov > bv || (ov == bv && oi < bi)) { bv = ov; bi = oi; }
    }
    pv = bv; pidx = bi;
    if (lane == 0) outp[k] = (bi == 0x7fffffff || bv == -INFINITY) ? -1 : bi;
  }
}

// ---------------------------------------------------------------------------
// Exact rescore: f64 dot of I_t with each candidate P row (f32 arrays),
// rounded to f32 after the 2^-5 scale (replicates the established f32-compare
// semantics, tie -> lower index), top-15 -> idx.
// ---------------------------------------------------------------------------
__global__ void __launch_bounds__(256) rescore_kernel(
    const float* __restrict__ I, const float* __restrict__ P,
    const int* __restrict__ cand, int* __restrict__ idx)
{
  const int row = blockIdx.x;
  const int base = row & ~(T_LEN - 1);
  const int tid = threadIdx.x;
  const int w = tid >> 6, lane = tid & 63;

  __shared__ float valS[NCAND];
  __shared__ int   sidxS[NCAND];
  __shared__ int   candS[NCAND];

  if (tid < NCAND) candS[tid] = cand[(size_t)row * NCAND + tid];
  __syncthreads();

  double iv[16];
  const float* irow = I + (size_t)row * D_DIM;
#pragma unroll
  for (int j = 0; j < 16; ++j) iv[j] = (double)irow[lane + (j << 6)];

  for (int c = w; c < NCAND; c += 4) {
    int s = candS[c];
    double acc = 0.0;
    if (s >= 0) {
      const float* prow = P + ((size_t)base + s) * D_DIM;
#pragma unroll
      for (int j = 0; j < 16; ++j)
        acc = fma(iv[j], (double)prow[lane + (j << 6)], acc);
    }
#pragma unroll
    for (int o = 32; o >= 1; o >>= 1) acc += __shfl_xor(acc, o);
    if (lane == 0) {
      valS[c] = (s >= 0) ? (float)(acc * 0.03125) : -INFINITY;
      sidxS[c] = s;
    }
  }
  __syncthreads();
  if (tid == 0) {
    bool taken[NCAND];
#pragma unroll
    for (int c = 0; c < NCAND; ++c) taken[c] = false;
    int* outp = idx + (size_t)row * 16;
    for (int k = 0; k < KSEL; ++k) {
      float best = -INFINITY; int bidx = 0x7fffffff; int bc = -1;
      for (int c = 0; c < NCAND; ++c) {
        if (taken[c] || sidxS[c] < 0) continue;
        float v = valS[c];
        if (v > best || (v == best && sidxS[c] < bidx)) { best = v; bidx = sidxS[c]; bc = c; }
      }
      if (bc >= 0) { taken[bc] = true; outp[k] = bidx; }
      else outp[k] = 0;
    }
  }
}

// ---------------------------------------------------------------------------
// Wo (K x N) -> transposed bf16 hi/lo planes (N x K). Runs after rescore
// (writes into the dead P region).
// ---------------------------------------------------------------------------
__global__ void __launch_bounds__(256) woconvT(const float* __restrict__ Wo,
                                               unsigned short* __restrict__ HT,
                                               unsigned short* __restrict__ LT)
{
  __shared__ float tile[64][65];
  const int k0 = blockIdx.y << 6, n0 = blockIdx.x << 6;
  const int tid = threadIdx.x;
  for (int idx = tid; idx < 4096; idx += 256) {
    int r = idx >> 6, c = idx & 63;
    tile[r][c] = Wo[(size_t)(k0 + r) * D_DIM + n0 + c];
  }
  __syncthreads();
  for (int idx = tid; idx < 4096; idx += 256) {
    int n = idx >> 6, k = idx & 63;
    float v = tile[k][n];
    unsigned short h = f32_to_bf16_rne(v);
    HT[(size_t)(n0 + n) * D_DIM + k0 + k] = h;
    LT[(size_t)(n0 + n) * D_DIM + k0 + k] = f32_to_bf16_rne(v - bf16_to_f32(h));
  }
}

// ---------------------------------------------------------------------------
// Per-(b,t): gather (bf16 Ih/Ph, converted once at LDS staging) + normalized
// gram + rel features + MLP + heads + softmax + bilinear palette blend.
// Writes V directly as bf16 hi/lo planes (no f32 V materialization).
// Gram from bf16 vectors adds ~1e-4 smooth-path noise (bilinear interp is
// continuous across floor boundaries -> no discrete risk).
// ---------------------------------------------------------------------------
__global__ void __launch_bounds__(256) relmlp_kernel(
    const unsigned short* __restrict__ Ih, const unsigned short* __restrict__ Ph,
    const float* __restrict__ nI, const float* __restrict__ nP,
    const int* __restrict__ topk,
    const float* __restrict__ W1, const float* __restrict__ b1,
    const float* __restrict__ W2, const float* __restrict__ b2,
    const float* __restrict__ Wc, const float* __restrict__ bc,
    const float* __restrict__ Wm, const float* __restrict__ bm,
    const float* __restrict__ palT,
    unsigned short* __restrict__ Vh, unsigned short* __restrict__ Vl)
{
  const int row = blockIdx.x;
  const int t = row & (T_LEN - 1);
  const int base = row & ~(T_LEN - 1);
  const int nk = (t + 1 < KSEL) ? (t + 1) : KSEL;
  const int tid = threadIdx.x;

  __shared__ float vecS[16][516];
  __shared__ float gS[16][16];
  __shared__ float relS[KSEL][17];
  __shared__ float h1S[KSEL][HIDN];
  __shared__ float h2S[KSEL][HIDN];
  __shared__ float nrmS[16];
  __shared__ int   sidxS[16];
  __shared__ float mixS[KSEL], wS[KSEL], zxS[KSEL], zyS[KSEL];
  __shared__ float coefS[4 * KSEL];
  __shared__ int   cellS[4 * KSEL];

  if (tid < 16) {
    int s = t;
    if (tid >= 1) s = (tid <= nk) ? topk[(size_t)row * 16 + (tid - 1)] : 0;
    sidxS[tid] = s;
    nrmS[tid] = (tid == 0) ? nI[row] : nP[base + s];
  }
  __syncthreads();

  const int r = tid >> 4, c0 = tid & 15;
  const unsigned short* srcrow = (r == 0)
      ? (Ih + (size_t)row * D_DIM)
      : (Ph + ((size_t)base + sidxS[r]) * D_DIM);

  int pi = 0, pj = 0;
  {
    int p = tid;
    if (p < 136) {
      int i = 0;
      while (p >= 16 - i) { p -= 16 - i; ++i; }
      pi = i; pj = i + p;
    }
  }
  const bool pairOn = (tid < 136) && (pi <= nk) && (pj <= nk);
  float4 acc4 = make_float4(0.f, 0.f, 0.f, 0.f);

  for (int half = 0; half < 2; ++half) {
    if (half) __syncthreads();
    if (r <= nk) {
      // 512 bf16 per half per row; 16 threads/row -> 4x ushort8 each,
      // converted to f32 ONCE at staging.
#pragma unroll
      for (int rep = 0; rep < 4; ++rep) {
        int q = c0 + 16 * rep;            // ushort8 chunk in [0,64)
        bf16x8 v8 = *(const bf16x8*)(srcrow + half * 512 + (q << 3));
        float4 f0, f1;
        f0.x = bf16_to_f32((unsigned short)v8[0]);
        f0.y = bf16_to_f32((unsigned short)v8[1]);
        f0.z = bf16_to_f32((unsigned short)v8[2]);
        f0.w = bf16_to_f32((unsigned short)v8[3]);
        f1.x = bf16_to_f32((unsigned short)v8[4]);
        f1.y = bf16_to_f32((unsigned short)v8[5]);
        f1.z = bf16_to_f32((unsigned short)v8[6]);
        f1.w = bf16_to_f32((unsigned short)v8[7]);
        *(float4*)&vecS[r][(q << 3)]     = f0;
        *(float4*)&vecS[r][(q << 3) + 4] = f1;
      }
    }
    __syncthreads();
    if (pairOn) {
      const float4* va = (const float4*)&vecS[pi][0];
      const float4* vb = (const float4*)&vecS[pj][0];
#pragma unroll 4
      for (int q = 0; q < 128; ++q) {
        float4 a4 = va[q], b4 = vb[q];
        acc4.x = fmaf(a4.x, b4.x, acc4.x);
        acc4.y = fmaf(a4.y, b4.y, acc4.y);
        acc4.z = fmaf(a4.z, b4.z, acc4.z);
        acc4.w = fmaf(a4.w, b4.w, acc4.w);
      }
    }
  }
  if (tid < 136) {
    float g = 0.f;
    if (pairOn) {
      float acc = (acc4.x + acc4.y) + (acc4.z + acc4.w);
      g = acc / (nrmS[pi] * nrmS[pj]);
      g = fminf(fmaxf(g, -1.f), 1.f);
    }
    gS[pi][pj] = g;
    gS[pj][pi] = g;
  }
  __syncthreads();

  if (tid < KSEL * 17) {
    int k = tid / 17, f = tid % 17;
    float v = 0.f;
    if (k < nk) {
      if (f < KSEL)        v = (f < nk) ? gS[k + 1][f + 1] : 0.f;
      else if (f == KSEL)  v = gS[0][k + 1];
      else                 v = (float)(t - sidxS[k + 1]) * (1.0f / (float)T_LEN);
    }
    relS[k][f] = v;
  }
  __syncthreads();

  for (int o = tid; o < KSEL * HIDN; o += 256) {
    int k = o >> 6, m = o & 63;
    float a = b1[m];
#pragma unroll
    for (int f = 0; f < 17; ++f) a = fmaf(relS[k][f], W1[f * HIDN + m], a);
    h1S[k][m] = geluf(a);
  }
  __syncthreads();
  for (int o = tid; o < KSEL * HIDN; o += 256) {
    int k = o >> 6, m = o & 63;
    float a = b2[m];
#pragma unroll 8
    for (int n = 0; n < HIDN; ++n) a = fmaf(h1S[k][n], W2[n * HIDN + m], a);
    h2S[k][m] = geluf(a);
  }
  __syncthreads();
  if (tid < KSEL) {
    float a0 = 0.f, a1 = 0.f, am = 0.f;
#pragma unroll 8
    for (int n = 0; n < HIDN; ++n) {
      float h = h2S[tid][n];
      a0 = fmaf(h, Wc[n * 2 + 0], a0);
      a1 = fmaf(h, Wc[n * 2 + 1], a1);
      am = fmaf(h, Wm[n], am);
    }
    zxS[tid] = tanhf(a0 + bc[0]);
    zyS[tid] = tanhf(a1 + bc[1]);
    mixS[tid] = am + bm[0];
  }
  __syncthreads();
  if (tid == 0) {
    float mx = -INFINITY;
    for (int k = 0; k < nk; ++k) mx = fmaxf(mx, mixS[k]);
    float ssum = 0.f;
    for (int k = 0; k < nk; ++k) { float e = expf(mixS[k] - mx); wS[k] = e; ssum += e; }
    float inv = 1.f / ssum;
    for (int k = 0; k < nk; ++k) wS[k] *= inv;
  }
  __syncthreads();
  if (tid < KSEL) {
    int k = tid;
    if (k < nk) {
      float w = wS[k];
      float fx = fminf(fmaxf((zxS[k] + 1.f) * 0.5f * 15.f, 0.f), 15.f);
      float fy = fminf(fmaxf((zyS[k] + 1.f) * 0.5f * 15.f, 0.f), 15.f);
      int x0 = (int)floorf(fx); int x1i = (x0 + 1 < 15) ? x0 + 1 : 15;
      int y0 = (int)floorf(fy); int y1i = (y0 + 1 < 15) ? y0 + 1 : 15;
      float wx = fx - (float)x0, wy = fy - (float)y0;
      cellS[k * 4 + 0] = y0 * 16 + x0;   coefS[k * 4 + 0] = w * (1.f - wy) * (1.f - wx);
      cellS[k * 4 + 1] = y0 * 16 + x1i;  coefS[k * 4 + 1] = w * (1.f - wy) * wx;
      cellS[k * 4 + 2] = y1i * 16 + x0;  coefS[k * 4 + 2] = w * wy * (1.f - wx);
      cellS[k * 4 + 3] = y1i * 16 + x1i; coefS[k * 4 + 3] = w * wy * wx;
    } else {
      cellS[k * 4 + 0] = cellS[k * 4 + 1] = cellS[k * 4 + 2] = cellS[k * 4 + 3] = 0;
      coefS[k * 4 + 0] = coefS[k * 4 + 1] = coefS[k * 4 + 2] = coefS[k * 4 + 3] = 0.f;
    }
  }
  __syncthreads();
  const int nj = 4 * nk;
  for (int d = tid; d < D_DIM; d += 256) {
    float a = 0.f;
    for (int j = 0; j < nj; ++j)
      a = fmaf(coefS[j], palT[(size_t)cellS[j] * D_DIM + d], a);
    unsigned short h = f32_to_bf16_rne(a);
    Vh[(size_t)row * D_DIM + d] = h;
    Vl[(size_t)row * D_DIM + d] = f32_to_bf16_rne(a - bf16_to_f32(h));
  }
}

// ---------------------------------------------------------------------------
// Split-bf16 MFMA GEMM for out = V @ Wo. (r10, unchanged.)
// ---------------------------------------------------------------------------
__global__ void __launch_bounds__(256) gemmbf(
    const unsigned short* __restrict__ Ah, const unsigned short* __restrict__ Al,
    const unsigned short* __restrict__ BhT, const unsigned short* __restrict__ BlT,
    float* __restrict__ C, int N, int K)
{
  const int m0 = blockIdx.y << 6, n0 = blockIdx.x << 7;
  const int tid = threadIdx.x;
  const int w = tid >> 6, lane = tid & 63;
  const int kg = lane >> 4, lm = lane & 15;
  const int am0 = (w & 1) << 5;
  const int bn0 = (w >> 1) << 6;

  __shared__ unsigned short As_h[2][64][40],  As_l[2][64][40];
  __shared__ unsigned short Bs_h[2][128][40], Bs_l[2][128][40];

  bf16x8 ones;
#pragma unroll
  for (int e = 0; e < 8; ++e) ones[e] = (short)0x3F80;

  for (int idx = tid; idx < 2048; idx += 256)
    As_h[0][idx >> 5][idx & 31] = f32_to_bf16_rne((float)(idx >> 5));
  for (int idx = tid; idx < 4096; idx += 256)
    Bs_h[0][idx >> 5][idx & 31] = f32_to_bf16_rne((float)(idx >> 5));
  __syncthreads();
  int mr[4], nc[4];
  {
    bf16x8 pa = *(const bf16x8*)&As_h[0][am0 + lm][kg << 3];
    bf16x8 pb = *(const bf16x8*)&Bs_h[0][bn0 + lm][kg << 3];
    f32x4v d1 = {0.f, 0.f, 0.f, 0.f}, d2 = {0.f, 0.f, 0.f, 0.f};
    d1 = __builtin_amdgcn_mfma_f32_16x16x32_bf16(pa, ones, d1, 0, 0, 0);
    d2 = __builtin_amdgcn_mfma_f32_16x16x32_bf16(ones, pb, d2, 0, 0, 0);
#pragma unroll
    for (int e = 0; e < 4; ++e) {
      mr[e] = ((int)d1[e]) >> 5;
      nc[e] = ((int)d2[e]) >> 5;
    }
  }
  __syncthreads();

  f32x4v c00 = {0,0,0,0}, c01 = {0,0,0,0}, c02 = {0,0,0,0}, c03 = {0,0,0,0};
  f32x4v c10 = {0,0,0,0}, c11 = {0,0,0,0}, c12 = {0,0,0,0}, c13 = {0,0,0,0};

  const int ar  = tid >> 2, ak8 = (tid & 3) << 3;
  const int bna = tid >> 2, bnb = 64 + (tid >> 2), bk8 = (tid & 3) << 3;

  bf16x8 rah, ral, rbh0, rbl0, rbh1, rbl1;

  rah  = *(const bf16x8*)(Ah  + (size_t)(m0 + ar) * K + ak8);
  ral  = *(const bf16x8*)(Al  + (size_t)(m0 + ar) * K + ak8);
  rbh0 = *(const bf16x8*)(BhT + (size_t)(n0 + bna) * K + bk8);
  rbl0 = *(const bf16x8*)(BlT + (size_t)(n0 + bna) * K + bk8);
  rbh1 = *(const bf16x8*)(BhT + (size_t)(n0 + bnb) * K + bk8);
  rbl1 = *(const bf16x8*)(BlT + (size_t)(n0 + bnb) * K + bk8);
  *(bf16x8*)&As_h[0][ar][ak8]  = rah;
  *(bf16x8*)&As_l[0][ar][ak8]  = ral;
  *(bf16x8*)&Bs_h[0][bna][bk8] = rbh0;
  *(bf16x8*)&Bs_l[0][bna][bk8] = rbl0;
  *(bf16x8*)&Bs_h[0][bnb][bk8] = rbh1;
  *(bf16x8*)&Bs_l[0][bnb][bk8] = rbl1;
  __syncthreads();

  int buf = 0;
  for (int k0 = 0; k0 < K; k0 += 32) {
    const bool more = (k0 + 32) < K;
    if (more) {
      const int kn = k0 + 32;
      rah  = *(const bf16x8*)(Ah  + (size_t)(m0 + ar) * K + kn + ak8);
      ral  = *(const bf16x8*)(Al  + (size_t)(m0 + ar) * K + kn + ak8);
      rbh0 = *(const bf16x8*)(BhT + (size_t)(n0 + bna) * K + kn + bk8);
      rbl0 = *(const bf16x8*)(BlT + (size_t)(n0 + bna) * K + kn + bk8);
      rbh1 = *(const bf16x8*)(BhT + (size_t)(n0 + bnb) * K + kn + bk8);
      rbl1 = *(const bf16x8*)(BlT + (size_t)(n0 + bnb) * K + kn + bk8);
    }
    {
      bf16x8 ah0 = *(const bf16x8*)&As_h[buf][am0 + lm][kg << 3];
      bf16x8 ah1 = *(const bf16x8*)&As_h[buf][am0 + 16 + lm][kg << 3];
      bf16x8 al0 = *(const bf16x8*)&As_l[buf][am0 + lm][kg << 3];
      bf16x8 al1 = *(const bf16x8*)&As_l[buf][am0 + 16 + lm][kg << 3];
      bf16x8 bh0 = *(const bf16x8*)&Bs_h[buf][bn0 + lm][kg << 3];
      bf16x8 bh1 = *(const bf16x8*)&Bs_h[buf][bn0 + 16 + lm][kg << 3];
      bf16x8 bh2 = *(const bf16x8*)&Bs_h[buf][bn0 + 32 + lm][kg << 3];
      bf16x8 bh3 = *(const bf16x8*)&Bs_h[buf][bn0 + 48 + lm][kg << 3];
      bf16x8 bl0 = *(const bf16x8*)&Bs_l[buf][bn0 + lm][kg << 3];
      bf16x8 bl1 = *(const bf16x8*)&Bs_l[buf][bn0 + 16 + lm][kg << 3];
      bf16x8 bl2 = *(const bf16x8*)&Bs_l[buf][bn0 + 32 + lm][kg << 3];
      bf16x8 bl3 = *(const bf16x8*)&Bs_l[buf][bn0 + 48 + lm][kg << 3];

      c00 = __builtin_amdgcn_mfma_f32_16x16x32_bf16(ah0, bh0, c00, 0, 0, 0);
      c01 = __builtin_amdgcn_mfma_f32_16x16x32_bf16(ah0, bh1, c01, 0, 0, 0);
      c02 = __builtin_amdgcn_mfma_f32_16x16x32_bf16(ah0, bh2, c02, 0, 0, 0);
      c03 = __builtin_amdgcn_mfma_f32_16x16x32_bf16(ah0, bh3, c03, 0, 0, 0);
      c10 = __builtin_amdgcn_mfma_f32_16x16x32_bf16(ah1, bh0, c10, 0, 0, 0);
      c11 = __builtin_amdgcn_mfma_f32_16x16x32_bf16(ah1, bh1, c11, 0, 0, 0);
      c12 = __builtin_amdgcn_mfma_f32_16x16x32_bf16(ah1, bh2, c12, 0, 0, 0);
      c13 = __builtin_amdgcn_mfma_f32_16x16x32_bf16(ah1, bh3, c13, 0, 0, 0);

      c00 = __builtin_amdgcn_mfma_f32_16x16x32_bf16(ah0, bl0, c00, 0, 0, 0);
      c01 = __builtin_amdgcn_mfma_f32_16x16x32_bf16(ah0, bl1, c01, 0, 0, 0);
      c02 = __builtin_amdgcn_mfma_f32_16x16x32_bf16(ah0, bl2, c02, 0, 0, 0);
      c03 = __builtin_amdgcn_mfma_f32_16x16x32_bf16(ah0, bl3, c03, 0, 0, 0);
      c10 = __builtin_amdgcn_mfma_f32_16x16x32_bf16(ah1, bl0, c10, 0, 0, 0);
      c11 = __builtin_amdgcn_mfma_f32_16x16x32_bf16(ah1, bl1, c11, 0, 0, 0);
      c12 = __builtin_amdgcn_mfma_f32_16x16x32_bf16(ah1, bl2, c12, 0, 0, 0);
      c13 = __builtin_amdgcn_mfma_f32_16x16x32_bf16(ah1, bl3, c13, 0, 0, 0);

      c00 = __builtin_amdgcn_mfma_f32_16x16x32_bf16(al0, bh0, c00, 0, 0, 0);
      c01 = __builtin_amdgcn_mfma_f32_16x16x32_bf16(al0, bh1, c01, 0, 0, 0);
      c02 = __builtin_amdgcn_mfma_f32_16x16x32_bf16(al0, bh2, c02, 0, 0, 0);
      c03 = __builtin_amdgcn_mfma_f32_16x16x32_bf16(al0, bh3, c03, 0, 0, 0);
      c10 = __builtin_amdgcn_mfma_f32_16x16x32_bf16(al1, bh0, c10, 0, 0, 0);
      c11 = __builtin_amdgcn_mfma_f32_16x16x32_bf16(al1, bh1, c11, 0, 0, 0);
      c12 = __builtin_amdgcn_mfma_f32_16x16x32_bf16(al1, bh2, c12, 0, 0, 0);
      c13 = __builtin_amdgcn_mfma_f32_16x16x32_bf16(al1, bh3, c13, 0, 0, 0);
    }
    if (more) {
      const int nb = buf ^ 1;
      *(bf16x8*)&As_h[nb][ar][ak8]  = rah;
      *(bf16x8*)&As_l[nb][ar][ak8]  = ral;
      *(bf16x8*)&Bs_h[nb][bna][bk8] = rbh0;
      *(bf16x8*)&Bs_l[nb][bna][bk8] = rbl0;
      *(bf16x8*)&Bs_h[nb][bnb][bk8] = rbh1;
      *(bf16x8*)&Bs_l[nb][bnb][bk8] = rbl1;
    }
    __syncthreads();
    buf ^= 1;
  }

#pragma unroll
  for (int e = 0; e < 4; ++e) {
    const size_t r0 = (size_t)(m0 + mr[e]) * N;
    const size_t r1 = r0 + (size_t)16 * N;
    const int c = n0 + nc[e];
    C[r0 + c +  0] = c00[e];
    C[r0 + c + 16] = c01[e];
    C[r0 + c + 32] = c02[e];
    C[r0 + c + 48] = c03[e];
    C[r1 + c +  0] = c10[e];
    C[r1 + c + 16] = c11[e];
    C[r1 + c + 32] = c12[e];
    C[r1 + c + 48] = c13[e];
  }
}

// ---------------------------------------------------------------------------
// Host launcher. 9 launches (was 13). Sb region (32MB) timeline:
//   [0,8MB)   tab (prep)            -> dead after rope
//   [16,24MB) Ih, [24,32MB) Ph (rope) -> dead after relmlp
//   [0,16MB)  Ssc bf16 S (screen)   -> dead after topk
//   [0,8MB)   Vh, [8,16MB) Vl (relmlp) -> consumed by gemmbf
// P region hosts WohT/WolT after rescore (P dead; relmlp uses Ph).
// ---------------------------------------------------------------------------
extern "C" void kernel_launch(void* const* d_in, const int* in_sizes, int n_in,
                              void* d_out, int out_size, void* d_ws, size_t ws_size,
                              hipStream_t stream)
{
  (void)in_sizes; (void)n_in; (void)out_size; (void)ws_size;
  const float* x   = (const float*)d_in[0];
  const float* Wi  = (const float*)d_in[1];
  const float* Wp  = (const float*)d_in[2];
  const float* pal = (const float*)d_in[3];
  const float* W1  = (const float*)d_in[4];
  const float* b1  = (const float*)d_in[5];
  const float* W2  = (const float*)d_in[6];
  const float* b2  = (const float*)d_in[7];
  const float* Wc  = (const float*)d_in[8];
  const float* bc  = (const float*)d_in[9];
  const float* Wm  = (const float*)d_in[10];
  const float* bm  = (const float*)d_in[11];
  const float* Wo  = (const float*)d_in[12];
  float* out = (float*)d_out;

  float* w = (float*)d_ws;
  float* palT = w;  w += (size_t)256 * D_DIM;
  float* I    = w;  w += (size_t)BATCH * T_LEN * D_DIM;
  float* P    = w;  w += (size_t)BATCH * T_LEN * D_DIM;
  float* Sb   = w;  w += (size_t)BATCH * T_LEN * T_LEN;
  float* nIb  = w;  w += (size_t)BATCH * T_LEN;
  float* nPb  = w;  w += (size_t)BATCH * T_LEN;
  int*   idx  = (int*)w;  w += (size_t)BATCH * T_LEN * 16;
  int*   cand = (int*)w;

  float2* tab = (float2*)Sb;
  unsigned short* Ssc = (unsigned short*)Sb;                              // [0,16MB)
  unsigned short* Ih  = (unsigned short*)(Sb + (size_t)4 * 1024 * 1024);  // [16,24MB)
  unsigned short* Ph  = Ih + (size_t)4 * 1024 * 1024;                     // [24,32MB)
  unsigned short* Vh  = (unsigned short*)Sb;                              // [0,8MB)
  unsigned short* Vl  = Vh + (size_t)4 * 1024 * 1024;                     // [8,16MB)
  unsigned short* WohT = (unsigned short*)P;
  unsigned short* WolT = WohT + (size_t)D_DIM * D_DIM;

  const int MROWS = BATCH * T_LEN;  // 4096

  // 1. prep: trig table + palette transpose (fused)
  prep_kernel<<<T_LEN + 1024, 256, 0, stream>>>(tab, pal, palT);

  // 2. I = x@Wi (z=0), P = x@Wp (z=1): f64 MFMA (selection-critical values).
  gemm64q<false><<<dim3(D_DIM / 128, MROWS / 64, 2), 256, 0, stream>>>(
      x, Wi, Wp, I, D_DIM, D_DIM,
      0L, 0L, (long)MROWS * D_DIM, 1.0);

  // 3. rope (+ bf16 hi-plane emit)
  rope_norm_kernel<<<MROWS, 256, 0, stream>>>(I, P, tab, nIb, nPb, Ih, Ph);

  // 4. bf16 screen GEMM -> Ssc
  screen_bf16<<<dim3(272, 1, 2), 256, 0, stream>>>(Ih, Ph, Ssc);

  // 5. top-NCAND candidates
  topk_screen<<<dim3(T_LEN / 4, BATCH), 256, 0, stream>>>(Ssc, cand);

  // 6. exact f64 rescore -> top-15 indices
  rescore_kernel<<<MROWS, 256, 0, stream>>>(I, P, cand, idx);

  // 7. Wo -> transposed bf16 planes (P dead now)
  woconvT<<<dim3(D_DIM / 64, D_DIM / 64), 256, 0, stream>>>(Wo, WohT, WolT);

  // 8. relmlp (bf16 gram inputs; writes Vh/Vl directly)
  relmlp_kernel<<<MROWS, 256, 0, stream>>>(Ih, Ph, nIb, nPb, idx,
                                           W1, b1, W2, b2, Wc, bc, Wm, bm,
                                           palT, Vh, Vl);

  // 9. out = V @ Wo via split-bf16 MFMA
  gemmbf<<<dim3(D_DIM / 128, MROWS / 64), 256, 0, stream>>>(
      Vh, Vl, WohT, WolT, out, D_DIM, D_DIM);
}

// Round 14
// 570.701 us; speedup vs baseline: 1.3583x; 1.2715x over previous
//
#include <hip/hip_runtime.h>
#include <math.h>

// Problem constants (fixed by the reference)
#define BATCH 2
#define T_LEN 2048
#define D_DIM 1024
#define KSEL  15
#define HIDN  64
#define NCAND 20

typedef short  bf16x8 __attribute__((ext_vector_type(8)));
typedef float  f32x4v __attribute__((ext_vector_type(4)));

__device__ __forceinline__ float geluf(float x) {
  return 0.5f * x * (1.0f + erff(x * 0.70710678118654752440f));
}

__device__ __forceinline__ unsigned short f32_to_bf16_rne(float x) {
  unsigned u = __builtin_bit_cast(unsigned, x);
  unsigned lsb = (u >> 16) & 1u;
  u += 0x7fffu + lsb;
  return (unsigned short)(u >> 16);
}
__device__ __forceinline__ float bf16_to_f32(unsigned short h) {
  unsigned u = ((unsigned)h) << 16;
  return __builtin_bit_cast(float, u);
}

// ---------------------------------------------------------------------------
// x -> 3 bf16 planes (h, m, l): x ~= h + m + l to ~2^-27 relative.
// ---------------------------------------------------------------------------
__global__ void __launch_bounds__(256) xsplit3(const float* __restrict__ X,
                                               unsigned short* __restrict__ H,
                                               unsigned short* __restrict__ M,
                                               unsigned short* __restrict__ L)
{
  const size_t i = ((size_t)blockIdx.x * 256 + threadIdx.x) * 4;
  float4 v = *(const float4*)(X + i);
  ushort4 h, m, l;
  float r;
  h.x = f32_to_bf16_rne(v.x); r = v.x - bf16_to_f32(h.x);
  m.x = f32_to_bf16_rne(r);   l.x = f32_to_bf16_rne(r - bf16_to_f32(m.x));
  h.y = f32_to_bf16_rne(v.y); r = v.y - bf16_to_f32(h.y);
  m.y = f32_to_bf16_rne(r);   l.y = f32_to_bf16_rne(r - bf16_to_f32(m.y));
  h.z = f32_to_bf16_rne(v.z); r = v.z - bf16_to_f32(h.z);
  m.z = f32_to_bf16_rne(r);   l.z = f32_to_bf16_rne(r - bf16_to_f32(m.z));
  h.w = f32_to_bf16_rne(v.w); r = v.w - bf16_to_f32(h.w);
  m.w = f32_to_bf16_rne(r);   l.w = f32_to_bf16_rne(r - bf16_to_f32(m.w));
  *(ushort4*)(H + i) = h;
  *(ushort4*)(M + i) = m;
  *(ushort4*)(L + i) = l;
}

// ---------------------------------------------------------------------------
// W (K x N, z picks Wi/Wp) -> transposed (N x K) 3 bf16 planes, packed at
// WT + z*3*1M + plane*1M elements.
// ---------------------------------------------------------------------------
__global__ void __launch_bounds__(256) wsplit3T(const float* __restrict__ Wi,
                                                const float* __restrict__ Wp,
                                                unsigned short* __restrict__ WT)
{
  __shared__ float tile[64][65];
  const int k0 = blockIdx.y << 6, n0 = blockIdx.x << 6;
  const int z = blockIdx.z;
  const float* W = z ? Wp : Wi;
  unsigned short* H = WT + (size_t)z * 3 * 1024 * 1024;
  unsigned short* M = H + (size_t)1024 * 1024;
  unsigned short* L = M + (size_t)1024 * 1024;
  const int tid = threadIdx.x;
  for (int idx = tid; idx < 4096; idx += 256) {
    int r = idx >> 6, c = idx & 63;
    tile[r][c] = W[(size_t)(k0 + r) * D_DIM + n0 + c];
  }
  __syncthreads();
  for (int idx = tid; idx < 4096; idx += 256) {
    int n = idx >> 6, k = idx & 63;
    float v = tile[k][n];
    unsigned short h = f32_to_bf16_rne(v);
    float r1 = v - bf16_to_f32(h);
    unsigned short m = f32_to_bf16_rne(r1);
    unsigned short l = f32_to_bf16_rne(r1 - bf16_to_f32(m));
    size_t o = (size_t)(n0 + n) * D_DIM + k0 + k;
    H[o] = h; M[o] = m; L[o] = l;
  }
}

// ---------------------------------------------------------------------------
// 3-plane split-bf16 MFMA GEMM for I = x@Wi (z=0), P = x@Wp (z=1).
// A planes (M x K), B planes transposed (N x K). 64x64 tile, BK=32, dbuf,
// 4 waves each 32x32 (2x2 MFMA tiles). 6 products per tile with SEPARATE
// accumulators by magnitude (hh | hm+mh | hl+mm+lh) -> f32-rounding noise
// ~2e-7 absolute on I/P (selection margin analysis in journal). Output
// layout via the proven in-kernel probe.
// ---------------------------------------------------------------------------
__global__ void __launch_bounds__(256) gemm3bf(
    const unsigned short* __restrict__ Xh, const unsigned short* __restrict__ Xm,
    const unsigned short* __restrict__ Xl, const unsigned short* __restrict__ WT,
    float* __restrict__ C)
{
  const int m0 = blockIdx.y << 6, n0 = blockIdx.x << 6;
  const int z = blockIdx.z;
  const unsigned short* BhT = WT + (size_t)z * 3 * 1024 * 1024;
  const unsigned short* BmT = BhT + (size_t)1024 * 1024;
  const unsigned short* BlT = BmT + (size_t)1024 * 1024;
  C += (size_t)z * 4096 * 1024;
  const int N = D_DIM, K = D_DIM;

  const int tid = threadIdx.x;
  const int w = tid >> 6, lane = tid & 63;
  const int kg = lane >> 4, lm = lane & 15;
  const int am0 = (w & 1) << 5;
  const int bn0 = (w >> 1) << 5;

  __shared__ unsigned short Ah[2][64][40], Am[2][64][40], Al[2][64][40];
  __shared__ unsigned short Bh[2][64][40], Bm[2][64][40], Bl[2][64][40];

  bf16x8 ones;
#pragma unroll
  for (int e = 0; e < 8; ++e) ones[e] = (short)0x3F80;

  // ---------------- layout probe (buf 0, h-planes) ----------------
  for (int idx = tid; idx < 2048; idx += 256) {
    Ah[0][idx >> 5][idx & 31] = f32_to_bf16_rne((float)(idx >> 5));
    Bh[0][idx >> 5][idx & 31] = f32_to_bf16_rne((float)(idx >> 5));
  }
  __syncthreads();
  int mr[4], nc[4];
  {
    bf16x8 pa = *(const bf16x8*)&Ah[0][am0 + lm][kg << 3];
    bf16x8 pb = *(const bf16x8*)&Bh[0][bn0 + lm][kg << 3];
    f32x4v d1 = {0.f, 0.f, 0.f, 0.f}, d2 = {0.f, 0.f, 0.f, 0.f};
    d1 = __builtin_amdgcn_mfma_f32_16x16x32_bf16(pa, ones, d1, 0, 0, 0);
    d2 = __builtin_amdgcn_mfma_f32_16x16x32_bf16(ones, pb, d2, 0, 0, 0);
#pragma unroll
    for (int e = 0; e < 4; ++e) {
      mr[e] = ((int)d1[e]) >> 5;   // row in [0,64)
      nc[e] = ((int)d2[e]) >> 5;   // col in [0,64), tile j=0
    }
  }
  __syncthreads();

  // accumulators: [i][j] tiles; separate magnitude classes
  f32x4v ch[2][2], cm[2][2], cl[2][2];
#pragma unroll
  for (int i = 0; i < 2; ++i)
#pragma unroll
    for (int j = 0; j < 2; ++j) {
      ch[i][j] = (f32x4v){0.f, 0.f, 0.f, 0.f};
      cm[i][j] = (f32x4v){0.f, 0.f, 0.f, 0.f};
      cl[i][j] = (f32x4v){0.f, 0.f, 0.f, 0.f};
    }

  // staging ownership: 64x32 ushorts = 256 chunks of 8 per plane
  const int ar = tid >> 2, ak8 = (tid & 3) << 3;

  bf16x8 rah, ram, ral, rbh, rbm, rbl;

  // prologue: k0 = 0 -> buf 0
  {
    size_t ao = (size_t)(m0 + ar) * K + ak8;
    size_t bo = (size_t)(n0 + ar) * K + ak8;
    rah = *(const bf16x8*)(Xh + ao); ram = *(const bf16x8*)(Xm + ao);
    ral = *(const bf16x8*)(Xl + ao);
    rbh = *(const bf16x8*)(BhT + bo); rbm = *(const bf16x8*)(BmT + bo);
    rbl = *(const bf16x8*)(BlT + bo);
  }
  *(bf16x8*)&Ah[0][ar][ak8] = rah;
  *(bf16x8*)&Am[0][ar][ak8] = ram;
  *(bf16x8*)&Al[0][ar][ak8] = ral;
  *(bf16x8*)&Bh[0][ar][ak8] = rbh;
  *(bf16x8*)&Bm[0][ar][ak8] = rbm;
  *(bf16x8*)&Bl[0][ar][ak8] = rbl;
  __syncthreads();

  int buf = 0;
  for (int k0 = 0; k0 < K; k0 += 32) {
    const bool more = (k0 + 32) < K;
    if (more) {
      const int kn = k0 + 32;
      size_t ao = (size_t)(m0 + ar) * K + kn + ak8;
      size_t bo = (size_t)(n0 + ar) * K + kn + ak8;
      rah = *(const bf16x8*)(Xh + ao); ram = *(const bf16x8*)(Xm + ao);
      ral = *(const bf16x8*)(Xl + ao);
      rbh = *(const bf16x8*)(BhT + bo); rbm = *(const bf16x8*)(BmT + bo);
      rbl = *(const bf16x8*)(BlT + bo);
    }
    {
      bf16x8 a_h[2], a_m[2], a_l[2], b_h[2], b_m[2], b_l[2];
#pragma unroll
      for (int i = 0; i < 2; ++i) {
        const int rrow = am0 + (i << 4) + lm;
        a_h[i] = *(const bf16x8*)&Ah[buf][rrow][kg << 3];
        a_m[i] = *(const bf16x8*)&Am[buf][rrow][kg << 3];
        a_l[i] = *(const bf16x8*)&Al[buf][rrow][kg << 3];
        const int nrow = bn0 + (i << 4) + lm;
        b_h[i] = *(const bf16x8*)&Bh[buf][nrow][kg << 3];
        b_m[i] = *(const bf16x8*)&Bm[buf][nrow][kg << 3];
        b_l[i] = *(const bf16x8*)&Bl[buf][nrow][kg << 3];
      }
#pragma unroll
      for (int i = 0; i < 2; ++i)
#pragma unroll
        for (int j = 0; j < 2; ++j) {
          ch[i][j] = __builtin_amdgcn_mfma_f32_16x16x32_bf16(a_h[i], b_h[j], ch[i][j], 0, 0, 0);
          cm[i][j] = __builtin_amdgcn_mfma_f32_16x16x32_bf16(a_h[i], b_m[j], cm[i][j], 0, 0, 0);
          cm[i][j] = __builtin_amdgcn_mfma_f32_16x16x32_bf16(a_m[i], b_h[j], cm[i][j], 0, 0, 0);
          cl[i][j] = __builtin_amdgcn_mfma_f32_16x16x32_bf16(a_h[i], b_l[j], cl[i][j], 0, 0, 0);
          cl[i][j] = __builtin_amdgcn_mfma_f32_16x16x32_bf16(a_m[i], b_m[j], cl[i][j], 0, 0, 0);
          cl[i][j] = __builtin_amdgcn_mfma_f32_16x16x32_bf16(a_l[i], b_h[j], cl[i][j], 0, 0, 0);
        }
    }
    if (more) {
      const int nb = buf ^ 1;
      *(bf16x8*)&Ah[nb][ar][ak8] = rah;
      *(bf16x8*)&Am[nb][ar][ak8] = ram;
      *(bf16x8*)&Al[nb][ar][ak8] = ral;
      *(bf16x8*)&Bh[nb][ar][ak8] = rbh;
      *(bf16x8*)&Bm[nb][ar][ak8] = rbm;
      *(bf16x8*)&Bl[nb][ar][ak8] = rbl;
    }
    __syncthreads();
    buf ^= 1;
  }

  // C-write via probed mapping (tile i -> rows +16i, tile j -> cols +16j)
#pragma unroll
  for (int i = 0; i < 2; ++i)
#pragma unroll
    for (int j = 0; j < 2; ++j)
#pragma unroll
      for (int e = 0; e < 4; ++e) {
        const int rrow = m0 + mr[e] + (i << 4);
        const int ccol = n0 + nc[e] + (j << 4);
        float v = (ch[i][j][e] + cm[i][j][e]) + cl[i][j][e];
        C[(size_t)rrow * N + ccol] = v;
      }
}

// ---------------------------------------------------------------------------
// PREP (fused): trig table (EXACT reference f32 bits — selection-critical)
// + palette transpose.
// ---------------------------------------------------------------------------
__global__ void __launch_bounds__(256) prep_kernel(float2* __restrict__ tab,
                                                   const float* __restrict__ pal,
                                                   float* __restrict__ palT)
{
  const int b = blockIdx.x;
  if (b < T_LEN) {
    const int t = b;
    for (int j = threadIdx.x; j < 512; j += 256) {
      double e = (double)j * (1.0 / 512.0);
      float pf = (float)pow(10000.0, e);
      float invf = 1.0f / pf;
      float angf = (float)t * invf;
      double s64, c64;
      sincos((double)angf, &s64, &c64);
      tab[(size_t)t * 512 + j] = make_float2((float)c64, (float)s64);
    }
  } else {
    const int bb = b - T_LEN;
    const int c = bb & 255, dg = bb >> 8;
    const int d = dg * 256 + threadIdx.x;
    palT[(size_t)c * D_DIM + d] = pal[(size_t)d * 256 + c];
  }
}

// ---------------------------------------------------------------------------
// RoPE in place + row L2 norms + bf16 hi planes Ih/Ph (fused emit).
// f32 rotation math unchanged — selection-critical.
// ---------------------------------------------------------------------------
__global__ void __launch_bounds__(256) rope_norm_kernel(
    float* __restrict__ bI, float* __restrict__ bP,
    const float2* __restrict__ tab,
    float* __restrict__ nI, float* __restrict__ nP,
    unsigned short* __restrict__ Ih, unsigned short* __restrict__ Ph)
{
  const int row = blockIdx.x;
  const int t = row & (T_LEN - 1);
  const int tid = threadIdx.x;
  __shared__ double redI[4], redP[4];
  double ssI = 0.0, ssP = 0.0;
  const size_t off = (size_t)row * D_DIM;
  for (int j = tid; j < 512; j += 256) {
    float2 cs = tab[(size_t)t * 512 + j];
    float c = cs.x, s = cs.y;

    float a1 = bI[off + j], a2 = bI[off + 512 + j];
    float o1 = __fsub_rn(__fmul_rn(a1, c), __fmul_rn(a2, s));
    float o2 = __fadd_rn(__fmul_rn(a1, s), __fmul_rn(a2, c));
    bI[off + j] = o1; bI[off + 512 + j] = o2;
    Ih[off + j] = f32_to_bf16_rne(o1); Ih[off + 512 + j] = f32_to_bf16_rne(o2);
    ssI += (double)o1 * o1 + (double)o2 * o2;

    float p1 = bP[off + j], p2 = bP[off + 512 + j];
    float q1 = __fsub_rn(__fmul_rn(p1, c), __fmul_rn(p2, s));
    float q2 = __fadd_rn(__fmul_rn(p1, s), __fmul_rn(p2, c));
    bP[off + j] = q1; bP[off + 512 + j] = q2;
    Ph[off + j] = f32_to_bf16_rne(q1); Ph[off + 512 + j] = f32_to_bf16_rne(q2);
    ssP += (double)q1 * q1 + (double)q2 * q2;
  }
#pragma unroll
  for (int o = 32; o >= 1; o >>= 1) { ssI += __shfl_xor(ssI, o); ssP += __shfl_xor(ssP, o); }
  if ((tid & 63) == 0) { redI[tid >> 6] = ssI; redP[tid >> 6] = ssP; }
  __syncthreads();
  if (tid == 0) {
    nI[row] = fmaxf((float)sqrt(redI[0] + redI[1] + redI[2] + redI[3]), 1e-12f);
    nP[row] = fmaxf((float)sqrt(redP[0] + redP[1] + redP[2] + redP[3]), 1e-12f);
  }
}

// ---------------------------------------------------------------------------
// bf16 SCREEN for S (candidates only; exact rescore follows). (r12, unchanged.)
// ---------------------------------------------------------------------------
__global__ void __launch_bounds__(256) screen_bf16(
    const unsigned short* __restrict__ Ih, const unsigned short* __restrict__ Ph,
    unsigned short* __restrict__ Ssc)
{
  int rem = blockIdx.x, bi = 0;
  while (rem >= (bi >> 1) + 1) { rem -= (bi >> 1) + 1; ++bi; }
  const int m0 = bi << 6, n0 = rem << 7;
  const int z = blockIdx.z;
  const unsigned short* A = Ih + (size_t)z * T_LEN * D_DIM;
  const unsigned short* B = Ph + (size_t)z * T_LEN * D_DIM;
  unsigned short* C = Ssc + (size_t)z * T_LEN * T_LEN;
  const int N = T_LEN, K = D_DIM;

  const int tid = threadIdx.x;
  const int w = tid >> 6, lane = tid & 63;
  const int kg = lane >> 4, lm = lane & 15;
  const int am0 = (w & 1) << 5;
  const int bn0 = (w >> 1) << 6;

  __shared__ unsigned short As_h[2][64][40];
  __shared__ unsigned short Bs_h[2][128][40];

  bf16x8 ones;
#pragma unroll
  for (int e = 0; e < 8; ++e) ones[e] = (short)0x3F80;

  for (int idx = tid; idx < 2048; idx += 256)
    As_h[0][idx >> 5][idx & 31] = f32_to_bf16_rne((float)(idx >> 5));
  for (int idx = tid; idx < 4096; idx += 256)
    Bs_h[0][idx >> 5][idx & 31] = f32_to_bf16_rne((float)(idx >> 5));
  __syncthreads();
  int mr[4], nc[4];
  {
    bf16x8 pa = *(const bf16x8*)&As_h[0][am0 + lm][kg << 3];
    bf16x8 pb = *(const bf16x8*)&Bs_h[0][bn0 + lm][kg << 3];
    f32x4v d1 = {0.f, 0.f, 0.f, 0.f}, d2 = {0.f, 0.f, 0.f, 0.f};
    d1 = __builtin_amdgcn_mfma_f32_16x16x32_bf16(pa, ones, d1, 0, 0, 0);
    d2 = __builtin_amdgcn_mfma_f32_16x16x32_bf16(ones, pb, d2, 0, 0, 0);
#pragma unroll
    for (int e = 0; e < 4; ++e) {
      mr[e] = ((int)d1[e]) >> 5;
      nc[e] = ((int)d2[e]) >> 5;
    }
  }
  __syncthreads();

  f32x4v c00 = {0,0,0,0}, c01 = {0,0,0,0}, c02 = {0,0,0,0}, c03 = {0,0,0,0};
  f32x4v c10 = {0,0,0,0}, c11 = {0,0,0,0}, c12 = {0,0,0,0}, c13 = {0,0,0,0};

  const int ar  = tid >> 2, ak8 = (tid & 3) << 3;
  const int bna = tid >> 2, bnb = 64 + (tid >> 2), bk8 = (tid & 3) << 3;

  bf16x8 ra, rb0, rb1;

  ra  = *(const bf16x8*)(A + (size_t)(m0 + ar) * K + ak8);
  rb0 = *(const bf16x8*)(B + (size_t)(n0 + bna) * K + bk8);
  rb1 = *(const bf16x8*)(B + (size_t)(n0 + bnb) * K + bk8);
  *(bf16x8*)&As_h[0][ar][ak8]  = ra;
  *(bf16x8*)&Bs_h[0][bna][bk8] = rb0;
  *(bf16x8*)&Bs_h[0][bnb][bk8] = rb1;
  __syncthreads();

  int buf = 0;
  for (int k0 = 0; k0 < K; k0 += 32) {
    const bool more = (k0 + 32) < K;
    if (more) {
      const int kn = k0 + 32;
      ra  = *(const bf16x8*)(A + (size_t)(m0 + ar) * K + kn + ak8);
      rb0 = *(const bf16x8*)(B + (size_t)(n0 + bna) * K + kn + bk8);
      rb1 = *(const bf16x8*)(B + (size_t)(n0 + bnb) * K + kn + bk8);
    }
    {
      bf16x8 a0 = *(const bf16x8*)&As_h[buf][am0 + lm][kg << 3];
      bf16x8 a1 = *(const bf16x8*)&As_h[buf][am0 + 16 + lm][kg << 3];
      bf16x8 b0 = *(const bf16x8*)&Bs_h[buf][bn0 + lm][kg << 3];
      bf16x8 b1 = *(const bf16x8*)&Bs_h[buf][bn0 + 16 + lm][kg << 3];
      bf16x8 b2 = *(const bf16x8*)&Bs_h[buf][bn0 + 32 + lm][kg << 3];
      bf16x8 b3 = *(const bf16x8*)&Bs_h[buf][bn0 + 48 + lm][kg << 3];
      c00 = __builtin_amdgcn_mfma_f32_16x16x32_bf16(a0, b0, c00, 0, 0, 0);
      c01 = __builtin_amdgcn_mfma_f32_16x16x32_bf16(a0, b1, c01, 0, 0, 0);
      c02 = __builtin_amdgcn_mfma_f32_16x16x32_bf16(a0, b2, c02, 0, 0, 0);
      c03 = __builtin_amdgcn_mfma_f32_16x16x32_bf16(a0, b3, c03, 0, 0, 0);
      c10 = __builtin_amdgcn_mfma_f32_16x16x32_bf16(a1, b0, c10, 0, 0, 0);
      c11 = __builtin_amdgcn_mfma_f32_16x16x32_bf16(a1, b1, c11, 0, 0, 0);
      c12 = __builtin_amdgcn_mfma_f32_16x16x32_bf16(a1, b2, c12, 0, 0, 0);
      c13 = __builtin_amdgcn_mfma_f32_16x16x32_bf16(a1, b3, c13, 0, 0, 0);
    }
    if (more) {
      const int nb = buf ^ 1;
      *(bf16x8*)&As_h[nb][ar][ak8]  = ra;
      *(bf16x8*)&Bs_h[nb][bna][bk8] = rb0;
      *(bf16x8*)&Bs_h[nb][bnb][bk8] = rb1;
    }
    __syncthreads();
    buf ^= 1;
  }

#pragma unroll
  for (int e = 0; e < 4; ++e) {
    const size_t r0 = (size_t)(m0 + mr[e]) * N;
    const size_t r1 = r0 + (size_t)16 * N;
    const int c = n0 + nc[e];
    C[r0 + c +  0] = f32_to_bf16_rne(c00[e]);
    C[r0 + c + 16] = f32_to_bf16_rne(c01[e]);
    C[r0 + c + 32] = f32_to_bf16_rne(c02[e]);
    C[r0 + c + 48] = f32_to_bf16_rne(c03[e]);
    C[r1 + c +  0] = f32_to_bf16_rne(c10[e]);
    C[r1 + c + 16] = f32_to_bf16_rne(c11[e]);
    C[r1 + c + 32] = f32_to_bf16_rne(c12[e]);
    C[r1 + c + 48] = f32_to_bf16_rne(c13[e]);
  }
}

// ---------------------------------------------------------------------------
// Top-NCAND screen candidates per causal row (bf16 S). -1 = invalid.
// ---------------------------------------------------------------------------
__global__ void __launch_bounds__(256) topk_screen(const unsigned short* __restrict__ Ssc,
                                                   int* __restrict__ cand)
{
  const int b = blockIdx.y;
  const unsigned short* S = Ssc + (size_t)b * T_LEN * T_LEN;
  const int wave = threadIdx.x >> 6, lane = threadIdx.x & 63;
  const int t = blockIdx.x * 4 + wave;
  const unsigned short* rowp = S + (size_t)t * T_LEN;
  float v[32];
#pragma unroll
  for (int i = 0; i < 32; ++i) {
    int s = lane + (i << 6);
    v[i] = (s <= t) ? bf16_to_f32(rowp[s]) : -INFINITY;
  }
  float pv = INFINITY; int pidx = -1;
  int* outp = cand + ((size_t)b * T_LEN + t) * NCAND;
  for (int k = 0; k < NCAND; ++k) {
    float bv = -INFINITY; int bi = 0x7fffffff;
#pragma unroll
    for (int i = 0; i < 32; ++i) {
      int s = lane + (i << 6);
      float vv = v[i];
      bool elig = (vv < pv) || (vv == pv && s > pidx);
      if (elig && vv > bv) { bv = vv; bi = s; }
    }
#pragma unroll
    for (int o = 32; o >= 1; o >>= 1) {
      float ov = __shfl_xor(bv, o);
      int oi = __shfl_xor(bi, o);
      if (ov > bv || (ov == bv && oi < bi)) { bv = ov; bi = oi; }
    }
    pv = bv; pidx = bi;
    if (lane == 0) outp[k] = (bi == 0x7fffffff || bv == -INFINITY) ? -1 : bi;
  }
}

// ---------------------------------------------------------------------------
// Exact rescore: f64 dot of I_t with each candidate P row (f32 arrays),
// rounded to f32 after the 2^-5 scale, tie -> lower index, top-15 -> idx.
// ---------------------------------------------------------------------------
__global__ void __launch_bounds__(256) rescore_kernel(
    const float* __restrict__ I, const float* __restrict__ P,
    const int* __restrict__ cand, int* __restrict__ idx)
{
  const int row = blockIdx.x;
  const int base = row & ~(T_LEN - 1);
  const int tid = threadIdx.x;
  const int w = tid >> 6, lane = tid & 63;

  __shared__ float valS[NCAND];
  __shared__ int   sidxS[NCAND];
  __shared__ int   candS[NCAND];

  if (tid < NCAND) candS[tid] = cand[(size_t)row * NCAND + tid];
  __syncthreads();

  double iv[16];
  const float* irow = I + (size_t)row * D_DIM;
#pragma unroll
  for (int j = 0; j < 16; ++j) iv[j] = (double)irow[lane + (j << 6)];

  for (int c = w; c < NCAND; c += 4) {
    int s = candS[c];
    double acc = 0.0;
    if (s >= 0) {
      const float* prow = P + ((size_t)base + s) * D_DIM;
#pragma unroll
      for (int j = 0; j < 16; ++j)
        acc = fma(iv[j], (double)prow[lane + (j << 6)], acc);
    }
#pragma unroll
    for (int o = 32; o >= 1; o >>= 1) acc += __shfl_xor(acc, o);
    if (lane == 0) {
      valS[c] = (s >= 0) ? (float)(acc * 0.03125) : -INFINITY;
      sidxS[c] = s;
    }
  }
  __syncthreads();
  if (tid == 0) {
    bool taken[NCAND];
#pragma unroll
    for (int c = 0; c < NCAND; ++c) taken[c] = false;
    int* outp = idx + (size_t)row * 16;
    for (int k = 0; k < KSEL; ++k) {
      float best = -INFINITY; int bidx = 0x7fffffff; int bc = -1;
      for (int c = 0; c < NCAND; ++c) {
        if (taken[c] || sidxS[c] < 0) continue;
        float v = valS[c];
        if (v > best || (v == best && sidxS[c] < bidx)) { best = v; bidx = sidxS[c]; bc = c; }
      }
      if (bc >= 0) { taken[bc] = true; outp[k] = bidx; }
      else outp[k] = 0;
    }
  }
}

// ---------------------------------------------------------------------------
// Wo (K x N) -> transposed bf16 hi/lo planes (N x K). After rescore (P dead).
// ---------------------------------------------------------------------------
__global__ void __launch_bounds__(256) woconvT(const float* __restrict__ Wo,
                                               unsigned short* __restrict__ HT,
                                               unsigned short* __restrict__ LT)
{
  __shared__ float tile[64][65];
  const int k0 = blockIdx.y << 6, n0 = blockIdx.x << 6;
  const int tid = threadIdx.x;
  for (int idx = tid; idx < 4096; idx += 256) {
    int r = idx >> 6, c = idx & 63;
    tile[r][c] = Wo[(size_t)(k0 + r) * D_DIM + n0 + c];
  }
  __syncthreads();
  for (int idx = tid; idx < 4096; idx += 256) {
    int n = idx >> 6, k = idx & 63;
    float v = tile[k][n];
    unsigned short h = f32_to_bf16_rne(v);
    HT[(size_t)(n0 + n) * D_DIM + k0 + k] = h;
    LT[(size_t)(n0 + n) * D_DIM + k0 + k] = f32_to_bf16_rne(v - bf16_to_f32(h));
  }
}

// ---------------------------------------------------------------------------
// Per-(b,t): gather (bf16 Ih/Ph) + normalized gram + rel features + MLP +
// heads + softmax + bilinear palette blend -> V as bf16 hi/lo planes.
// ---------------------------------------------------------------------------
__global__ void __launch_bounds__(256) relmlp_kernel(
    const unsigned short* __restrict__ Ih, const unsigned short* __restrict__ Ph,
    const float* __restrict__ nI, const float* __restrict__ nP,
    const int* __restrict__ topk,
    const float* __restrict__ W1, const float* __restrict__ b1,
    const float* __restrict__ W2, const float* __restrict__ b2,
    const float* __restrict__ Wc, const float* __restrict__ bc,
    const float* __restrict__ Wm, const float* __restrict__ bm,
    const float* __restrict__ palT,
    unsigned short* __restrict__ Vh, unsigned short* __restrict__ Vl)
{
  const int row = blockIdx.x;
  const int t = row & (T_LEN - 1);
  const int base = row & ~(T_LEN - 1);
  const int nk = (t + 1 < KSEL) ? (t + 1) : KSEL;
  const int tid = threadIdx.x;

  __shared__ float vecS[16][516];
  __shared__ float gS[16][16];
  __shared__ float relS[KSEL][17];
  __shared__ float h1S[KSEL][HIDN];
  __shared__ float h2S[KSEL][HIDN];
  __shared__ float nrmS[16];
  __shared__ int   sidxS[16];
  __shared__ float mixS[KSEL], wS[KSEL], zxS[KSEL], zyS[KSEL];
  __shared__ float coefS[4 * KSEL];
  __shared__ int   cellS[4 * KSEL];

  if (tid < 16) {
    int s = t;
    if (tid >= 1) s = (tid <= nk) ? topk[(size_t)row * 16 + (tid - 1)] : 0;
    sidxS[tid] = s;
    nrmS[tid] = (tid == 0) ? nI[row] : nP[base + s];
  }
  __syncthreads();

  const int r = tid >> 4, c0 = tid & 15;
  const unsigned short* srcrow = (r == 0)
      ? (Ih + (size_t)row * D_DIM)
      : (Ph + ((size_t)base + sidxS[r]) * D_DIM);

  int pi = 0, pj = 0;
  {
    int p = tid;
    if (p < 136) {
      int i = 0;
      while (p >= 16 - i) { p -= 16 - i; ++i; }
      pi = i; pj = i + p;
    }
  }
  const bool pairOn = (tid < 136) && (pi <= nk) && (pj <= nk);
  float4 acc4 = make_float4(0.f, 0.f, 0.f, 0.f);

  for (int half = 0; half < 2; ++half) {
    if (half) __syncthreads();
    if (r <= nk) {
#pragma unroll
      for (int rep = 0; rep < 4; ++rep) {
        int q = c0 + 16 * rep;
        bf16x8 v8 = *(const bf16x8*)(srcrow + half * 512 + (q << 3));
        float4 f0, f1;
        f0.x = bf16_to_f32((unsigned short)v8[0]);
        f0.y = bf16_to_f32((unsigned short)v8[1]);
        f0.z = bf16_to_f32((unsigned short)v8[2]);
        f0.w = bf16_to_f32((unsigned short)v8[3]);
        f1.x = bf16_to_f32((unsigned short)v8[4]);
        f1.y = bf16_to_f32((unsigned short)v8[5]);
        f1.z = bf16_to_f32((unsigned short)v8[6]);
        f1.w = bf16_to_f32((unsigned short)v8[7]);
        *(float4*)&vecS[r][(q << 3)]     = f0;
        *(float4*)&vecS[r][(q << 3) + 4] = f1;
      }
    }
    __syncthreads();
    if (pairOn) {
      const float4* va = (const float4*)&vecS[pi][0];
      const float4* vb = (const float4*)&vecS[pj][0];
#pragma unroll 4
      for (int q = 0; q < 128; ++q) {
        float4 a4 = va[q], b4 = vb[q];
        acc4.x = fmaf(a4.x, b4.x, acc4.x);
        acc4.y = fmaf(a4.y, b4.y, acc4.y);
        acc4.z = fmaf(a4.z, b4.z, acc4.z);
        acc4.w = fmaf(a4.w, b4.w, acc4.w);
      }
    }
  }
  if (tid < 136) {
    float g = 0.f;
    if (pairOn) {
      float acc = (acc4.x + acc4.y) + (acc4.z + acc4.w);
      g = acc / (nrmS[pi] * nrmS[pj]);
      g = fminf(fmaxf(g, -1.f), 1.f);
    }
    gS[pi][pj] = g;
    gS[pj][pi] = g;
  }
  __syncthreads();

  if (tid < KSEL * 17) {
    int k = tid / 17, f = tid % 17;
    float v = 0.f;
    if (k < nk) {
      if (f < KSEL)        v = (f < nk) ? gS[k + 1][f + 1] : 0.f;
      else if (f == KSEL)  v = gS[0][k + 1];
      else                 v = (float)(t - sidxS[k + 1]) * (1.0f / (float)T_LEN);
    }
    relS[k][f] = v;
  }
  __syncthreads();

  for (int o = tid; o < KSEL * HIDN; o += 256) {
    int k = o >> 6, m = o & 63;
    float a = b1[m];
#pragma unroll
    for (int f = 0; f < 17; ++f) a = fmaf(relS[k][f], W1[f * HIDN + m], a);
    h1S[k][m] = geluf(a);
  }
  __syncthreads();
  for (int o = tid; o < KSEL * HIDN; o += 256) {
    int k = o >> 6, m = o & 63;
    float a = b2[m];
#pragma unroll 8
    for (int n = 0; n < HIDN; ++n) a = fmaf(h1S[k][n], W2[n * HIDN + m], a);
    h2S[k][m] = geluf(a);
  }
  __syncthreads();
  if (tid < KSEL) {
    float a0 = 0.f, a1 = 0.f, am = 0.f;
#pragma unroll 8
    for (int n = 0; n < HIDN; ++n) {
      float h = h2S[tid][n];
      a0 = fmaf(h, Wc[n * 2 + 0], a0);
      a1 = fmaf(h, Wc[n * 2 + 1], a1);
      am = fmaf(h, Wm[n], am);
    }
    zxS[tid] = tanhf(a0 + bc[0]);
    zyS[tid] = tanhf(a1 + bc[1]);
    mixS[tid] = am + bm[0];
  }
  __syncthreads();
  if (tid == 0) {
    float mx = -INFINITY;
    for (int k = 0; k < nk; ++k) mx = fmaxf(mx, mixS[k]);
    float ssum = 0.f;
    for (int k = 0; k < nk; ++k) { float e = expf(mixS[k] - mx); wS[k] = e; ssum += e; }
    float inv = 1.f / ssum;
    for (int k = 0; k < nk; ++k) wS[k] *= inv;
  }
  __syncthreads();
  if (tid < KSEL) {
    int k = tid;
    if (k < nk) {
      float w = wS[k];
      float fx = fminf(fmaxf((zxS[k] + 1.f) * 0.5f * 15.f, 0.f), 15.f);
      float fy = fminf(fmaxf((zyS[k] + 1.f) * 0.5f * 15.f, 0.f), 15.f);
      int x0 = (int)floorf(fx); int x1i = (x0 + 1 < 15) ? x0 + 1 : 15;
      int y0 = (int)floorf(fy); int y1i = (y0 + 1 < 15) ? y0 + 1 : 15;
      float wx = fx - (float)x0, wy = fy - (float)y0;
      cellS[k * 4 + 0] = y0 * 16 + x0;   coefS[k * 4 + 0] = w * (1.f - wy) * (1.f - wx);
      cellS[k * 4 + 1] = y0 * 16 + x1i;  coefS[k * 4 + 1] = w * (1.f - wy) * wx;
      cellS[k * 4 + 2] = y1i * 16 + x0;  coefS[k * 4 + 2] = w * wy * (1.f - wx);
      cellS[k * 4 + 3] = y1i * 16 + x1i; coefS[k * 4 + 3] = w * wy * wx;
    } else {
      cellS[k * 4 + 0] = cellS[k * 4 + 1] = cellS[k * 4 + 2] = cellS[k * 4 + 3] = 0;
      coefS[k * 4 + 0] = coefS[k * 4 + 1] = coefS[k * 4 + 2] = coefS[k * 4 + 3] = 0.f;
    }
  }
  __syncthreads();
  const int nj = 4 * nk;
  for (int d = tid; d < D_DIM; d += 256) {
    float a = 0.f;
    for (int j = 0; j < nj; ++j)
      a = fmaf(coefS[j], palT[(size_t)cellS[j] * D_DIM + d], a);
    unsigned short h = f32_to_bf16_rne(a);
    Vh[(size_t)row * D_DIM + d] = h;
    Vl[(size_t)row * D_DIM + d] = f32_to_bf16_rne(a - bf16_to_f32(h));
  }
}

// ---------------------------------------------------------------------------
// Split-bf16 MFMA GEMM for out = V @ Wo. (r10, unchanged.)
// ---------------------------------------------------------------------------
__global__ void __launch_bounds__(256) gemmbf(
    const unsigned short* __restrict__ Ah, const unsigned short* __restrict__ Al,
    const unsigned short* __restrict__ BhT, const unsigned short* __restrict__ BlT,
    float* __restrict__ C, int N, int K)
{
  const int m0 = blockIdx.y << 6, n0 = blockIdx.x << 7;
  const int tid = threadIdx.x;
  const int w = tid >> 6, lane = tid & 63;
  const int kg = lane >> 4, lm = lane & 15;
  const int am0 = (w & 1) << 5;
  const int bn0 = (w >> 1) << 6;

  __shared__ unsigned short As_h[2][64][40],  As_l[2][64][40];
  __shared__ unsigned short Bs_h[2][128][40], Bs_l[2][128][40];

  bf16x8 ones;
#pragma unroll
  for (int e = 0; e < 8; ++e) ones[e] = (short)0x3F80;

  for (int idx = tid; idx < 2048; idx += 256)
    As_h[0][idx >> 5][idx & 31] = f32_to_bf16_rne((float)(idx >> 5));
  for (int idx = tid; idx < 4096; idx += 256)
    Bs_h[0][idx >> 5][idx & 31] = f32_to_bf16_rne((float)(idx >> 5));
  __syncthreads();
  int mr[4], nc[4];
  {
    bf16x8 pa = *(const bf16x8*)&As_h[0][am0 + lm][kg << 3];
    bf16x8 pb = *(const bf16x8*)&Bs_h[0][bn0 + lm][kg << 3];
    f32x4v d1 = {0.f, 0.f, 0.f, 0.f}, d2 = {0.f, 0.f, 0.f, 0.f};
    d1 = __builtin_amdgcn_mfma_f32_16x16x32_bf16(pa, ones, d1, 0, 0, 0);
    d2 = __builtin_amdgcn_mfma_f32_16x16x32_bf16(ones, pb, d2, 0, 0, 0);
#pragma unroll
    for (int e = 0; e < 4; ++e) {
      mr[e] = ((int)d1[e]) >> 5;
      nc[e] = ((int)d2[e]) >> 5;
    }
  }
  __syncthreads();

  f32x4v c00 = {0,0,0,0}, c01 = {0,0,0,0}, c02 = {0,0,0,0}, c03 = {0,0,0,0};
  f32x4v c10 = {0,0,0,0}, c11 = {0,0,0,0}, c12 = {0,0,0,0}, c13 = {0,0,0,0};

  const int ar  = tid >> 2, ak8 = (tid & 3) << 3;
  const int bna = tid >> 2, bnb = 64 + (tid >> 2), bk8 = (tid & 3) << 3;

  bf16x8 rah, ral, rbh0, rbl0, rbh1, rbl1;

  rah  = *(const bf16x8*)(Ah  + (size_t)(m0 + ar) * K + ak8);
  ral  = *(const bf16x8*)(Al  + (size_t)(m0 + ar) * K + ak8);
  rbh0 = *(const bf16x8*)(BhT + (size_t)(n0 + bna) * K + bk8);
  rbl0 = *(const bf16x8*)(BlT + (size_t)(n0 + bna) * K + bk8);
  rbh1 = *(const bf16x8*)(BhT + (size_t)(n0 + bnb) * K + bk8);
  rbl1 = *(const bf16x8*)(BlT + (size_t)(n0 + bnb) * K + bk8);
  *(bf16x8*)&As_h[0][ar][ak8]  = rah;
  *(bf16x8*)&As_l[0][ar][ak8]  = ral;
  *(bf16x8*)&Bs_h[0][bna][bk8] = rbh0;
  *(bf16x8*)&Bs_l[0][bna][bk8] = rbl0;
  *(bf16x8*)&Bs_h[0][bnb][bk8] = rbh1;
  *(bf16x8*)&Bs_l[0][bnb][bk8] = rbl1;
  __syncthreads();

  int buf = 0;
  for (int k0 = 0; k0 < K; k0 += 32) {
    const bool more = (k0 + 32) < K;
    if (more) {
      const int kn = k0 + 32;
      rah  = *(const bf16x8*)(Ah  + (size_t)(m0 + ar) * K + kn + ak8);
      ral  = *(const bf16x8*)(Al  + (size_t)(m0 + ar) * K + kn + ak8);
      rbh0 = *(const bf16x8*)(BhT + (size_t)(n0 + bna) * K + kn + bk8);
      rbl0 = *(const bf16x8*)(BlT + (size_t)(n0 + bna) * K + kn + bk8);
      rbh1 = *(const bf16x8*)(BhT + (size_t)(n0 + bnb) * K + kn + bk8);
      rbl1 = *(const bf16x8*)(BlT + (size_t)(n0 + bnb) * K + kn + bk8);
    }
    {
      bf16x8 ah0 = *(const bf16x8*)&As_h[buf][am0 + lm][kg << 3];
      bf16x8 ah1 = *(const bf16x8*)&As_h[buf][am0 + 16 + lm][kg << 3];
      bf16x8 al0 = *(const bf16x8*)&As_l[buf][am0 + lm][kg << 3];
      bf16x8 al1 = *(const bf16x8*)&As_l[buf][am0 + 16 + lm][kg << 3];
      bf16x8 bh0 = *(const bf16x8*)&Bs_h[buf][bn0 + lm][kg << 3];
      bf16x8 bh1 = *(const bf16x8*)&Bs_h[buf][bn0 + 16 + lm][kg << 3];
      bf16x8 bh2 = *(const bf16x8*)&Bs_h[buf][bn0 + 32 + lm][kg << 3];
      bf16x8 bh3 = *(const bf16x8*)&Bs_h[buf][bn0 + 48 + lm][kg << 3];
      bf16x8 bl0 = *(const bf16x8*)&Bs_l[buf][bn0 + lm][kg << 3];
      bf16x8 bl1 = *(const bf16x8*)&Bs_l[buf][bn0 + 16 + lm][kg << 3];
      bf16x8 bl2 = *(const bf16x8*)&Bs_l[buf][bn0 + 32 + lm][kg << 3];
      bf16x8 bl3 = *(const bf16x8*)&Bs_l[buf][bn0 + 48 + lm][kg << 3];

      c00 = __builtin_amdgcn_mfma_f32_16x16x32_bf16(ah0, bh0, c00, 0, 0, 0);
      c01 = __builtin_amdgcn_mfma_f32_16x16x32_bf16(ah0, bh1, c01, 0, 0, 0);
      c02 = __builtin_amdgcn_mfma_f32_16x16x32_bf16(ah0, bh2, c02, 0, 0, 0);
      c03 = __builtin_amdgcn_mfma_f32_16x16x32_bf16(ah0, bh3, c03, 0, 0, 0);
      c10 = __builtin_amdgcn_mfma_f32_16x16x32_bf16(ah1, bh0, c10, 0, 0, 0);
      c11 = __builtin_amdgcn_mfma_f32_16x16x32_bf16(ah1, bh1, c11, 0, 0, 0);
      c12 = __builtin_amdgcn_mfma_f32_16x16x32_bf16(ah1, bh2, c12, 0, 0, 0);
      c13 = __builtin_amdgcn_mfma_f32_16x16x32_bf16(ah1, bh3, c13, 0, 0, 0);

      c00 = __builtin_amdgcn_mfma_f32_16x16x32_bf16(ah0, bl0, c00, 0, 0, 0);
      c01 = __builtin_amdgcn_mfma_f32_16x16x32_bf16(ah0, bl1, c01, 0, 0, 0);
      c02 = __builtin_amdgcn_mfma_f32_16x16x32_bf16(ah0, bl2, c02, 0, 0, 0);
      c03 = __builtin_amdgcn_mfma_f32_16x16x32_bf16(ah0, bl3, c03, 0, 0, 0);
      c10 = __builtin_amdgcn_mfma_f32_16x16x32_bf16(ah1, bl0, c10, 0, 0, 0);
      c11 = __builtin_amdgcn_mfma_f32_16x16x32_bf16(ah1, bl1, c11, 0, 0, 0);
      c12 = __builtin_amdgcn_mfma_f32_16x16x32_bf16(ah1, bl2, c12, 0, 0, 0);
      c13 = __builtin_amdgcn_mfma_f32_16x16x32_bf16(ah1, bl3, c13, 0, 0, 0);

      c00 = __builtin_amdgcn_mfma_f32_16x16x32_bf16(al0, bh0, c00, 0, 0, 0);
      c01 = __builtin_amdgcn_mfma_f32_16x16x32_bf16(al0, bh1, c01, 0, 0, 0);
      c02 = __builtin_amdgcn_mfma_f32_16x16x32_bf16(al0, bh2, c02, 0, 0, 0);
      c03 = __builtin_amdgcn_mfma_f32_16x16x32_bf16(al0, bh3, c03, 0, 0, 0);
      c10 = __builtin_amdgcn_mfma_f32_16x16x32_bf16(al1, bh0, c10, 0, 0, 0);
      c11 = __builtin_amdgcn_mfma_f32_16x16x32_bf16(al1, bh1, c11, 0, 0, 0);
      c12 = __builtin_amdgcn_mfma_f32_16x16x32_bf16(al1, bh2, c12, 0, 0, 0);
      c13 = __builtin_amdgcn_mfma_f32_16x16x32_bf16(al1, bh3, c13, 0, 0, 0);
    }
    if (more) {
      const int nb = buf ^ 1;
      *(bf16x8*)&As_h[nb][ar][ak8]  = rah;
      *(bf16x8*)&As_l[nb][ar][ak8]  = ral;
      *(bf16x8*)&Bs_h[nb][bna][bk8] = rbh0;
      *(bf16x8*)&Bs_l[nb][bna][bk8] = rbl0;
      *(bf16x8*)&Bs_h[nb][bnb][bk8] = rbh1;
      *(bf16x8*)&Bs_l[nb][bnb][bk8] = rbl1;
    }
    __syncthreads();
    buf ^= 1;
  }

#pragma unroll
  for (int e = 0; e < 4; ++e) {
    const size_t r0 = (size_t)(m0 + mr[e]) * N;
    const size_t r1 = r0 + (size_t)16 * N;
    const int c = n0 + nc[e];
    C[r0 + c +  0] = c00[e];
    C[r0 + c + 16] = c01[e];
    C[r0 + c + 32] = c02[e];
    C[r0 + c + 48] = c03[e];
    C[r1 + c +  0] = c10[e];
    C[r1 + c + 16] = c11[e];
    C[r1 + c + 32] = c12[e];
    C[r1 + c + 48] = c13[e];
  }
}

// ---------------------------------------------------------------------------
// Host launcher. 11 launches. Memory timeline:
//   Sb[0,24MB): x 3-planes (xsplit3) -> dead after gemm3bf
//   d_out[0,12MB): W 3-plane sets (wsplit3T) -> dead after gemm3bf;
//                  overwritten by final gemmbf
//   Sb[0,8MB): tab (prep, after gemm3bf) -> dead after rope
//   Sb[16,24) Ih, [24,32) Ph (rope) -> dead after relmlp
//   Sb[0,16): Ssc (screen) -> dead after topk; then Vh/Vl (relmlp)
//   P region: WohT/WolT after rescore.
// ---------------------------------------------------------------------------
extern "C" void kernel_launch(void* const* d_in, const int* in_sizes, int n_in,
                              void* d_out, int out_size, void* d_ws, size_t ws_size,
                              hipStream_t stream)
{
  (void)in_sizes; (void)n_in; (void)out_size; (void)ws_size;
  const float* x   = (const float*)d_in[0];
  const float* Wi  = (const float*)d_in[1];
  const float* Wp  = (const float*)d_in[2];
  const float* pal = (const float*)d_in[3];
  const float* W1  = (const float*)d_in[4];
  const float* b1  = (const float*)d_in[5];
  const float* W2  = (const float*)d_in[6];
  const float* b2  = (const float*)d_in[7];
  const float* Wc  = (const float*)d_in[8];
  const float* bc  = (const float*)d_in[9];
  const float* Wm  = (const float*)d_in[10];
  const float* bm  = (const float*)d_in[11];
  const float* Wo  = (const float*)d_in[12];
  float* out = (float*)d_out;

  float* w = (float*)d_ws;
  float* palT = w;  w += (size_t)256 * D_DIM;
  float* I    = w;  w += (size_t)BATCH * T_LEN * D_DIM;
  float* P    = w;  w += (size_t)BATCH * T_LEN * D_DIM;
  float* Sb   = w;  w += (size_t)BATCH * T_LEN * T_LEN;
  float* nIb  = w;  w += (size_t)BATCH * T_LEN;
  float* nPb  = w;  w += (size_t)BATCH * T_LEN;
  int*   idx  = (int*)w;  w += (size_t)BATCH * T_LEN * 16;
  int*   cand = (int*)w;

  // x planes in Sb[0,24MB)
  unsigned short* Xh = (unsigned short*)Sb;
  unsigned short* Xm = Xh + (size_t)4096 * 1024;
  unsigned short* Xl = Xm + (size_t)4096 * 1024;
  // W planes in d_out (scratch until final gemmbf)
  unsigned short* WT = (unsigned short*)d_out;

  float2* tab = (float2*)Sb;
  unsigned short* Ssc = (unsigned short*)Sb;                              // [0,16MB)
  unsigned short* Ih  = (unsigned short*)(Sb + (size_t)4 * 1024 * 1024);  // [16,24MB)
  unsigned short* Ph  = Ih + (size_t)4 * 1024 * 1024;                     // [24,32MB)
  unsigned short* Vh  = (unsigned short*)Sb;                              // [0,8MB)
  unsigned short* Vl  = Vh + (size_t)4 * 1024 * 1024;                     // [8,16MB)
  unsigned short* WohT = (unsigned short*)P;
  unsigned short* WolT = WohT + (size_t)D_DIM * D_DIM;

  const int MROWS = BATCH * T_LEN;  // 4096

  // 1-2. 3-plane splits of x and Wi/Wp
  xsplit3<<<(MROWS * D_DIM) / (256 * 4), 256, 0, stream>>>(x, Xh, Xm, Xl);
  wsplit3T<<<dim3(D_DIM / 64, D_DIM / 64, 2), 256, 0, stream>>>(Wi, Wp, WT);

  // 3. I = x@Wi (z=0), P = x@Wp (z=1): 3-plane bf16 MFMA
  gemm3bf<<<dim3(D_DIM / 64, MROWS / 64, 2), 256, 0, stream>>>(
      Xh, Xm, Xl, WT, I);

  // 4. prep: trig table + palette transpose (x planes dead now)
  prep_kernel<<<T_LEN + 1024, 256, 0, stream>>>(tab, pal, palT);

  // 5. rope (+ bf16 hi-plane emit)
  rope_norm_kernel<<<MROWS, 256, 0, stream>>>(I, P, tab, nIb, nPb, Ih, Ph);

  // 6. bf16 screen GEMM -> Ssc
  screen_bf16<<<dim3(272, 1, 2), 256, 0, stream>>>(Ih, Ph, Ssc);

  // 7. top-NCAND candidates
  topk_screen<<<dim3(T_LEN / 4, BATCH), 256, 0, stream>>>(Ssc, cand);

  // 8. exact f64 rescore -> top-15 indices
  rescore_kernel<<<MROWS, 256, 0, stream>>>(I, P, cand, idx);

  // 9. Wo -> transposed bf16 planes (P dead now)
  woconvT<<<dim3(D_DIM / 64, D_DIM / 64), 256, 0, stream>>>(Wo, WohT, WolT);

  // 10. relmlp (bf16 gram inputs; writes Vh/Vl directly)
  relmlp_kernel<<<MROWS, 256, 0, stream>>>(Ih, Ph, nIb, nPb, idx,
                                           W1, b1, W2, b2, Wc, bc, Wm, bm,
                                           palT, Vh, Vl);

  // 11. out = V @ Wo via split-bf16 MFMA (overwrites the W-plane scratch)
  gemmbf<<<dim3(D_DIM / 128, MROWS / 64), 256, 0, stream>>>(
      Vh, Vl, WohT, WolT, out, D_DIM, D_DIM);
}

// Round 15
// 536.624 us; speedup vs baseline: 1.4446x; 1.0635x over previous
//
#include <hip/hip_runtime.h>
#include <math.h>

// Problem constants (fixed by the reference)
#define BATCH 2
#define T_LEN 2048
#define D_DIM 1024
#define KSEL  15
#define HIDN  64
#define NCAND 20

typedef short  bf16x8 __attribute__((ext_vector_type(8)));
typedef float  f32x4v __attribute__((ext_vector_type(4)));

__device__ __forceinline__ float geluf(float x) {
  return 0.5f * x * (1.0f + erff(x * 0.70710678118654752440f));
}

__device__ __forceinline__ unsigned short f32_to_bf16_rne(float x) {
  unsigned u = __builtin_bit_cast(unsigned, x);
  unsigned lsb = (u >> 16) & 1u;
  u += 0x7fffu + lsb;
  return (unsigned short)(u >> 16);
}
__device__ __forceinline__ float bf16_to_f32(unsigned short h) {
  unsigned u = ((unsigned)h) << 16;
  return __builtin_bit_cast(float, u);
}

// ---------------------------------------------------------------------------
// x -> 3 bf16 planes (h, m, l): x ~= h + m + l to ~2^-27 relative.
// ---------------------------------------------------------------------------
__global__ void __launch_bounds__(256) xsplit3(const float* __restrict__ X,
                                               unsigned short* __restrict__ H,
                                               unsigned short* __restrict__ M,
                                               unsigned short* __restrict__ L)
{
  const size_t i = ((size_t)blockIdx.x * 256 + threadIdx.x) * 4;
  float4 v = *(const float4*)(X + i);
  ushort4 h, m, l;
  float r;
  h.x = f32_to_bf16_rne(v.x); r = v.x - bf16_to_f32(h.x);
  m.x = f32_to_bf16_rne(r);   l.x = f32_to_bf16_rne(r - bf16_to_f32(m.x));
  h.y = f32_to_bf16_rne(v.y); r = v.y - bf16_to_f32(h.y);
  m.y = f32_to_bf16_rne(r);   l.y = f32_to_bf16_rne(r - bf16_to_f32(m.y));
  h.z = f32_to_bf16_rne(v.z); r = v.z - bf16_to_f32(h.z);
  m.z = f32_to_bf16_rne(r);   l.z = f32_to_bf16_rne(r - bf16_to_f32(m.z));
  h.w = f32_to_bf16_rne(v.w); r = v.w - bf16_to_f32(h.w);
  m.w = f32_to_bf16_rne(r);   l.w = f32_to_bf16_rne(r - bf16_to_f32(m.w));
  *(ushort4*)(H + i) = h;
  *(ushort4*)(M + i) = m;
  *(ushort4*)(L + i) = l;
}

// ---------------------------------------------------------------------------
// W (K x N, z picks Wi/Wp) -> transposed (N x K) 3 bf16 planes.
// ---------------------------------------------------------------------------
__global__ void __launch_bounds__(256) wsplit3T(const float* __restrict__ Wi,
                                                const float* __restrict__ Wp,
                                                unsigned short* __restrict__ WT)
{
  __shared__ float tile[64][65];
  const int k0 = blockIdx.y << 6, n0 = blockIdx.x << 6;
  const int z = blockIdx.z;
  const float* W = z ? Wp : Wi;
  unsigned short* H = WT + (size_t)z * 3 * 1024 * 1024;
  unsigned short* M = H + (size_t)1024 * 1024;
  unsigned short* L = M + (size_t)1024 * 1024;
  const int tid = threadIdx.x;
  for (int idx = tid; idx < 4096; idx += 256) {
    int r = idx >> 6, c = idx & 63;
    tile[r][c] = W[(size_t)(k0 + r) * D_DIM + n0 + c];
  }
  __syncthreads();
  for (int idx = tid; idx < 4096; idx += 256) {
    int n = idx >> 6, k = idx & 63;
    float v = tile[k][n];
    unsigned short h = f32_to_bf16_rne(v);
    float r1 = v - bf16_to_f32(h);
    unsigned short m = f32_to_bf16_rne(r1);
    unsigned short l = f32_to_bf16_rne(r1 - bf16_to_f32(m));
    size_t o = (size_t)(n0 + n) * D_DIM + k0 + k;
    H[o] = h; M[o] = m; L[o] = l;
  }
}

// ---------------------------------------------------------------------------
// 3-plane split-bf16 MFMA GEMM for I = x@Wi (z=0), P = x@Wp (z=1).
// (r14, unchanged — magnitude-classed accumulators, probe layout.)
// ---------------------------------------------------------------------------
__global__ void __launch_bounds__(256) gemm3bf(
    const unsigned short* __restrict__ Xh, const unsigned short* __restrict__ Xm,
    const unsigned short* __restrict__ Xl, const unsigned short* __restrict__ WT,
    float* __restrict__ C)
{
  const int m0 = blockIdx.y << 6, n0 = blockIdx.x << 6;
  const int z = blockIdx.z;
  const unsigned short* BhT = WT + (size_t)z * 3 * 1024 * 1024;
  const unsigned short* BmT = BhT + (size_t)1024 * 1024;
  const unsigned short* BlT = BmT + (size_t)1024 * 1024;
  C += (size_t)z * 4096 * 1024;
  const int N = D_DIM, K = D_DIM;

  const int tid = threadIdx.x;
  const int w = tid >> 6, lane = tid & 63;
  const int kg = lane >> 4, lm = lane & 15;
  const int am0 = (w & 1) << 5;
  const int bn0 = (w >> 1) << 5;

  __shared__ unsigned short Ah[2][64][40], Am[2][64][40], Al[2][64][40];
  __shared__ unsigned short Bh[2][64][40], Bm[2][64][40], Bl[2][64][40];

  bf16x8 ones;
#pragma unroll
  for (int e = 0; e < 8; ++e) ones[e] = (short)0x3F80;

  for (int idx = tid; idx < 2048; idx += 256) {
    Ah[0][idx >> 5][idx & 31] = f32_to_bf16_rne((float)(idx >> 5));
    Bh[0][idx >> 5][idx & 31] = f32_to_bf16_rne((float)(idx >> 5));
  }
  __syncthreads();
  int mr[4], nc[4];
  {
    bf16x8 pa = *(const bf16x8*)&Ah[0][am0 + lm][kg << 3];
    bf16x8 pb = *(const bf16x8*)&Bh[0][bn0 + lm][kg << 3];
    f32x4v d1 = {0.f, 0.f, 0.f, 0.f}, d2 = {0.f, 0.f, 0.f, 0.f};
    d1 = __builtin_amdgcn_mfma_f32_16x16x32_bf16(pa, ones, d1, 0, 0, 0);
    d2 = __builtin_amdgcn_mfma_f32_16x16x32_bf16(ones, pb, d2, 0, 0, 0);
#pragma unroll
    for (int e = 0; e < 4; ++e) {
      mr[e] = ((int)d1[e]) >> 5;
      nc[e] = ((int)d2[e]) >> 5;
    }
  }
  __syncthreads();

  f32x4v ch[2][2], cm[2][2], cl[2][2];
#pragma unroll
  for (int i = 0; i < 2; ++i)
#pragma unroll
    for (int j = 0; j < 2; ++j) {
      ch[i][j] = (f32x4v){0.f, 0.f, 0.f, 0.f};
      cm[i][j] = (f32x4v){0.f, 0.f, 0.f, 0.f};
      cl[i][j] = (f32x4v){0.f, 0.f, 0.f, 0.f};
    }

  const int ar = tid >> 2, ak8 = (tid & 3) << 3;

  bf16x8 rah, ram, ral, rbh, rbm, rbl;

  {
    size_t ao = (size_t)(m0 + ar) * K + ak8;
    size_t bo = (size_t)(n0 + ar) * K + ak8;
    rah = *(const bf16x8*)(Xh + ao); ram = *(const bf16x8*)(Xm + ao);
    ral = *(const bf16x8*)(Xl + ao);
    rbh = *(const bf16x8*)(BhT + bo); rbm = *(const bf16x8*)(BmT + bo);
    rbl = *(const bf16x8*)(BlT + bo);
  }
  *(bf16x8*)&Ah[0][ar][ak8] = rah;
  *(bf16x8*)&Am[0][ar][ak8] = ram;
  *(bf16x8*)&Al[0][ar][ak8] = ral;
  *(bf16x8*)&Bh[0][ar][ak8] = rbh;
  *(bf16x8*)&Bm[0][ar][ak8] = rbm;
  *(bf16x8*)&Bl[0][ar][ak8] = rbl;
  __syncthreads();

  int buf = 0;
  for (int k0 = 0; k0 < K; k0 += 32) {
    const bool more = (k0 + 32) < K;
    if (more) {
      const int kn = k0 + 32;
      size_t ao = (size_t)(m0 + ar) * K + kn + ak8;
      size_t bo = (size_t)(n0 + ar) * K + kn + ak8;
      rah = *(const bf16x8*)(Xh + ao); ram = *(const bf16x8*)(Xm + ao);
      ral = *(const bf16x8*)(Xl + ao);
      rbh = *(const bf16x8*)(BhT + bo); rbm = *(const bf16x8*)(BmT + bo);
      rbl = *(const bf16x8*)(BlT + bo);
    }
    {
      bf16x8 a_h[2], a_m[2], a_l[2], b_h[2], b_m[2], b_l[2];
#pragma unroll
      for (int i = 0; i < 2; ++i) {
        const int rrow = am0 + (i << 4) + lm;
        a_h[i] = *(const bf16x8*)&Ah[buf][rrow][kg << 3];
        a_m[i] = *(const bf16x8*)&Am[buf][rrow][kg << 3];
        a_l[i] = *(const bf16x8*)&Al[buf][rrow][kg << 3];
        const int nrow = bn0 + (i << 4) + lm;
        b_h[i] = *(const bf16x8*)&Bh[buf][nrow][kg << 3];
        b_m[i] = *(const bf16x8*)&Bm[buf][nrow][kg << 3];
        b_l[i] = *(const bf16x8*)&Bl[buf][nrow][kg << 3];
      }
#pragma unroll
      for (int i = 0; i < 2; ++i)
#pragma unroll
        for (int j = 0; j < 2; ++j) {
          ch[i][j] = __builtin_amdgcn_mfma_f32_16x16x32_bf16(a_h[i], b_h[j], ch[i][j], 0, 0, 0);
          cm[i][j] = __builtin_amdgcn_mfma_f32_16x16x32_bf16(a_h[i], b_m[j], cm[i][j], 0, 0, 0);
          cm[i][j] = __builtin_amdgcn_mfma_f32_16x16x32_bf16(a_m[i], b_h[j], cm[i][j], 0, 0, 0);
          cl[i][j] = __builtin_amdgcn_mfma_f32_16x16x32_bf16(a_h[i], b_l[j], cl[i][j], 0, 0, 0);
          cl[i][j] = __builtin_amdgcn_mfma_f32_16x16x32_bf16(a_m[i], b_m[j], cl[i][j], 0, 0, 0);
          cl[i][j] = __builtin_amdgcn_mfma_f32_16x16x32_bf16(a_l[i], b_h[j], cl[i][j], 0, 0, 0);
        }
    }
    if (more) {
      const int nb = buf ^ 1;
      *(bf16x8*)&Ah[nb][ar][ak8] = rah;
      *(bf16x8*)&Am[nb][ar][ak8] = ram;
      *(bf16x8*)&Al[nb][ar][ak8] = ral;
      *(bf16x8*)&Bh[nb][ar][ak8] = rbh;
      *(bf16x8*)&Bm[nb][ar][ak8] = rbm;
      *(bf16x8*)&Bl[nb][ar][ak8] = rbl;
    }
    __syncthreads();
    buf ^= 1;
  }

#pragma unroll
  for (int i = 0; i < 2; ++i)
#pragma unroll
    for (int j = 0; j < 2; ++j)
#pragma unroll
      for (int e = 0; e < 4; ++e) {
        const int rrow = m0 + mr[e] + (i << 4);
        const int ccol = n0 + nc[e] + (j << 4);
        float v = (ch[i][j][e] + cm[i][j][e]) + cl[i][j][e];
        C[(size_t)rrow * N + ccol] = v;
      }
}

// ---------------------------------------------------------------------------
// PREP (fused): trig table (EXACT reference f32 bits — selection-critical)
// + palette transpose.
// ---------------------------------------------------------------------------
__global__ void __launch_bounds__(256) prep_kernel(float2* __restrict__ tab,
                                                   const float* __restrict__ pal,
                                                   float* __restrict__ palT)
{
  const int b = blockIdx.x;
  if (b < T_LEN) {
    const int t = b;
    for (int j = threadIdx.x; j < 512; j += 256) {
      double e = (double)j * (1.0 / 512.0);
      float pf = (float)pow(10000.0, e);
      float invf = 1.0f / pf;
      float angf = (float)t * invf;
      double s64, c64;
      sincos((double)angf, &s64, &c64);
      tab[(size_t)t * 512 + j] = make_float2((float)c64, (float)s64);
    }
  } else {
    const int bb = b - T_LEN;
    const int c = bb & 255, dg = bb >> 8;
    const int d = dg * 256 + threadIdx.x;
    palT[(size_t)c * D_DIM + d] = pal[(size_t)d * 256 + c];
  }
}

// ---------------------------------------------------------------------------
// RoPE in place + row L2 norms + bf16 hi planes Ih/Ph (fused emit).
// f32 rotation math unchanged — selection-critical.
// ---------------------------------------------------------------------------
__global__ void __launch_bounds__(256) rope_norm_kernel(
    float* __restrict__ bI, float* __restrict__ bP,
    const float2* __restrict__ tab,
    float* __restrict__ nI, float* __restrict__ nP,
    unsigned short* __restrict__ Ih, unsigned short* __restrict__ Ph)
{
  const int row = blockIdx.x;
  const int t = row & (T_LEN - 1);
  const int tid = threadIdx.x;
  __shared__ double redI[4], redP[4];
  double ssI = 0.0, ssP = 0.0;
  const size_t off = (size_t)row * D_DIM;
  for (int j = tid; j < 512; j += 256) {
    float2 cs = tab[(size_t)t * 512 + j];
    float c = cs.x, s = cs.y;

    float a1 = bI[off + j], a2 = bI[off + 512 + j];
    float o1 = __fsub_rn(__fmul_rn(a1, c), __fmul_rn(a2, s));
    float o2 = __fadd_rn(__fmul_rn(a1, s), __fmul_rn(a2, c));
    bI[off + j] = o1; bI[off + 512 + j] = o2;
    Ih[off + j] = f32_to_bf16_rne(o1); Ih[off + 512 + j] = f32_to_bf16_rne(o2);
    ssI += (double)o1 * o1 + (double)o2 * o2;

    float p1 = bP[off + j], p2 = bP[off + 512 + j];
    float q1 = __fsub_rn(__fmul_rn(p1, c), __fmul_rn(p2, s));
    float q2 = __fadd_rn(__fmul_rn(p1, s), __fmul_rn(p2, c));
    bP[off + j] = q1; bP[off + 512 + j] = q2;
    Ph[off + j] = f32_to_bf16_rne(q1); Ph[off + 512 + j] = f32_to_bf16_rne(q2);
    ssP += (double)q1 * q1 + (double)q2 * q2;
  }
#pragma unroll
  for (int o = 32; o >= 1; o >>= 1) { ssI += __shfl_xor(ssI, o); ssP += __shfl_xor(ssP, o); }
  if ((tid & 63) == 0) { redI[tid >> 6] = ssI; redP[tid >> 6] = ssP; }
  __syncthreads();
  if (tid == 0) {
    nI[row] = fmaxf((float)sqrt(redI[0] + redI[1] + redI[2] + redI[3]), 1e-12f);
    nP[row] = fmaxf((float)sqrt(redP[0] + redP[1] + redP[2] + redP[3]), 1e-12f);
  }
}

// ---------------------------------------------------------------------------
// bf16 SCREEN for S (candidates only; exact rescore follows). (unchanged.)
// ---------------------------------------------------------------------------
__global__ void __launch_bounds__(256) screen_bf16(
    const unsigned short* __restrict__ Ih, const unsigned short* __restrict__ Ph,
    unsigned short* __restrict__ Ssc)
{
  int rem = blockIdx.x, bi = 0;
  while (rem >= (bi >> 1) + 1) { rem -= (bi >> 1) + 1; ++bi; }
  const int m0 = bi << 6, n0 = rem << 7;
  const int z = blockIdx.z;
  const unsigned short* A = Ih + (size_t)z * T_LEN * D_DIM;
  const unsigned short* B = Ph + (size_t)z * T_LEN * D_DIM;
  unsigned short* C = Ssc + (size_t)z * T_LEN * T_LEN;
  const int N = T_LEN, K = D_DIM;

  const int tid = threadIdx.x;
  const int w = tid >> 6, lane = tid & 63;
  const int kg = lane >> 4, lm = lane & 15;
  const int am0 = (w & 1) << 5;
  const int bn0 = (w >> 1) << 6;

  __shared__ unsigned short As_h[2][64][40];
  __shared__ unsigned short Bs_h[2][128][40];

  bf16x8 ones;
#pragma unroll
  for (int e = 0; e < 8; ++e) ones[e] = (short)0x3F80;

  for (int idx = tid; idx < 2048; idx += 256)
    As_h[0][idx >> 5][idx & 31] = f32_to_bf16_rne((float)(idx >> 5));
  for (int idx = tid; idx < 4096; idx += 256)
    Bs_h[0][idx >> 5][idx & 31] = f32_to_bf16_rne((float)(idx >> 5));
  __syncthreads();
  int mr[4], nc[4];
  {
    bf16x8 pa = *(const bf16x8*)&As_h[0][am0 + lm][kg << 3];
    bf16x8 pb = *(const bf16x8*)&Bs_h[0][bn0 + lm][kg << 3];
    f32x4v d1 = {0.f, 0.f, 0.f, 0.f}, d2 = {0.f, 0.f, 0.f, 0.f};
    d1 = __builtin_amdgcn_mfma_f32_16x16x32_bf16(pa, ones, d1, 0, 0, 0);
    d2 = __builtin_amdgcn_mfma_f32_16x16x32_bf16(ones, pb, d2, 0, 0, 0);
#pragma unroll
    for (int e = 0; e < 4; ++e) {
      mr[e] = ((int)d1[e]) >> 5;
      nc[e] = ((int)d2[e]) >> 5;
    }
  }
  __syncthreads();

  f32x4v c00 = {0,0,0,0}, c01 = {0,0,0,0}, c02 = {0,0,0,0}, c03 = {0,0,0,0};
  f32x4v c10 = {0,0,0,0}, c11 = {0,0,0,0}, c12 = {0,0,0,0}, c13 = {0,0,0,0};

  const int ar  = tid >> 2, ak8 = (tid & 3) << 3;
  const int bna = tid >> 2, bnb = 64 + (tid >> 2), bk8 = (tid & 3) << 3;

  bf16x8 ra, rb0, rb1;

  ra  = *(const bf16x8*)(A + (size_t)(m0 + ar) * K + ak8);
  rb0 = *(const bf16x8*)(B + (size_t)(n0 + bna) * K + bk8);
  rb1 = *(const bf16x8*)(B + (size_t)(n0 + bnb) * K + bk8);
  *(bf16x8*)&As_h[0][ar][ak8]  = ra;
  *(bf16x8*)&Bs_h[0][bna][bk8] = rb0;
  *(bf16x8*)&Bs_h[0][bnb][bk8] = rb1;
  __syncthreads();

  int buf = 0;
  for (int k0 = 0; k0 < K; k0 += 32) {
    const bool more = (k0 + 32) < K;
    if (more) {
      const int kn = k0 + 32;
      ra  = *(const bf16x8*)(A + (size_t)(m0 + ar) * K + kn + ak8);
      rb0 = *(const bf16x8*)(B + (size_t)(n0 + bna) * K + kn + bk8);
      rb1 = *(const bf16x8*)(B + (size_t)(n0 + bnb) * K + kn + bk8);
    }
    {
      bf16x8 a0 = *(const bf16x8*)&As_h[buf][am0 + lm][kg << 3];
      bf16x8 a1 = *(const bf16x8*)&As_h[buf][am0 + 16 + lm][kg << 3];
      bf16x8 b0 = *(const bf16x8*)&Bs_h[buf][bn0 + lm][kg << 3];
      bf16x8 b1 = *(const bf16x8*)&Bs_h[buf][bn0 + 16 + lm][kg << 3];
      bf16x8 b2 = *(const bf16x8*)&Bs_h[buf][bn0 + 32 + lm][kg << 3];
      bf16x8 b3 = *(const bf16x8*)&Bs_h[buf][bn0 + 48 + lm][kg << 3];
      c00 = __builtin_amdgcn_mfma_f32_16x16x32_bf16(a0, b0, c00, 0, 0, 0);
      c01 = __builtin_amdgcn_mfma_f32_16x16x32_bf16(a0, b1, c01, 0, 0, 0);
      c02 = __builtin_amdgcn_mfma_f32_16x16x32_bf16(a0, b2, c02, 0, 0, 0);
      c03 = __builtin_amdgcn_mfma_f32_16x16x32_bf16(a0, b3, c03, 0, 0, 0);
      c10 = __builtin_amdgcn_mfma_f32_16x16x32_bf16(a1, b0, c10, 0, 0, 0);
      c11 = __builtin_amdgcn_mfma_f32_16x16x32_bf16(a1, b1, c11, 0, 0, 0);
      c12 = __builtin_amdgcn_mfma_f32_16x16x32_bf16(a1, b2, c12, 0, 0, 0);
      c13 = __builtin_amdgcn_mfma_f32_16x16x32_bf16(a1, b3, c13, 0, 0, 0);
    }
    if (more) {
      const int nb = buf ^ 1;
      *(bf16x8*)&As_h[nb][ar][ak8]  = ra;
      *(bf16x8*)&Bs_h[nb][bna][bk8] = rb0;
      *(bf16x8*)&Bs_h[nb][bnb][bk8] = rb1;
    }
    __syncthreads();
    buf ^= 1;
  }

#pragma unroll
  for (int e = 0; e < 4; ++e) {
    const size_t r0 = (size_t)(m0 + mr[e]) * N;
    const size_t r1 = r0 + (size_t)16 * N;
    const int c = n0 + nc[e];
    C[r0 + c +  0] = f32_to_bf16_rne(c00[e]);
    C[r0 + c + 16] = f32_to_bf16_rne(c01[e]);
    C[r0 + c + 32] = f32_to_bf16_rne(c02[e]);
    C[r0 + c + 48] = f32_to_bf16_rne(c03[e]);
    C[r1 + c +  0] = f32_to_bf16_rne(c10[e]);
    C[r1 + c + 16] = f32_to_bf16_rne(c11[e]);
    C[r1 + c + 32] = f32_to_bf16_rne(c12[e]);
    C[r1 + c + 48] = f32_to_bf16_rne(c13[e]);
  }
}

// ---------------------------------------------------------------------------
// Top-NCAND screen candidates per causal row (bf16 S). -1 = invalid.
// ---------------------------------------------------------------------------
__global__ void __launch_bounds__(256) topk_screen(const unsigned short* __restrict__ Ssc,
                                                   int* __restrict__ cand)
{
  const int b = blockIdx.y;
  const unsigned short* S = Ssc + (size_t)b * T_LEN * T_LEN;
  const int wave = threadIdx.x >> 6, lane = threadIdx.x & 63;
  const int t = blockIdx.x * 4 + wave;
  const unsigned short* rowp = S + (size_t)t * T_LEN;
  float v[32];
#pragma unroll
  for (int i = 0; i < 32; ++i) {
    int s = lane + (i << 6);
    v[i] = (s <= t) ? bf16_to_f32(rowp[s]) : -INFINITY;
  }
  float pv = INFINITY; int pidx = -1;
  int* outp = cand + ((size_t)b * T_LEN + t) * NCAND;
  for (int k = 0; k < NCAND; ++k) {
    float bv = -INFINITY; int bi = 0x7fffffff;
#pragma unroll
    for (int i = 0; i < 32; ++i) {
      int s = lane + (i << 6);
      float vv = v[i];
      bool elig = (vv < pv) || (vv == pv && s > pidx);
      if (elig && vv > bv) { bv = vv; bi = s; }
    }
#pragma unroll
    for (int o = 32; o >= 1; o >>= 1) {
      float ov = __shfl_xor(bv, o);
      int oi = __shfl_xor(bi, o);
      if (ov > bv || (ov == bv && oi < bi)) { bv = ov; bi = oi; }
    }
    pv = bv; pidx = bi;
    if (lane == 0) outp[k] = (bi == 0x7fffffff || bv == -INFINITY) ? -1 : bi;
  }
}

// ---------------------------------------------------------------------------
// Exact rescore: f64 dot of I_t with each candidate P row (f32 arrays),
// rounded to f32 after the 2^-5 scale, tie -> lower index, top-15 -> idx.
// ---------------------------------------------------------------------------
__global__ void __launch_bounds__(256) rescore_kernel(
    const float* __restrict__ I, const float* __restrict__ P,
    const int* __restrict__ cand, int* __restrict__ idx)
{
  const int row = blockIdx.x;
  const int base = row & ~(T_LEN - 1);
  const int tid = threadIdx.x;
  const int w = tid >> 6, lane = tid & 63;

  __shared__ float valS[NCAND];
  __shared__ int   sidxS[NCAND];
  __shared__ int   candS[NCAND];

  if (tid < NCAND) candS[tid] = cand[(size_t)row * NCAND + tid];
  __syncthreads();

  double iv[16];
  const float* irow = I + (size_t)row * D_DIM;
#pragma unroll
  for (int j = 0; j < 16; ++j) iv[j] = (double)irow[lane + (j << 6)];

  for (int c = w; c < NCAND; c += 4) {
    int s = candS[c];
    double acc = 0.0;
    if (s >= 0) {
      const float* prow = P + ((size_t)base + s) * D_DIM;
#pragma unroll
      for (int j = 0; j < 16; ++j)
        acc = fma(iv[j], (double)prow[lane + (j << 6)], acc);
    }
#pragma unroll
    for (int o = 32; o >= 1; o >>= 1) acc += __shfl_xor(acc, o);
    if (lane == 0) {
      valS[c] = (s >= 0) ? (float)(acc * 0.03125) : -INFINITY;
      sidxS[c] = s;
    }
  }
  __syncthreads();
  if (tid == 0) {
    bool taken[NCAND];
#pragma unroll
    for (int c = 0; c < NCAND; ++c) taken[c] = false;
    int* outp = idx + (size_t)row * 16;
    for (int k = 0; k < KSEL; ++k) {
      float best = -INFINITY; int bidx = 0x7fffffff; int bc = -1;
      for (int c = 0; c < NCAND; ++c) {
        if (taken[c] || sidxS[c] < 0) continue;
        float v = valS[c];
        if (v > best || (v == best && sidxS[c] < bidx)) { best = v; bidx = sidxS[c]; bc = c; }
      }
      if (bc >= 0) { taken[bc] = true; outp[k] = bidx; }
      else outp[k] = 0;
    }
  }
}

// ---------------------------------------------------------------------------
// Wo (K x N) -> transposed bf16 hi/lo planes (N x K). After rescore (P dead).
// ---------------------------------------------------------------------------
__global__ void __launch_bounds__(256) woconvT(const float* __restrict__ Wo,
                                               unsigned short* __restrict__ HT,
                                               unsigned short* __restrict__ LT)
{
  __shared__ float tile[64][65];
  const int k0 = blockIdx.y << 6, n0 = blockIdx.x << 6;
  const int tid = threadIdx.x;
  for (int idx = tid; idx < 4096; idx += 256) {
    int r = idx >> 6, c = idx & 63;
    tile[r][c] = Wo[(size_t)(k0 + r) * D_DIM + n0 + c];
  }
  __syncthreads();
  for (int idx = tid; idx < 4096; idx += 256) {
    int n = idx >> 6, k = idx & 63;
    float v = tile[k][n];
    unsigned short h = f32_to_bf16_rne(v);
    HT[(size_t)(n0 + n) * D_DIM + k0 + k] = h;
    LT[(size_t)(n0 + n) * D_DIM + k0 + k] = f32_to_bf16_rne(v - bf16_to_f32(h));
  }
}

// ---------------------------------------------------------------------------
// Per-(b,t): gather (bf16 Ih/Ph) + MFMA GRAM (one wave, 32x 16x16x32 bf16,
// probe-based output layout — replaces r14's 136-thread serial dot loops)
// + rel features + MLP + heads + softmax + bilinear palette blend -> V
// bf16 hi/lo planes.
// ---------------------------------------------------------------------------
__global__ void __launch_bounds__(256) relmlp_kernel(
    const unsigned short* __restrict__ Ih, const unsigned short* __restrict__ Ph,
    const float* __restrict__ nI, const float* __restrict__ nP,
    const int* __restrict__ topk,
    const float* __restrict__ W1, const float* __restrict__ b1,
    const float* __restrict__ W2, const float* __restrict__ b2,
    const float* __restrict__ Wc, const float* __restrict__ bc,
    const float* __restrict__ Wm, const float* __restrict__ bm,
    const float* __restrict__ palT,
    unsigned short* __restrict__ Vh, unsigned short* __restrict__ Vl)
{
  const int row = blockIdx.x;
  const int t = row & (T_LEN - 1);
  const int base = row & ~(T_LEN - 1);
  const int nk = (t + 1 < KSEL) ? (t + 1) : KSEL;
  const int tid = threadIdx.x;
  const int lane = tid & 63;

  __shared__ unsigned short vecU[16][1032];   // bf16 rows, +8 pad (2-way conflict, ~free)
  __shared__ unsigned short pb[16][36];       // probe buffer
  __shared__ float gS[16][16];
  __shared__ float relS[KSEL][17];
  __shared__ float h1S[KSEL][HIDN];
  __shared__ float h2S[KSEL][HIDN];
  __shared__ float nrmS[16];
  __shared__ int   sidxS[16];
  __shared__ float mixS[KSEL], wS[KSEL], zxS[KSEL], zyS[KSEL];
  __shared__ float coefS[4 * KSEL];
  __shared__ int   cellS[4 * KSEL];

  if (tid < 16) {
    int s = t;
    if (tid >= 1) s = (tid <= nk) ? topk[(size_t)row * 16 + (tid - 1)] : 0;
    sidxS[tid] = s;
    nrmS[tid] = (tid == 0) ? nI[row] : nP[base + s];
  }
  if (tid < 64) {
#pragma unroll
    for (int i = 0; i < 8; ++i) {
      int e = (tid << 3) + i;          // 0..511
      pb[e >> 5][e & 31] = f32_to_bf16_rne((float)(e >> 5));
    }
  }
  __syncthreads();

  // stage 16 rows x 1024 bf16 (2048 ushort8 chunks; 8 per thread).
  // rows > nk zero-filled so masked gram outputs can't be NaN.
#pragma unroll
  for (int i = 0; i < 8; ++i) {
    int c = (tid << 3) + i;            // chunk id 0..2047
    int rr = c >> 7;
    int off = (c & 127) << 3;
    bf16x8 v = {0, 0, 0, 0, 0, 0, 0, 0};
    if (rr <= nk) {
      const unsigned short* src = (rr == 0)
          ? (Ih + (size_t)row * D_DIM)
          : (Ph + ((size_t)base + sidxS[rr]) * D_DIM);
      v = *(const bf16x8*)(src + off);
    }
    *(bf16x8*)&vecU[rr][off] = v;
  }
  __syncthreads();

  // ---- MFMA gram (wave 0 only): G = V V^T, V = vecU (16 x 1024) ----
  if (tid < 64) {
    const int lm = lane & 15, kg = lane >> 4;
    bf16x8 ones;
#pragma unroll
    for (int e = 0; e < 8; ++e) ones[e] = (short)0x3F80;
    bf16x8 pa = *(const bf16x8*)&pb[lm][kg << 3];
    f32x4v d1 = {0.f, 0.f, 0.f, 0.f}, d2 = {0.f, 0.f, 0.f, 0.f};
    d1 = __builtin_amdgcn_mfma_f32_16x16x32_bf16(pa, ones, d1, 0, 0, 0);
    d2 = __builtin_amdgcn_mfma_f32_16x16x32_bf16(ones, pa, d2, 0, 0, 0);
    int mr[4], nc[4];
#pragma unroll
    for (int e = 0; e < 4; ++e) {
      mr[e] = ((int)d1[e]) >> 5;
      nc[e] = ((int)d2[e]) >> 5;
    }
    f32x4v acc = {0.f, 0.f, 0.f, 0.f};
#pragma unroll
    for (int ks = 0; ks < 32; ++ks) {
      bf16x8 a = *(const bf16x8*)&vecU[lm][(ks << 5) + (kg << 3)];
      acc = __builtin_amdgcn_mfma_f32_16x16x32_bf16(a, a, acc, 0, 0, 0);
    }
#pragma unroll
    for (int e = 0; e < 4; ++e) {
      int pi2 = mr[e], pj2 = nc[e];
      float g = 0.f;
      if (pi2 <= nk && pj2 <= nk) {
        g = acc[e] / (nrmS[pi2] * nrmS[pj2]);
        g = fminf(fmaxf(g, -1.f), 1.f);
      }
      gS[pi2][pj2] = g;
    }
  }
  __syncthreads();

  if (tid < KSEL * 17) {
    int k = tid / 17, f = tid % 17;
    float v = 0.f;
    if (k < nk) {
      if (f < KSEL)        v = (f < nk) ? gS[k + 1][f + 1] : 0.f;
      else if (f == KSEL)  v = gS[0][k + 1];
      else                 v = (float)(t - sidxS[k + 1]) * (1.0f / (float)T_LEN);
    }
    relS[k][f] = v;
  }
  __syncthreads();

  for (int o = tid; o < KSEL * HIDN; o += 256) {
    int k = o >> 6, m = o & 63;
    float a = b1[m];
#pragma unroll
    for (int f = 0; f < 17; ++f) a = fmaf(relS[k][f], W1[f * HIDN + m], a);
    h1S[k][m] = geluf(a);
  }
  __syncthreads();
  for (int o = tid; o < KSEL * HIDN; o += 256) {
    int k = o >> 6, m = o & 63;
    float a = b2[m];
#pragma unroll 8
    for (int n = 0; n < HIDN; ++n) a = fmaf(h1S[k][n], W2[n * HIDN + m], a);
    h2S[k][m] = geluf(a);
  }
  __syncthreads();
  if (tid < KSEL) {
    float a0 = 0.f, a1 = 0.f, am = 0.f;
#pragma unroll 8
    for (int n = 0; n < HIDN; ++n) {
      float h = h2S[tid][n];
      a0 = fmaf(h, Wc[n * 2 + 0], a0);
      a1 = fmaf(h, Wc[n * 2 + 1], a1);
      am = fmaf(h, Wm[n], am);
    }
    zxS[tid] = tanhf(a0 + bc[0]);
    zyS[tid] = tanhf(a1 + bc[1]);
    mixS[tid] = am + bm[0];
  }
  __syncthreads();
  if (tid == 0) {
    float mx = -INFINITY;
    for (int k = 0; k < nk; ++k) mx = fmaxf(mx, mixS[k]);
    float ssum = 0.f;
    for (int k = 0; k < nk; ++k) { float e = expf(mixS[k] - mx); wS[k] = e; ssum += e; }
    float inv = 1.f / ssum;
    for (int k = 0; k < nk; ++k) wS[k] *= inv;
  }
  __syncthreads();
  if (tid < KSEL) {
    int k = tid;
    if (k < nk) {
      float w = wS[k];
      float fx = fminf(fmaxf((zxS[k] + 1.f) * 0.5f * 15.f, 0.f), 15.f);
      float fy = fminf(fmaxf((zyS[k] + 1.f) * 0.5f * 15.f, 0.f), 15.f);
      int x0 = (int)floorf(fx); int x1i = (x0 + 1 < 15) ? x0 + 1 : 15;
      int y0 = (int)floorf(fy); int y1i = (y0 + 1 < 15) ? y0 + 1 : 15;
      float wx = fx - (float)x0, wy = fy - (float)y0;
      cellS[k * 4 + 0] = y0 * 16 + x0;   coefS[k * 4 + 0] = w * (1.f - wy) * (1.f - wx);
      cellS[k * 4 + 1] = y0 * 16 + x1i;  coefS[k * 4 + 1] = w * (1.f - wy) * wx;
      cellS[k * 4 + 2] = y1i * 16 + x0;  coefS[k * 4 + 2] = w * wy * (1.f - wx);
      cellS[k * 4 + 3] = y1i * 16 + x1i; coefS[k * 4 + 3] = w * wy * wx;
    } else {
      cellS[k * 4 + 0] = cellS[k * 4 + 1] = cellS[k * 4 + 2] = cellS[k * 4 + 3] = 0;
      coefS[k * 4 + 0] = coefS[k * 4 + 1] = coefS[k * 4 + 2] = coefS[k * 4 + 3] = 0.f;
    }
  }
  __syncthreads();
  const int nj = 4 * nk;
  for (int d = tid; d < D_DIM; d += 256) {
    float a = 0.f;
    for (int j = 0; j < nj; ++j)
      a = fmaf(coefS[j], palT[(size_t)cellS[j] * D_DIM + d], a);
    unsigned short h = f32_to_bf16_rne(a);
    Vh[(size_t)row * D_DIM + d] = h;
    Vl[(size_t)row * D_DIM + d] = f32_to_bf16_rne(a - bf16_to_f32(h));
  }
}

// ---------------------------------------------------------------------------
// Split-bf16 MFMA GEMM for out = V @ Wo. (r10, unchanged.)
// ---------------------------------------------------------------------------
__global__ void __launch_bounds__(256) gemmbf(
    const unsigned short* __restrict__ Ah, const unsigned short* __restrict__ Al,
    const unsigned short* __restrict__ BhT, const unsigned short* __restrict__ BlT,
    float* __restrict__ C, int N, int K)
{
  const int m0 = blockIdx.y << 6, n0 = blockIdx.x << 7;
  const int tid = threadIdx.x;
  const int w = tid >> 6, lane = tid & 63;
  const int kg = lane >> 4, lm = lane & 15;
  const int am0 = (w & 1) << 5;
  const int bn0 = (w >> 1) << 6;

  __shared__ unsigned short As_h[2][64][40],  As_l[2][64][40];
  __shared__ unsigned short Bs_h[2][128][40], Bs_l[2][128][40];

  bf16x8 ones;
#pragma unroll
  for (int e = 0; e < 8; ++e) ones[e] = (short)0x3F80;

  for (int idx = tid; idx < 2048; idx += 256)
    As_h[0][idx >> 5][idx & 31] = f32_to_bf16_rne((float)(idx >> 5));
  for (int idx = tid; idx < 4096; idx += 256)
    Bs_h[0][idx >> 5][idx & 31] = f32_to_bf16_rne((float)(idx >> 5));
  __syncthreads();
  int mr[4], nc[4];
  {
    bf16x8 pa = *(const bf16x8*)&As_h[0][am0 + lm][kg << 3];
    bf16x8 pb = *(const bf16x8*)&Bs_h[0][bn0 + lm][kg << 3];
    f32x4v d1 = {0.f, 0.f, 0.f, 0.f}, d2 = {0.f, 0.f, 0.f, 0.f};
    d1 = __builtin_amdgcn_mfma_f32_16x16x32_bf16(pa, ones, d1, 0, 0, 0);
    d2 = __builtin_amdgcn_mfma_f32_16x16x32_bf16(ones, pb, d2, 0, 0, 0);
#pragma unroll
    for (int e = 0; e < 4; ++e) {
      mr[e] = ((int)d1[e]) >> 5;
      nc[e] = ((int)d2[e]) >> 5;
    }
  }
  __syncthreads();

  f32x4v c00 = {0,0,0,0}, c01 = {0,0,0,0}, c02 = {0,0,0,0}, c03 = {0,0,0,0};
  f32x4v c10 = {0,0,0,0}, c11 = {0,0,0,0}, c12 = {0,0,0,0}, c13 = {0,0,0,0};

  const int ar  = tid >> 2, ak8 = (tid & 3) << 3;
  const int bna = tid >> 2, bnb = 64 + (tid >> 2), bk8 = (tid & 3) << 3;

  bf16x8 rah, ral, rbh0, rbl0, rbh1, rbl1;

  rah  = *(const bf16x8*)(Ah  + (size_t)(m0 + ar) * K + ak8);
  ral  = *(const bf16x8*)(Al  + (size_t)(m0 + ar) * K + ak8);
  rbh0 = *(const bf16x8*)(BhT + (size_t)(n0 + bna) * K + bk8);
  rbl0 = *(const bf16x8*)(BlT + (size_t)(n0 + bna) * K + bk8);
  rbh1 = *(const bf16x8*)(BhT + (size_t)(n0 + bnb) * K + bk8);
  rbl1 = *(const bf16x8*)(BlT + (size_t)(n0 + bnb) * K + bk8);
  *(bf16x8*)&As_h[0][ar][ak8]  = rah;
  *(bf16x8*)&As_l[0][ar][ak8]  = ral;
  *(bf16x8*)&Bs_h[0][bna][bk8] = rbh0;
  *(bf16x8*)&Bs_l[0][bna][bk8] = rbl0;
  *(bf16x8*)&Bs_h[0][bnb][bk8] = rbh1;
  *(bf16x8*)&Bs_l[0][bnb][bk8] = rbl1;
  __syncthreads();

  int buf = 0;
  for (int k0 = 0; k0 < K; k0 += 32) {
    const bool more = (k0 + 32) < K;
    if (more) {
      const int kn = k0 + 32;
      rah  = *(const bf16x8*)(Ah  + (size_t)(m0 + ar) * K + kn + ak8);
      ral  = *(const bf16x8*)(Al  + (size_t)(m0 + ar) * K + kn + ak8);
      rbh0 = *(const bf16x8*)(BhT + (size_t)(n0 + bna) * K + kn + bk8);
      rbl0 = *(const bf16x8*)(BlT + (size_t)(n0 + bna) * K + kn + bk8);
      rbh1 = *(const bf16x8*)(BhT + (size_t)(n0 + bnb) * K + kn + bk8);
      rbl1 = *(const bf16x8*)(BlT + (size_t)(n0 + bnb) * K + kn + bk8);
    }
    {
      bf16x8 ah0 = *(const bf16x8*)&As_h[buf][am0 + lm][kg << 3];
      bf16x8 ah1 = *(const bf16x8*)&As_h[buf][am0 + 16 + lm][kg << 3];
      bf16x8 al0 = *(const bf16x8*)&As_l[buf][am0 + lm][kg << 3];
      bf16x8 al1 = *(const bf16x8*)&As_l[buf][am0 + 16 + lm][kg << 3];
      bf16x8 bh0 = *(const bf16x8*)&Bs_h[buf][bn0 + lm][kg << 3];
      bf16x8 bh1 = *(const bf16x8*)&Bs_h[buf][bn0 + 16 + lm][kg << 3];
      bf16x8 bh2 = *(const bf16x8*)&Bs_h[buf][bn0 + 32 + lm][kg << 3];
      bf16x8 bh3 = *(const bf16x8*)&Bs_h[buf][bn0 + 48 + lm][kg << 3];
      bf16x8 bl0 = *(const bf16x8*)&Bs_l[buf][bn0 + lm][kg << 3];
      bf16x8 bl1 = *(const bf16x8*)&Bs_l[buf][bn0 + 16 + lm][kg << 3];
      bf16x8 bl2 = *(const bf16x8*)&Bs_l[buf][bn0 + 32 + lm][kg << 3];
      bf16x8 bl3 = *(const bf16x8*)&Bs_l[buf][bn0 + 48 + lm][kg << 3];

      c00 = __builtin_amdgcn_mfma_f32_16x16x32_bf16(ah0, bh0, c00, 0, 0, 0);
      c01 = __builtin_amdgcn_mfma_f32_16x16x32_bf16(ah0, bh1, c01, 0, 0, 0);
      c02 = __builtin_amdgcn_mfma_f32_16x16x32_bf16(ah0, bh2, c02, 0, 0, 0);
      c03 = __builtin_amdgcn_mfma_f32_16x16x32_bf16(ah0, bh3, c03, 0, 0, 0);
      c10 = __builtin_amdgcn_mfma_f32_16x16x32_bf16(ah1, bh0, c10, 0, 0, 0);
      c11 = __builtin_amdgcn_mfma_f32_16x16x32_bf16(ah1, bh1, c11, 0, 0, 0);
      c12 = __builtin_amdgcn_mfma_f32_16x16x32_bf16(ah1, bh2, c12, 0, 0, 0);
      c13 = __builtin_amdgcn_mfma_f32_16x16x32_bf16(ah1, bh3, c13, 0, 0, 0);

      c00 = __builtin_amdgcn_mfma_f32_16x16x32_bf16(ah0, bl0, c00, 0, 0, 0);
      c01 = __builtin_amdgcn_mfma_f32_16x16x32_bf16(ah0, bl1, c01, 0, 0, 0);
      c02 = __builtin_amdgcn_mfma_f32_16x16x32_bf16(ah0, bl2, c02, 0, 0, 0);
      c03 = __builtin_amdgcn_mfma_f32_16x16x32_bf16(ah0, bl3, c03, 0, 0, 0);
      c10 = __builtin_amdgcn_mfma_f32_16x16x32_bf16(ah1, bl0, c10, 0, 0, 0);
      c11 = __builtin_amdgcn_mfma_f32_16x16x32_bf16(ah1, bl1, c11, 0, 0, 0);
      c12 = __builtin_amdgcn_mfma_f32_16x16x32_bf16(ah1, bl2, c12, 0, 0, 0);
      c13 = __builtin_amdgcn_mfma_f32_16x16x32_bf16(ah1, bl3, c13, 0, 0, 0);

      c00 = __builtin_amdgcn_mfma_f32_16x16x32_bf16(al0, bh0, c00, 0, 0, 0);
      c01 = __builtin_amdgcn_mfma_f32_16x16x32_bf16(al0, bh1, c01, 0, 0, 0);
      c02 = __builtin_amdgcn_mfma_f32_16x16x32_bf16(al0, bh2, c02, 0, 0, 0);
      c03 = __builtin_amdgcn_mfma_f32_16x16x32_bf16(al0, bh3, c03, 0, 0, 0);
      c10 = __builtin_amdgcn_mfma_f32_16x16x32_bf16(al1, bh0, c10, 0, 0, 0);
      c11 = __builtin_amdgcn_mfma_f32_16x16x32_bf16(al1, bh1, c11, 0, 0, 0);
      c12 = __builtin_amdgcn_mfma_f32_16x16x32_bf16(al1, bh2, c12, 0, 0, 0);
      c13 = __builtin_amdgcn_mfma_f32_16x16x32_bf16(al1, bh3, c13, 0, 0, 0);
    }
    if (more) {
      const int nb = buf ^ 1;
      *(bf16x8*)&As_h[nb][ar][ak8]  = rah;
      *(bf16x8*)&As_l[nb][ar][ak8]  = ral;
      *(bf16x8*)&Bs_h[nb][bna][bk8] = rbh0;
      *(bf16x8*)&Bs_l[nb][bna][bk8] = rbl0;
      *(bf16x8*)&Bs_h[nb][bnb][bk8] = rbh1;
      *(bf16x8*)&Bs_l[nb][bnb][bk8] = rbl1;
    }
    __syncthreads();
    buf ^= 1;
  }

#pragma unroll
  for (int e = 0; e < 4; ++e) {
    const size_t r0 = (size_t)(m0 + mr[e]) * N;
    const size_t r1 = r0 + (size_t)16 * N;
    const int c = n0 + nc[e];
    C[r0 + c +  0] = c00[e];
    C[r0 + c + 16] = c01[e];
    C[r0 + c + 32] = c02[e];
    C[r0 + c + 48] = c03[e];
    C[r1 + c +  0] = c10[e];
    C[r1 + c + 16] = c11[e];
    C[r1 + c + 32] = c12[e];
    C[r1 + c + 48] = c13[e];
  }
}

// ---------------------------------------------------------------------------
// Host launcher. (r14 structure, unchanged.)
// ---------------------------------------------------------------------------
extern "C" void kernel_launch(void* const* d_in, const int* in_sizes, int n_in,
                              void* d_out, int out_size, void* d_ws, size_t ws_size,
                              hipStream_t stream)
{
  (void)in_sizes; (void)n_in; (void)out_size; (void)ws_size;
  const float* x   = (const float*)d_in[0];
  const float* Wi  = (const float*)d_in[1];
  const float* Wp  = (const float*)d_in[2];
  const float* pal = (const float*)d_in[3];
  const float* W1  = (const float*)d_in[4];
  const float* b1  = (const float*)d_in[5];
  const float* W2  = (const float*)d_in[6];
  const float* b2  = (const float*)d_in[7];
  const float* Wc  = (const float*)d_in[8];
  const float* bc  = (const float*)d_in[9];
  const float* Wm  = (const float*)d_in[10];
  const float* bm  = (const float*)d_in[11];
  const float* Wo  = (const float*)d_in[12];
  float* out = (float*)d_out;

  float* w = (float*)d_ws;
  float* palT = w;  w += (size_t)256 * D_DIM;
  float* I    = w;  w += (size_t)BATCH * T_LEN * D_DIM;
  float* P    = w;  w += (size_t)BATCH * T_LEN * D_DIM;
  float* Sb   = w;  w += (size_t)BATCH * T_LEN * T_LEN;
  float* nIb  = w;  w += (size_t)BATCH * T_LEN;
  float* nPb  = w;  w += (size_t)BATCH * T_LEN;
  int*   idx  = (int*)w;  w += (size_t)BATCH * T_LEN * 16;
  int*   cand = (int*)w;

  unsigned short* Xh = (unsigned short*)Sb;
  unsigned short* Xm = Xh + (size_t)4096 * 1024;
  unsigned short* Xl = Xm + (size_t)4096 * 1024;
  unsigned short* WT = (unsigned short*)d_out;

  float2* tab = (float2*)Sb;
  unsigned short* Ssc = (unsigned short*)Sb;
  unsigned short* Ih  = (unsigned short*)(Sb + (size_t)4 * 1024 * 1024);
  unsigned short* Ph  = Ih + (size_t)4 * 1024 * 1024;
  unsigned short* Vh  = (unsigned short*)Sb;
  unsigned short* Vl  = Vh + (size_t)4 * 1024 * 1024;
  unsigned short* WohT = (unsigned short*)P;
  unsigned short* WolT = WohT + (size_t)D_DIM * D_DIM;

  const int MROWS = BATCH * T_LEN;  // 4096

  xsplit3<<<(MROWS * D_DIM) / (256 * 4), 256, 0, stream>>>(x, Xh, Xm, Xl);
  wsplit3T<<<dim3(D_DIM / 64, D_DIM / 64, 2), 256, 0, stream>>>(Wi, Wp, WT);

  gemm3bf<<<dim3(D_DIM / 64, MROWS / 64, 2), 256, 0, stream>>>(
      Xh, Xm, Xl, WT, I);

  prep_kernel<<<T_LEN + 1024, 256, 0, stream>>>(tab, pal, palT);

  rope_norm_kernel<<<MROWS, 256, 0, stream>>>(I, P, tab, nIb, nPb, Ih, Ph);

  screen_bf16<<<dim3(272, 1, 2), 256, 0, stream>>>(Ih, Ph, Ssc);

  topk_screen<<<dim3(T_LEN / 4, BATCH), 256, 0, stream>>>(Ssc, cand);

  rescore_kernel<<<MROWS, 256, 0, stream>>>(I, P, cand, idx);

  woconvT<<<dim3(D_DIM / 64, D_DIM / 64), 256, 0, stream>>>(Wo, WohT, WolT);

  relmlp_kernel<<<MROWS, 256, 0, stream>>>(Ih, Ph, nIb, nPb, idx,
                                           W1, b1, W2, b2, Wc, bc, Wm, bm,
                                           palT, Vh, Vl);

  gemmbf<<<dim3(D_DIM / 128, MROWS / 64), 256, 0, stream>>>(
      Vh, Vl, WohT, WolT, out, D_DIM, D_DIM);
}

// Round 16
// 532.706 us; speedup vs baseline: 1.4552x; 1.0074x over previous
//
#include <hip/hip_runtime.h>
#include <math.h>

// Problem constants (fixed by the reference)
#define BATCH 2
#define T_LEN 2048
#define D_DIM 1024
#define KSEL  15
#define HIDN  64
#define NCAND 20

typedef short  bf16x8 __attribute__((ext_vector_type(8)));
typedef float  f32x4v __attribute__((ext_vector_type(4)));

__device__ __forceinline__ float geluf(float x) {
  return 0.5f * x * (1.0f + erff(x * 0.70710678118654752440f));
}

__device__ __forceinline__ unsigned short f32_to_bf16_rne(float x) {
  unsigned u = __builtin_bit_cast(unsigned, x);
  unsigned lsb = (u >> 16) & 1u;
  u += 0x7fffu + lsb;
  return (unsigned short)(u >> 16);
}
__device__ __forceinline__ float bf16_to_f32(unsigned short h) {
  unsigned u = ((unsigned)h) << 16;
  return __builtin_bit_cast(float, u);
}

// ---------------------------------------------------------------------------
// x -> 3 bf16 planes (h, m, l): x ~= h + m + l to ~2^-27 relative.
// ---------------------------------------------------------------------------
__global__ void __launch_bounds__(256) xsplit3(const float* __restrict__ X,
                                               unsigned short* __restrict__ H,
                                               unsigned short* __restrict__ M,
                                               unsigned short* __restrict__ L)
{
  const size_t i = ((size_t)blockIdx.x * 256 + threadIdx.x) * 4;
  float4 v = *(const float4*)(X + i);
  ushort4 h, m, l;
  float r;
  h.x = f32_to_bf16_rne(v.x); r = v.x - bf16_to_f32(h.x);
  m.x = f32_to_bf16_rne(r);   l.x = f32_to_bf16_rne(r - bf16_to_f32(m.x));
  h.y = f32_to_bf16_rne(v.y); r = v.y - bf16_to_f32(h.y);
  m.y = f32_to_bf16_rne(r);   l.y = f32_to_bf16_rne(r - bf16_to_f32(m.y));
  h.z = f32_to_bf16_rne(v.z); r = v.z - bf16_to_f32(h.z);
  m.z = f32_to_bf16_rne(r);   l.z = f32_to_bf16_rne(r - bf16_to_f32(m.z));
  h.w = f32_to_bf16_rne(v.w); r = v.w - bf16_to_f32(h.w);
  m.w = f32_to_bf16_rne(r);   l.w = f32_to_bf16_rne(r - bf16_to_f32(m.w));
  *(ushort4*)(H + i) = h;
  *(ushort4*)(M + i) = m;
  *(ushort4*)(L + i) = l;
}

// ---------------------------------------------------------------------------
// W (K x N, z picks Wi/Wp) -> transposed (N x K) 3 bf16 planes.
// ---------------------------------------------------------------------------
__global__ void __launch_bounds__(256) wsplit3T(const float* __restrict__ Wi,
                                                const float* __restrict__ Wp,
                                                unsigned short* __restrict__ WT)
{
  __shared__ float tile[64][65];
  const int k0 = blockIdx.y << 6, n0 = blockIdx.x << 6;
  const int z = blockIdx.z;
  const float* W = z ? Wp : Wi;
  unsigned short* H = WT + (size_t)z * 3 * 1024 * 1024;
  unsigned short* M = H + (size_t)1024 * 1024;
  unsigned short* L = M + (size_t)1024 * 1024;
  const int tid = threadIdx.x;
  for (int idx = tid; idx < 4096; idx += 256) {
    int r = idx >> 6, c = idx & 63;
    tile[r][c] = W[(size_t)(k0 + r) * D_DIM + n0 + c];
  }
  __syncthreads();
  for (int idx = tid; idx < 4096; idx += 256) {
    int n = idx >> 6, k = idx & 63;
    float v = tile[k][n];
    unsigned short h = f32_to_bf16_rne(v);
    float r1 = v - bf16_to_f32(h);
    unsigned short m = f32_to_bf16_rne(r1);
    unsigned short l = f32_to_bf16_rne(r1 - bf16_to_f32(m));
    size_t o = (size_t)(n0 + n) * D_DIM + k0 + k;
    H[o] = h; M[o] = m; L[o] = l;
  }
}

// ---------------------------------------------------------------------------
// 3-plane split-bf16 MFMA GEMM for I = x@Wi (z=0), P = x@Wp (z=1).
// (r14/r15, unchanged.)
// ---------------------------------------------------------------------------
__global__ void __launch_bounds__(256) gemm3bf(
    const unsigned short* __restrict__ Xh, const unsigned short* __restrict__ Xm,
    const unsigned short* __restrict__ Xl, const unsigned short* __restrict__ WT,
    float* __restrict__ C)
{
  const int m0 = blockIdx.y << 6, n0 = blockIdx.x << 6;
  const int z = blockIdx.z;
  const unsigned short* BhT = WT + (size_t)z * 3 * 1024 * 1024;
  const unsigned short* BmT = BhT + (size_t)1024 * 1024;
  const unsigned short* BlT = BmT + (size_t)1024 * 1024;
  C += (size_t)z * 4096 * 1024;
  const int N = D_DIM, K = D_DIM;

  const int tid = threadIdx.x;
  const int w = tid >> 6, lane = tid & 63;
  const int kg = lane >> 4, lm = lane & 15;
  const int am0 = (w & 1) << 5;
  const int bn0 = (w >> 1) << 5;

  __shared__ unsigned short Ah[2][64][40], Am[2][64][40], Al[2][64][40];
  __shared__ unsigned short Bh[2][64][40], Bm[2][64][40], Bl[2][64][40];

  bf16x8 ones;
#pragma unroll
  for (int e = 0; e < 8; ++e) ones[e] = (short)0x3F80;

  for (int idx = tid; idx < 2048; idx += 256) {
    Ah[0][idx >> 5][idx & 31] = f32_to_bf16_rne((float)(idx >> 5));
    Bh[0][idx >> 5][idx & 31] = f32_to_bf16_rne((float)(idx >> 5));
  }
  __syncthreads();
  int mr[4], nc[4];
  {
    bf16x8 pa = *(const bf16x8*)&Ah[0][am0 + lm][kg << 3];
    bf16x8 pb = *(const bf16x8*)&Bh[0][bn0 + lm][kg << 3];
    f32x4v d1 = {0.f, 0.f, 0.f, 0.f}, d2 = {0.f, 0.f, 0.f, 0.f};
    d1 = __builtin_amdgcn_mfma_f32_16x16x32_bf16(pa, ones, d1, 0, 0, 0);
    d2 = __builtin_amdgcn_mfma_f32_16x16x32_bf16(ones, pb, d2, 0, 0, 0);
#pragma unroll
    for (int e = 0; e < 4; ++e) {
      mr[e] = ((int)d1[e]) >> 5;
      nc[e] = ((int)d2[e]) >> 5;
    }
  }
  __syncthreads();

  f32x4v ch[2][2], cm[2][2], cl[2][2];
#pragma unroll
  for (int i = 0; i < 2; ++i)
#pragma unroll
    for (int j = 0; j < 2; ++j) {
      ch[i][j] = (f32x4v){0.f, 0.f, 0.f, 0.f};
      cm[i][j] = (f32x4v){0.f, 0.f, 0.f, 0.f};
      cl[i][j] = (f32x4v){0.f, 0.f, 0.f, 0.f};
    }

  const int ar = tid >> 2, ak8 = (tid & 3) << 3;

  bf16x8 rah, ram, ral, rbh, rbm, rbl;

  {
    size_t ao = (size_t)(m0 + ar) * K + ak8;
    size_t bo = (size_t)(n0 + ar) * K + ak8;
    rah = *(const bf16x8*)(Xh + ao); ram = *(const bf16x8*)(Xm + ao);
    ral = *(const bf16x8*)(Xl + ao);
    rbh = *(const bf16x8*)(BhT + bo); rbm = *(const bf16x8*)(BmT + bo);
    rbl = *(const bf16x8*)(BlT + bo);
  }
  *(bf16x8*)&Ah[0][ar][ak8] = rah;
  *(bf16x8*)&Am[0][ar][ak8] = ram;
  *(bf16x8*)&Al[0][ar][ak8] = ral;
  *(bf16x8*)&Bh[0][ar][ak8] = rbh;
  *(bf16x8*)&Bm[0][ar][ak8] = rbm;
  *(bf16x8*)&Bl[0][ar][ak8] = rbl;
  __syncthreads();

  int buf = 0;
  for (int k0 = 0; k0 < K; k0 += 32) {
    const bool more = (k0 + 32) < K;
    if (more) {
      const int kn = k0 + 32;
      size_t ao = (size_t)(m0 + ar) * K + kn + ak8;
      size_t bo = (size_t)(n0 + ar) * K + kn + ak8;
      rah = *(const bf16x8*)(Xh + ao); ram = *(const bf16x8*)(Xm + ao);
      ral = *(const bf16x8*)(Xl + ao);
      rbh = *(const bf16x8*)(BhT + bo); rbm = *(const bf16x8*)(BmT + bo);
      rbl = *(const bf16x8*)(BlT + bo);
    }
    {
      bf16x8 a_h[2], a_m[2], a_l[2], b_h[2], b_m[2], b_l[2];
#pragma unroll
      for (int i = 0; i < 2; ++i) {
        const int rrow = am0 + (i << 4) + lm;
        a_h[i] = *(const bf16x8*)&Ah[buf][rrow][kg << 3];
        a_m[i] = *(const bf16x8*)&Am[buf][rrow][kg << 3];
        a_l[i] = *(const bf16x8*)&Al[buf][rrow][kg << 3];
        const int nrow = bn0 + (i << 4) + lm;
        b_h[i] = *(const bf16x8*)&Bh[buf][nrow][kg << 3];
        b_m[i] = *(const bf16x8*)&Bm[buf][nrow][kg << 3];
        b_l[i] = *(const bf16x8*)&Bl[buf][nrow][kg << 3];
      }
#pragma unroll
      for (int i = 0; i < 2; ++i)
#pragma unroll
        for (int j = 0; j < 2; ++j) {
          ch[i][j] = __builtin_amdgcn_mfma_f32_16x16x32_bf16(a_h[i], b_h[j], ch[i][j], 0, 0, 0);
          cm[i][j] = __builtin_amdgcn_mfma_f32_16x16x32_bf16(a_h[i], b_m[j], cm[i][j], 0, 0, 0);
          cm[i][j] = __builtin_amdgcn_mfma_f32_16x16x32_bf16(a_m[i], b_h[j], cm[i][j], 0, 0, 0);
          cl[i][j] = __builtin_amdgcn_mfma_f32_16x16x32_bf16(a_h[i], b_l[j], cl[i][j], 0, 0, 0);
          cl[i][j] = __builtin_amdgcn_mfma_f32_16x16x32_bf16(a_m[i], b_m[j], cl[i][j], 0, 0, 0);
          cl[i][j] = __builtin_amdgcn_mfma_f32_16x16x32_bf16(a_l[i], b_h[j], cl[i][j], 0, 0, 0);
        }
    }
    if (more) {
      const int nb = buf ^ 1;
      *(bf16x8*)&Ah[nb][ar][ak8] = rah;
      *(bf16x8*)&Am[nb][ar][ak8] = ram;
      *(bf16x8*)&Al[nb][ar][ak8] = ral;
      *(bf16x8*)&Bh[nb][ar][ak8] = rbh;
      *(bf16x8*)&Bm[nb][ar][ak8] = rbm;
      *(bf16x8*)&Bl[nb][ar][ak8] = rbl;
    }
    __syncthreads();
    buf ^= 1;
  }

#pragma unroll
  for (int i = 0; i < 2; ++i)
#pragma unroll
    for (int j = 0; j < 2; ++j)
#pragma unroll
      for (int e = 0; e < 4; ++e) {
        const int rrow = m0 + mr[e] + (i << 4);
        const int ccol = n0 + nc[e] + (j << 4);
        float v = (ch[i][j][e] + cm[i][j][e]) + cl[i][j][e];
        C[(size_t)rrow * N + ccol] = v;
      }
}

// ---------------------------------------------------------------------------
// PREP (fused): trig table (EXACT reference f32 bits — selection-critical)
// + palette transpose.
// ---------------------------------------------------------------------------
__global__ void __launch_bounds__(256) prep_kernel(float2* __restrict__ tab,
                                                   const float* __restrict__ pal,
                                                   float* __restrict__ palT)
{
  const int b = blockIdx.x;
  if (b < T_LEN) {
    const int t = b;
    for (int j = threadIdx.x; j < 512; j += 256) {
      double e = (double)j * (1.0 / 512.0);
      float pf = (float)pow(10000.0, e);
      float invf = 1.0f / pf;
      float angf = (float)t * invf;
      double s64, c64;
      sincos((double)angf, &s64, &c64);
      tab[(size_t)t * 512 + j] = make_float2((float)c64, (float)s64);
    }
  } else {
    const int bb = b - T_LEN;
    const int c = bb & 255, dg = bb >> 8;
    const int d = dg * 256 + threadIdx.x;
    palT[(size_t)c * D_DIM + d] = pal[(size_t)d * 256 + c];
  }
}

// ---------------------------------------------------------------------------
// RoPE in place + row L2 norms + bf16 hi planes Ih/Ph (fused emit).
// f32 rotation math unchanged — selection-critical.
// ---------------------------------------------------------------------------
__global__ void __launch_bounds__(256) rope_norm_kernel(
    float* __restrict__ bI, float* __restrict__ bP,
    const float2* __restrict__ tab,
    float* __restrict__ nI, float* __restrict__ nP,
    unsigned short* __restrict__ Ih, unsigned short* __restrict__ Ph)
{
  const int row = blockIdx.x;
  const int t = row & (T_LEN - 1);
  const int tid = threadIdx.x;
  __shared__ double redI[4], redP[4];
  double ssI = 0.0, ssP = 0.0;
  const size_t off = (size_t)row * D_DIM;
  for (int j = tid; j < 512; j += 256) {
    float2 cs = tab[(size_t)t * 512 + j];
    float c = cs.x, s = cs.y;

    float a1 = bI[off + j], a2 = bI[off + 512 + j];
    float o1 = __fsub_rn(__fmul_rn(a1, c), __fmul_rn(a2, s));
    float o2 = __fadd_rn(__fmul_rn(a1, s), __fmul_rn(a2, c));
    bI[off + j] = o1; bI[off + 512 + j] = o2;
    Ih[off + j] = f32_to_bf16_rne(o1); Ih[off + 512 + j] = f32_to_bf16_rne(o2);
    ssI += (double)o1 * o1 + (double)o2 * o2;

    float p1 = bP[off + j], p2 = bP[off + 512 + j];
    float q1 = __fsub_rn(__fmul_rn(p1, c), __fmul_rn(p2, s));
    float q2 = __fadd_rn(__fmul_rn(p1, s), __fmul_rn(p2, c));
    bP[off + j] = q1; bP[off + 512 + j] = q2;
    Ph[off + j] = f32_to_bf16_rne(q1); Ph[off + 512 + j] = f32_to_bf16_rne(q2);
    ssP += (double)q1 * q1 + (double)q2 * q2;
  }
#pragma unroll
  for (int o = 32; o >= 1; o >>= 1) { ssI += __shfl_xor(ssI, o); ssP += __shfl_xor(ssP, o); }
  if ((tid & 63) == 0) { redI[tid >> 6] = ssI; redP[tid >> 6] = ssP; }
  __syncthreads();
  if (tid == 0) {
    nI[row] = fmaxf((float)sqrt(redI[0] + redI[1] + redI[2] + redI[3]), 1e-12f);
    nP[row] = fmaxf((float)sqrt(redP[0] + redP[1] + redP[2] + redP[3]), 1e-12f);
  }
}

// ---------------------------------------------------------------------------
// bf16 SCREEN for S (candidates only; exact rescore follows). (unchanged.)
// ---------------------------------------------------------------------------
__global__ void __launch_bounds__(256) screen_bf16(
    const unsigned short* __restrict__ Ih, const unsigned short* __restrict__ Ph,
    unsigned short* __restrict__ Ssc)
{
  int rem = blockIdx.x, bi = 0;
  while (rem >= (bi >> 1) + 1) { rem -= (bi >> 1) + 1; ++bi; }
  const int m0 = bi << 6, n0 = rem << 7;
  const int z = blockIdx.z;
  const unsigned short* A = Ih + (size_t)z * T_LEN * D_DIM;
  const unsigned short* B = Ph + (size_t)z * T_LEN * D_DIM;
  unsigned short* C = Ssc + (size_t)z * T_LEN * T_LEN;
  const int N = T_LEN, K = D_DIM;

  const int tid = threadIdx.x;
  const int w = tid >> 6, lane = tid & 63;
  const int kg = lane >> 4, lm = lane & 15;
  const int am0 = (w & 1) << 5;
  const int bn0 = (w >> 1) << 6;

  __shared__ unsigned short As_h[2][64][40];
  __shared__ unsigned short Bs_h[2][128][40];

  bf16x8 ones;
#pragma unroll
  for (int e = 0; e < 8; ++e) ones[e] = (short)0x3F80;

  for (int idx = tid; idx < 2048; idx += 256)
    As_h[0][idx >> 5][idx & 31] = f32_to_bf16_rne((float)(idx >> 5));
  for (int idx = tid; idx < 4096; idx += 256)
    Bs_h[0][idx >> 5][idx & 31] = f32_to_bf16_rne((float)(idx >> 5));
  __syncthreads();
  int mr[4], nc[4];
  {
    bf16x8 pa = *(const bf16x8*)&As_h[0][am0 + lm][kg << 3];
    bf16x8 pb = *(const bf16x8*)&Bs_h[0][bn0 + lm][kg << 3];
    f32x4v d1 = {0.f, 0.f, 0.f, 0.f}, d2 = {0.f, 0.f, 0.f, 0.f};
    d1 = __builtin_amdgcn_mfma_f32_16x16x32_bf16(pa, ones, d1, 0, 0, 0);
    d2 = __builtin_amdgcn_mfma_f32_16x16x32_bf16(ones, pb, d2, 0, 0, 0);
#pragma unroll
    for (int e = 0; e < 4; ++e) {
      mr[e] = ((int)d1[e]) >> 5;
      nc[e] = ((int)d2[e]) >> 5;
    }
  }
  __syncthreads();

  f32x4v c00 = {0,0,0,0}, c01 = {0,0,0,0}, c02 = {0,0,0,0}, c03 = {0,0,0,0};
  f32x4v c10 = {0,0,0,0}, c11 = {0,0,0,0}, c12 = {0,0,0,0}, c13 = {0,0,0,0};

  const int ar  = tid >> 2, ak8 = (tid & 3) << 3;
  const int bna = tid >> 2, bnb = 64 + (tid >> 2), bk8 = (tid & 3) << 3;

  bf16x8 ra, rb0, rb1;

  ra  = *(const bf16x8*)(A + (size_t)(m0 + ar) * K + ak8);
  rb0 = *(const bf16x8*)(B + (size_t)(n0 + bna) * K + bk8);
  rb1 = *(const bf16x8*)(B + (size_t)(n0 + bnb) * K + bk8);
  *(bf16x8*)&As_h[0][ar][ak8]  = ra;
  *(bf16x8*)&Bs_h[0][bna][bk8] = rb0;
  *(bf16x8*)&Bs_h[0][bnb][bk8] = rb1;
  __syncthreads();

  int buf = 0;
  for (int k0 = 0; k0 < K; k0 += 32) {
    const bool more = (k0 + 32) < K;
    if (more) {
      const int kn = k0 + 32;
      ra  = *(const bf16x8*)(A + (size_t)(m0 + ar) * K + kn + ak8);
      rb0 = *(const bf16x8*)(B + (size_t)(n0 + bna) * K + kn + bk8);
      rb1 = *(const bf16x8*)(B + (size_t)(n0 + bnb) * K + kn + bk8);
    }
    {
      bf16x8 a0 = *(const bf16x8*)&As_h[buf][am0 + lm][kg << 3];
      bf16x8 a1 = *(const bf16x8*)&As_h[buf][am0 + 16 + lm][kg << 3];
      bf16x8 b0 = *(const bf16x8*)&Bs_h[buf][bn0 + lm][kg << 3];
      bf16x8 b1 = *(const bf16x8*)&Bs_h[buf][bn0 + 16 + lm][kg << 3];
      bf16x8 b2 = *(const bf16x8*)&Bs_h[buf][bn0 + 32 + lm][kg << 3];
      bf16x8 b3 = *(const bf16x8*)&Bs_h[buf][bn0 + 48 + lm][kg << 3];
      c00 = __builtin_amdgcn_mfma_f32_16x16x32_bf16(a0, b0, c00, 0, 0, 0);
      c01 = __builtin_amdgcn_mfma_f32_16x16x32_bf16(a0, b1, c01, 0, 0, 0);
      c02 = __builtin_amdgcn_mfma_f32_16x16x32_bf16(a0, b2, c02, 0, 0, 0);
      c03 = __builtin_amdgcn_mfma_f32_16x16x32_bf16(a0, b3, c03, 0, 0, 0);
      c10 = __builtin_amdgcn_mfma_f32_16x16x32_bf16(a1, b0, c10, 0, 0, 0);
      c11 = __builtin_amdgcn_mfma_f32_16x16x32_bf16(a1, b1, c11, 0, 0, 0);
      c12 = __builtin_amdgcn_mfma_f32_16x16x32_bf16(a1, b2, c12, 0, 0, 0);
      c13 = __builtin_amdgcn_mfma_f32_16x16x32_bf16(a1, b3, c13, 0, 0, 0);
    }
    if (more) {
      const int nb = buf ^ 1;
      *(bf16x8*)&As_h[nb][ar][ak8]  = ra;
      *(bf16x8*)&Bs_h[nb][bna][bk8] = rb0;
      *(bf16x8*)&Bs_h[nb][bnb][bk8] = rb1;
    }
    __syncthreads();
    buf ^= 1;
  }

#pragma unroll
  for (int e = 0; e < 4; ++e) {
    const size_t r0 = (size_t)(m0 + mr[e]) * N;
    const size_t r1 = r0 + (size_t)16 * N;
    const int c = n0 + nc[e];
    C[r0 + c +  0] = f32_to_bf16_rne(c00[e]);
    C[r0 + c + 16] = f32_to_bf16_rne(c01[e]);
    C[r0 + c + 32] = f32_to_bf16_rne(c02[e]);
    C[r0 + c + 48] = f32_to_bf16_rne(c03[e]);
    C[r1 + c +  0] = f32_to_bf16_rne(c10[e]);
    C[r1 + c + 16] = f32_to_bf16_rne(c11[e]);
    C[r1 + c + 32] = f32_to_bf16_rne(c12[e]);
    C[r1 + c + 48] = f32_to_bf16_rne(c13[e]);
  }
}

// ---------------------------------------------------------------------------
// Top-NCAND screen candidates per causal row (bf16 S). -1 = invalid.
// ---------------------------------------------------------------------------
__global__ void __launch_bounds__(256) topk_screen(const unsigned short* __restrict__ Ssc,
                                                   int* __restrict__ cand)
{
  const int b = blockIdx.y;
  const unsigned short* S = Ssc + (size_t)b * T_LEN * T_LEN;
  const int wave = threadIdx.x >> 6, lane = threadIdx.x & 63;
  const int t = blockIdx.x * 4 + wave;
  const unsigned short* rowp = S + (size_t)t * T_LEN;
  float v[32];
#pragma unroll
  for (int i = 0; i < 32; ++i) {
    int s = lane + (i << 6);
    v[i] = (s <= t) ? bf16_to_f32(rowp[s]) : -INFINITY;
  }
  float pv = INFINITY; int pidx = -1;
  int* outp = cand + ((size_t)b * T_LEN + t) * NCAND;
  for (int k = 0; k < NCAND; ++k) {
    float bv = -INFINITY; int bi = 0x7fffffff;
#pragma unroll
    for (int i = 0; i < 32; ++i) {
      int s = lane + (i << 6);
      float vv = v[i];
      bool elig = (vv < pv) || (vv == pv && s > pidx);
      if (elig && vv > bv) { bv = vv; bi = s; }
    }
#pragma unroll
    for (int o = 32; o >= 1; o >>= 1) {
      float ov = __shfl_xor(bv, o);
      int oi = __shfl_xor(bi, o);
      if (ov > bv || (ov == bv && oi < bi)) { bv = ov; bi = oi; }
    }
    pv = bv; pidx = bi;
    if (lane == 0) outp[k] = (bi == 0x7fffffff || bv == -INFINITY) ? -1 : bi;
  }
}

// ---------------------------------------------------------------------------
// Exact rescore: f64 dot of I_t with each candidate P row (f32 arrays),
// rounded to f32 after the 2^-5 scale, tie -> lower index, top-15 -> idx.
// ---------------------------------------------------------------------------
__global__ void __launch_bounds__(256) rescore_kernel(
    const float* __restrict__ I, const float* __restrict__ P,
    const int* __restrict__ cand, int* __restrict__ idx)
{
  const int row = blockIdx.x;
  const int base = row & ~(T_LEN - 1);
  const int tid = threadIdx.x;
  const int w = tid >> 6, lane = tid & 63;

  __shared__ float valS[NCAND];
  __shared__ int   sidxS[NCAND];
  __shared__ int   candS[NCAND];

  if (tid < NCAND) candS[tid] = cand[(size_t)row * NCAND + tid];
  __syncthreads();

  double iv[16];
  const float* irow = I + (size_t)row * D_DIM;
#pragma unroll
  for (int j = 0; j < 16; ++j) iv[j] = (double)irow[lane + (j << 6)];

  for (int c = w; c < NCAND; c += 4) {
    int s = candS[c];
    double acc = 0.0;
    if (s >= 0) {
      const float* prow = P + ((size_t)base + s) * D_DIM;
#pragma unroll
      for (int j = 0; j < 16; ++j)
        acc = fma(iv[j], (double)prow[lane + (j << 6)], acc);
    }
#pragma unroll
    for (int o = 32; o >= 1; o >>= 1) acc += __shfl_xor(acc, o);
    if (lane == 0) {
      valS[c] = (s >= 0) ? (float)(acc * 0.03125) : -INFINITY;
      sidxS[c] = s;
    }
  }
  __syncthreads();
  if (tid == 0) {
    bool taken[NCAND];
#pragma unroll
    for (int c = 0; c < NCAND; ++c) taken[c] = false;
    int* outp = idx + (size_t)row * 16;
    for (int k = 0; k < KSEL; ++k) {
      float best = -INFINITY; int bidx = 0x7fffffff; int bc = -1;
      for (int c = 0; c < NCAND; ++c) {
        if (taken[c] || sidxS[c] < 0) continue;
        float v = valS[c];
        if (v > best || (v == best && sidxS[c] < bidx)) { best = v; bidx = sidxS[c]; bc = c; }
      }
      if (bc >= 0) { taken[bc] = true; outp[k] = bidx; }
      else outp[k] = 0;
    }
  }
}

// ---------------------------------------------------------------------------
// Wo (K x N) -> transposed bf16 hi/lo planes (N x K). After rescore (P dead).
// ---------------------------------------------------------------------------
__global__ void __launch_bounds__(256) woconvT(const float* __restrict__ Wo,
                                               unsigned short* __restrict__ HT,
                                               unsigned short* __restrict__ LT)
{
  __shared__ float tile[64][65];
  const int k0 = blockIdx.y << 6, n0 = blockIdx.x << 6;
  const int tid = threadIdx.x;
  for (int idx = tid; idx < 4096; idx += 256) {
    int r = idx >> 6, c = idx & 63;
    tile[r][c] = Wo[(size_t)(k0 + r) * D_DIM + n0 + c];
  }
  __syncthreads();
  for (int idx = tid; idx < 4096; idx += 256) {
    int n = idx >> 6, k = idx & 63;
    float v = tile[k][n];
    unsigned short h = f32_to_bf16_rne(v);
    HT[(size_t)(n0 + n) * D_DIM + k0 + k] = h;
    LT[(size_t)(n0 + n) * D_DIM + k0 + k] = f32_to_bf16_rne(v - bf16_to_f32(h));
  }
}

// ---------------------------------------------------------------------------
// Per-(b,t), WAVE-PER-ROW (4 rows per block): gather fragments DIRECT from
// global (no vecU LDS staging), MFMA gram on every wave, rel features +
// MLP + heads + softmax + bilinear palette blend -> V bf16 hi/lo planes.
// Arithmetic order identical to r15 (same MFMA sequence, same loop orders)
// -> bit-identical results; only the thread mapping changed.
// Probe trick: with fragment convention "lane (kg,lm) slot j = row lm,
// k = ks*32+kg*8+j", the probe A/B fragment is the CONSTANT bf16(lm).
// ---------------------------------------------------------------------------
__global__ void __launch_bounds__(256) relmlp_kernel(
    const unsigned short* __restrict__ Ih, const unsigned short* __restrict__ Ph,
    const float* __restrict__ nI, const float* __restrict__ nP,
    const int* __restrict__ topk,
    const float* __restrict__ W1, const float* __restrict__ b1,
    const float* __restrict__ W2, const float* __restrict__ b2,
    const float* __restrict__ Wc, const float* __restrict__ bc,
    const float* __restrict__ Wm, const float* __restrict__ bm,
    const float* __restrict__ palT,
    unsigned short* __restrict__ Vh, unsigned short* __restrict__ Vl)
{
  const int wv   = threadIdx.x >> 6;          // wave id: row owner
  const int lane = threadIdx.x & 63;
  const int row  = (blockIdx.x << 2) + wv;
  const int t    = row & (T_LEN - 1);
  const int base = row & ~(T_LEN - 1);
  const int nk   = (t + 1 < KSEL) ? (t + 1) : KSEL;

  __shared__ int   sidxS[4][16];
  __shared__ float nrmS[4][16];
  __shared__ float gS[4][16][16];
  __shared__ float relS[4][KSEL][18];
  __shared__ float h1S[4][KSEL][HIDN];
  __shared__ float h2S[4][KSEL][HIDN];
  __shared__ float mixS[4][KSEL], wSS[4][KSEL], zxS[4][KSEL], zyS[4][KSEL];
  __shared__ float coefS[4][4 * KSEL];
  __shared__ int   cellS[4][4 * KSEL];

  if (lane < 16) {
    int s = t;
    if (lane >= 1) s = (lane <= nk) ? topk[(size_t)row * 16 + (lane - 1)] : 0;
    sidxS[wv][lane] = s;
    nrmS[wv][lane] = (lane == 0) ? nI[row] : nP[base + s];
  }
  __syncthreads();

  // ---- gram: direct-global MFMA fragments, all 4 waves ----
  const int lm = lane & 15, kg = lane >> 4;
  {
    const unsigned short* src = (lm == 0)
        ? (Ih + (size_t)row * D_DIM)
        : (Ph + ((size_t)base + sidxS[wv][lm]) * D_DIM);
    f32x4v acc = {0.f, 0.f, 0.f, 0.f};
#pragma unroll
    for (int ks = 0; ks < 32; ++ks) {
      bf16x8 a;
      if (lm <= nk) a = *(const bf16x8*)(src + (ks << 5) + (kg << 3));
      else {
        bf16x8 zz = {0, 0, 0, 0, 0, 0, 0, 0};
        a = zz;
      }
      acc = __builtin_amdgcn_mfma_f32_16x16x32_bf16(a, a, acc, 0, 0, 0);
    }
    bf16x8 pa, ones;
    unsigned short lmb = f32_to_bf16_rne((float)lm);
#pragma unroll
    for (int e = 0; e < 8; ++e) { pa[e] = (short)lmb; ones[e] = (short)0x3F80; }
    f32x4v d1 = {0.f, 0.f, 0.f, 0.f}, d2 = {0.f, 0.f, 0.f, 0.f};
    d1 = __builtin_amdgcn_mfma_f32_16x16x32_bf16(pa, ones, d1, 0, 0, 0);
    d2 = __builtin_amdgcn_mfma_f32_16x16x32_bf16(ones, pa, d2, 0, 0, 0);
#pragma unroll
    for (int e = 0; e < 4; ++e) {
      int pi2 = ((int)d1[e]) >> 5;
      int pj2 = ((int)d2[e]) >> 5;
      float g = 0.f;
      if (pi2 <= nk && pj2 <= nk) {
        g = acc[e] / (nrmS[wv][pi2] * nrmS[wv][pj2]);
        g = fminf(fmaxf(g, -1.f), 1.f);
      }
      gS[wv][pi2][pj2] = g;
    }
  }
  __syncthreads();

  // ---- rel features ----
  for (int o = lane; o < KSEL * 17; o += 64) {
    int k = o / 17, f = o % 17;
    float v = 0.f;
    if (k < nk) {
      if (f < KSEL)        v = (f < nk) ? gS[wv][k + 1][f + 1] : 0.f;
      else if (f == KSEL)  v = gS[wv][0][k + 1];
      else                 v = (float)(t - sidxS[wv][k + 1]) * (1.0f / (float)T_LEN);
    }
    relS[wv][k][f] = v;
  }
  __syncthreads();

  // ---- MLP1: lane = output channel m ----
#pragma unroll
  for (int k = 0; k < KSEL; ++k) {
    float a = b1[lane];
#pragma unroll
    for (int f = 0; f < 17; ++f) a = fmaf(relS[wv][k][f], W1[f * HIDN + lane], a);
    h1S[wv][k][lane] = geluf(a);
  }
  __syncthreads();

  // ---- MLP2 ----
#pragma unroll
  for (int k = 0; k < KSEL; ++k) {
    float a = b2[lane];
#pragma unroll 8
    for (int n = 0; n < HIDN; ++n) a = fmaf(h1S[wv][k][n], W2[n * HIDN + lane], a);
    h2S[wv][k][lane] = geluf(a);
  }
  __syncthreads();

  // ---- heads ----
  if (lane < KSEL) {
    float a0 = 0.f, a1 = 0.f, am = 0.f;
#pragma unroll 8
    for (int n = 0; n < HIDN; ++n) {
      float h = h2S[wv][lane][n];
      a0 = fmaf(h, Wc[n * 2 + 0], a0);
      a1 = fmaf(h, Wc[n * 2 + 1], a1);
      am = fmaf(h, Wm[n], am);
    }
    zxS[wv][lane] = tanhf(a0 + bc[0]);
    zyS[wv][lane] = tanhf(a1 + bc[1]);
    mixS[wv][lane] = am + bm[0];
  }
  __syncthreads();

  // ---- softmax (lane 0 of each wave) ----
  if (lane == 0) {
    float mx = -INFINITY;
    for (int k = 0; k < nk; ++k) mx = fmaxf(mx, mixS[wv][k]);
    float ssum = 0.f;
    for (int k = 0; k < nk; ++k) { float e = expf(mixS[wv][k] - mx); wSS[wv][k] = e; ssum += e; }
    float inv = 1.f / ssum;
    for (int k = 0; k < nk; ++k) wSS[wv][k] *= inv;
  }
  __syncthreads();

  // ---- bilinear coefficients ----
  if (lane < KSEL) {
    int k = lane;
    if (k < nk) {
      float w = wSS[wv][k];
      float fx = fminf(fmaxf((zxS[wv][k] + 1.f) * 0.5f * 15.f, 0.f), 15.f);
      float fy = fminf(fmaxf((zyS[wv][k] + 1.f) * 0.5f * 15.f, 0.f), 15.f);
      int x0 = (int)floorf(fx); int x1i = (x0 + 1 < 15) ? x0 + 1 : 15;
      int y0 = (int)floorf(fy); int y1i = (y0 + 1 < 15) ? y0 + 1 : 15;
      float wx = fx - (float)x0, wy = fy - (float)y0;
      cellS[wv][k * 4 + 0] = y0 * 16 + x0;   coefS[wv][k * 4 + 0] = w * (1.f - wy) * (1.f - wx);
      cellS[wv][k * 4 + 1] = y0 * 16 + x1i;  coefS[wv][k * 4 + 1] = w * (1.f - wy) * wx;
      cellS[wv][k * 4 + 2] = y1i * 16 + x0;  coefS[wv][k * 4 + 2] = w * wy * (1.f - wx);
      cellS[wv][k * 4 + 3] = y1i * 16 + x1i; coefS[wv][k * 4 + 3] = w * wy * wx;
    } else {
      cellS[wv][k * 4 + 0] = cellS[wv][k * 4 + 1] = cellS[wv][k * 4 + 2] = cellS[wv][k * 4 + 3] = 0;
      coefS[wv][k * 4 + 0] = coefS[wv][k * 4 + 1] = coefS[wv][k * 4 + 2] = coefS[wv][k * 4 + 3] = 0.f;
    }
  }
  __syncthreads();

  // ---- palette blend -> V bf16 planes ----
  const int nj = 4 * nk;
  for (int d = lane; d < D_DIM; d += 64) {
    float a = 0.f;
    for (int j = 0; j < nj; ++j)
      a = fmaf(coefS[wv][j], palT[(size_t)cellS[wv][j] * D_DIM + d], a);
    unsigned short h = f32_to_bf16_rne(a);
    Vh[(size_t)row * D_DIM + d] = h;
    Vl[(size_t)row * D_DIM + d] = f32_to_bf16_rne(a - bf16_to_f32(h));
  }
}

// ---------------------------------------------------------------------------
// Split-bf16 MFMA GEMM for out = V @ Wo. (r10, unchanged.)
// ---------------------------------------------------------------------------
__global__ void __launch_bounds__(256) gemmbf(
    const unsigned short* __restrict__ Ah, const unsigned short* __restrict__ Al,
    const unsigned short* __restrict__ BhT, const unsigned short* __restrict__ BlT,
    float* __restrict__ C, int N, int K)
{
  const int m0 = blockIdx.y << 6, n0 = blockIdx.x << 7;
  const int tid = threadIdx.x;
  const int w = tid >> 6, lane = tid & 63;
  const int kg = lane >> 4, lm = lane & 15;
  const int am0 = (w & 1) << 5;
  const int bn0 = (w >> 1) << 6;

  __shared__ unsigned short As_h[2][64][40],  As_l[2][64][40];
  __shared__ unsigned short Bs_h[2][128][40], Bs_l[2][128][40];

  bf16x8 ones;
#pragma unroll
  for (int e = 0; e < 8; ++e) ones[e] = (short)0x3F80;

  for (int idx = tid; idx < 2048; idx += 256)
    As_h[0][idx >> 5][idx & 31] = f32_to_bf16_rne((float)(idx >> 5));
  for (int idx = tid; idx < 4096; idx += 256)
    Bs_h[0][idx >> 5][idx & 31] = f32_to_bf16_rne((float)(idx >> 5));
  __syncthreads();
  int mr[4], nc[4];
  {
    bf16x8 pa = *(const bf16x8*)&As_h[0][am0 + lm][kg << 3];
    bf16x8 pb = *(const bf16x8*)&Bs_h[0][bn0 + lm][kg << 3];
    f32x4v d1 = {0.f, 0.f, 0.f, 0.f}, d2 = {0.f, 0.f, 0.f, 0.f};
    d1 = __builtin_amdgcn_mfma_f32_16x16x32_bf16(pa, ones, d1, 0, 0, 0);
    d2 = __builtin_amdgcn_mfma_f32_16x16x32_bf16(ones, pb, d2, 0, 0, 0);
#pragma unroll
    for (int e = 0; e < 4; ++e) {
      mr[e] = ((int)d1[e]) >> 5;
      nc[e] = ((int)d2[e]) >> 5;
    }
  }
  __syncthreads();

  f32x4v c00 = {0,0,0,0}, c01 = {0,0,0,0}, c02 = {0,0,0,0}, c03 = {0,0,0,0};
  f32x4v c10 = {0,0,0,0}, c11 = {0,0,0,0}, c12 = {0,0,0,0}, c13 = {0,0,0,0};

  const int ar  = tid >> 2, ak8 = (tid & 3) << 3;
  const int bna = tid >> 2, bnb = 64 + (tid >> 2), bk8 = (tid & 3) << 3;

  bf16x8 rah, ral, rbh0, rbl0, rbh1, rbl1;

  rah  = *(const bf16x8*)(Ah  + (size_t)(m0 + ar) * K + ak8);
  ral  = *(const bf16x8*)(Al  + (size_t)(m0 + ar) * K + ak8);
  rbh0 = *(const bf16x8*)(BhT + (size_t)(n0 + bna) * K + bk8);
  rbl0 = *(const bf16x8*)(BlT + (size_t)(n0 + bna) * K + bk8);
  rbh1 = *(const bf16x8*)(BhT + (size_t)(n0 + bnb) * K + bk8);
  rbl1 = *(const bf16x8*)(BlT + (size_t)(n0 + bnb) * K + bk8);
  *(bf16x8*)&As_h[0][ar][ak8]  = rah;
  *(bf16x8*)&As_l[0][ar][ak8]  = ral;
  *(bf16x8*)&Bs_h[0][bna][bk8] = rbh0;
  *(bf16x8*)&Bs_l[0][bna][bk8] = rbl0;
  *(bf16x8*)&Bs_h[0][bnb][bk8] = rbh1;
  *(bf16x8*)&Bs_l[0][bnb][bk8] = rbl1;
  __syncthreads();

  int buf = 0;
  for (int k0 = 0; k0 < K; k0 += 32) {
    const bool more = (k0 + 32) < K;
    if (more) {
      const int kn = k0 + 32;
      rah  = *(const bf16x8*)(Ah  + (size_t)(m0 + ar) * K + kn + ak8);
      ral  = *(const bf16x8*)(Al  + (size_t)(m0 + ar) * K + kn + ak8);
      rbh0 = *(const bf16x8*)(BhT + (size_t)(n0 + bna) * K + kn + bk8);
      rbl0 = *(const bf16x8*)(BlT + (size_t)(n0 + bna) * K + kn + bk8);
      rbh1 = *(const bf16x8*)(BhT + (size_t)(n0 + bnb) * K + kn + bk8);
      rbl1 = *(const bf16x8*)(BlT + (size_t)(n0 + bnb) * K + kn + bk8);
    }
    {
      bf16x8 ah0 = *(const bf16x8*)&As_h[buf][am0 + lm][kg << 3];
      bf16x8 ah1 = *(const bf16x8*)&As_h[buf][am0 + 16 + lm][kg << 3];
      bf16x8 al0 = *(const bf16x8*)&As_l[buf][am0 + lm][kg << 3];
      bf16x8 al1 = *(const bf16x8*)&As_l[buf][am0 + 16 + lm][kg << 3];
      bf16x8 bh0 = *(const bf16x8*)&Bs_h[buf][bn0 + lm][kg << 3];
      bf16x8 bh1 = *(const bf16x8*)&Bs_h[buf][bn0 + 16 + lm][kg << 3];
      bf16x8 bh2 = *(const bf16x8*)&Bs_h[buf][bn0 + 32 + lm][kg << 3];
      bf16x8 bh3 = *(const bf16x8*)&Bs_h[buf][bn0 + 48 + lm][kg << 3];
      bf16x8 bl0 = *(const bf16x8*)&Bs_l[buf][bn0 + lm][kg << 3];
      bf16x8 bl1 = *(const bf16x8*)&Bs_l[buf][bn0 + 16 + lm][kg << 3];
      bf16x8 bl2 = *(const bf16x8*)&Bs_l[buf][bn0 + 32 + lm][kg << 3];
      bf16x8 bl3 = *(const bf16x8*)&Bs_l[buf][bn0 + 48 + lm][kg << 3];

      c00 = __builtin_amdgcn_mfma_f32_16x16x32_bf16(ah0, bh0, c00, 0, 0, 0);
      c01 = __builtin_amdgcn_mfma_f32_16x16x32_bf16(ah0, bh1, c01, 0, 0, 0);
      c02 = __builtin_amdgcn_mfma_f32_16x16x32_bf16(ah0, bh2, c02, 0, 0, 0);
      c03 = __builtin_amdgcn_mfma_f32_16x16x32_bf16(ah0, bh3, c03, 0, 0, 0);
      c10 = __builtin_amdgcn_mfma_f32_16x16x32_bf16(ah1, bh0, c10, 0, 0, 0);
      c11 = __builtin_amdgcn_mfma_f32_16x16x32_bf16(ah1, bh1, c11, 0, 0, 0);
      c12 = __builtin_amdgcn_mfma_f32_16x16x32_bf16(ah1, bh2, c12, 0, 0, 0);
      c13 = __builtin_amdgcn_mfma_f32_16x16x32_bf16(ah1, bh3, c13, 0, 0, 0);

      c00 = __builtin_amdgcn_mfma_f32_16x16x32_bf16(ah0, bl0, c00, 0, 0, 0);
      c01 = __builtin_amdgcn_mfma_f32_16x16x32_bf16(ah0, bl1, c01, 0, 0, 0);
      c02 = __builtin_amdgcn_mfma_f32_16x16x32_bf16(ah0, bl2, c02, 0, 0, 0);
      c03 = __builtin_amdgcn_mfma_f32_16x16x32_bf16(ah0, bl3, c03, 0, 0, 0);
      c10 = __builtin_amdgcn_mfma_f32_16x16x32_bf16(ah1, bl0, c10, 0, 0, 0);
      c11 = __builtin_amdgcn_mfma_f32_16x16x32_bf16(ah1, bl1, c11, 0, 0, 0);
      c12 = __builtin_amdgcn_mfma_f32_16x16x32_bf16(ah1, bl2, c12, 0, 0, 0);
      c13 = __builtin_amdgcn_mfma_f32_16x16x32_bf16(ah1, bl3, c13, 0, 0, 0);

      c00 = __builtin_amdgcn_mfma_f32_16x16x32_bf16(al0, bh0, c00, 0, 0, 0);
      c01 = __builtin_amdgcn_mfma_f32_16x16x32_bf16(al0, bh1, c01, 0, 0, 0);
      c02 = __builtin_amdgcn_mfma_f32_16x16x32_bf16(al0, bh2, c02, 0, 0, 0);
      c03 = __builtin_amdgcn_mfma_f32_16x16x32_bf16(al0, bh3, c03, 0, 0, 0);
      c10 = __builtin_amdgcn_mfma_f32_16x16x32_bf16(al1, bh0, c10, 0, 0, 0);
      c11 = __builtin_amdgcn_mfma_f32_16x16x32_bf16(al1, bh1, c11, 0, 0, 0);
      c12 = __builtin_amdgcn_mfma_f32_16x16x32_bf16(al1, bh2, c12, 0, 0, 0);
      c13 = __builtin_amdgcn_mfma_f32_16x16x32_bf16(al1, bh3, c13, 0, 0, 0);
    }
    if (more) {
      const int nb = buf ^ 1;
      *(bf16x8*)&As_h[nb][ar][ak8]  = rah;
      *(bf16x8*)&As_l[nb][ar][ak8]  = ral;
      *(bf16x8*)&Bs_h[nb][bna][bk8] = rbh0;
      *(bf16x8*)&Bs_l[nb][bna][bk8] = rbl0;
      *(bf16x8*)&Bs_h[nb][bnb][bk8] = rbh1;
      *(bf16x8*)&Bs_l[nb][bnb][bk8] = rbl1;
    }
    __syncthreads();
    buf ^= 1;
  }

#pragma unroll
  for (int e = 0; e < 4; ++e) {
    const size_t r0 = (size_t)(m0 + mr[e]) * N;
    const size_t r1 = r0 + (size_t)16 * N;
    const int c = n0 + nc[e];
    C[r0 + c +  0] = c00[e];
    C[r0 + c + 16] = c01[e];
    C[r0 + c + 32] = c02[e];
    C[r0 + c + 48] = c03[e];
    C[r1 + c +  0] = c10[e];
    C[r1 + c + 16] = c11[e];
    C[r1 + c + 32] = c12[e];
    C[r1 + c + 48] = c13[e];
  }
}

// ---------------------------------------------------------------------------
// Host launcher. (r15 structure; relmlp grid 4096 -> 1024.)
// ---------------------------------------------------------------------------
extern "C" void kernel_launch(void* const* d_in, const int* in_sizes, int n_in,
                              void* d_out, int out_size, void* d_ws, size_t ws_size,
                              hipStream_t stream)
{
  (void)in_sizes; (void)n_in; (void)out_size; (void)ws_size;
  const float* x   = (const float*)d_in[0];
  const float* Wi  = (const float*)d_in[1];
  const float* Wp  = (const float*)d_in[2];
  const float* pal = (const float*)d_in[3];
  const float* W1  = (const float*)d_in[4];
  const float* b1  = (const float*)d_in[5];
  const float* W2  = (const float*)d_in[6];
  const float* b2  = (const float*)d_in[7];
  const float* Wc  = (const float*)d_in[8];
  const float* bc  = (const float*)d_in[9];
  const float* Wm  = (const float*)d_in[10];
  const float* bm  = (const float*)d_in[11];
  const float* Wo  = (const float*)d_in[12];
  float* out = (float*)d_out;

  float* w = (float*)d_ws;
  float* palT = w;  w += (size_t)256 * D_DIM;
  float* I    = w;  w += (size_t)BATCH * T_LEN * D_DIM;
  float* P    = w;  w += (size_t)BATCH * T_LEN * D_DIM;
  float* Sb   = w;  w += (size_t)BATCH * T_LEN * T_LEN;
  float* nIb  = w;  w += (size_t)BATCH * T_LEN;
  float* nPb  = w;  w += (size_t)BATCH * T_LEN;
  int*   idx  = (int*)w;  w += (size_t)BATCH * T_LEN * 16;
  int*   cand = (int*)w;

  unsigned short* Xh = (unsigned short*)Sb;
  unsigned short* Xm = Xh + (size_t)4096 * 1024;
  unsigned short* Xl = Xm + (size_t)4096 * 1024;
  unsigned short* WT = (unsigned short*)d_out;

  float2* tab = (float2*)Sb;
  unsigned short* Ssc = (unsigned short*)Sb;
  unsigned short* Ih  = (unsigned short*)(Sb + (size_t)4 * 1024 * 1024);
  unsigned short* Ph  = Ih + (size_t)4 * 1024 * 1024;
  unsigned short* Vh  = (unsigned short*)Sb;
  unsigned short* Vl  = Vh + (size_t)4 * 1024 * 1024;
  unsigned short* WohT = (unsigned short*)P;
  unsigned short* WolT = WohT + (size_t)D_DIM * D_DIM;

  const int MROWS = BATCH * T_LEN;  // 4096

  xsplit3<<<(MROWS * D_DIM) / (256 * 4), 256, 0, stream>>>(x, Xh, Xm, Xl);
  wsplit3T<<<dim3(D_DIM / 64, D_DIM / 64, 2), 256, 0, stream>>>(Wi, Wp, WT);

  gemm3bf<<<dim3(D_DIM / 64, MROWS / 64, 2), 256, 0, stream>>>(
      Xh, Xm, Xl, WT, I);

  prep_kernel<<<T_LEN + 1024, 256, 0, stream>>>(tab, pal, palT);

  rope_norm_kernel<<<MROWS, 256, 0, stream>>>(I, P, tab, nIb, nPb, Ih, Ph);

  screen_bf16<<<dim3(272, 1, 2), 256, 0, stream>>>(Ih, Ph, Ssc);

  topk_screen<<<dim3(T_LEN / 4, BATCH), 256, 0, stream>>>(Ssc, cand);

  rescore_kernel<<<MROWS, 256, 0, stream>>>(I, P, cand, idx);

  woconvT<<<dim3(D_DIM / 64, D_DIM / 64), 256, 0, stream>>>(Wo, WohT, WolT);

  relmlp_kernel<<<MROWS / 4, 256, 0, stream>>>(Ih, Ph, nIb, nPb, idx,
                                               W1, b1, W2, b2, Wc, bc, Wm, bm,
                                               palT, Vh, Vl);

  gemmbf<<<dim3(D_DIM / 128, MROWS / 64), 256, 0, stream>>>(
      Vh, Vl, WohT, WolT, out, D_DIM, D_DIM);
}